// Round 1
// baseline (349.560 us; speedup 1.0000x reference)
//
#include <hip/hip_runtime.h>
#include <stdint.h>
#include <stddef.h>

#define H_ 8
#define T_ 1024

typedef __attribute__((ext_vector_type(8))) short s16x8;
typedef __attribute__((ext_vector_type(4))) float f32x4;

static __device__ __forceinline__ unsigned short f2bf(float f){
  unsigned u = __float_as_uint(f);
  u += 0x7fffu + ((u >> 16) & 1u);          // round-to-nearest-even
  return (unsigned short)(u >> 16);
}
static __device__ __forceinline__ float bf2f(unsigned short b){
  return __uint_as_float(((unsigned)b) << 16);
}

// ---------------- cast hidden_states to bf16 hi + lo (split for precise router GEMM)
__global__ void cast_hs(const float* __restrict__ X, unsigned short* __restrict__ hi,
                        unsigned short* __restrict__ lo){
  size_t idx = ((size_t)blockIdx.x * 256 + threadIdx.x) * 8;
  float4 a = *(const float4*)(X + idx);
  float4 b = *(const float4*)(X + idx + 4);
  float v[8] = {a.x,a.y,a.z,a.w,b.x,b.y,b.z,b.w};
  unsigned short hh[8], ll[8];
#pragma unroll
  for(int i=0;i<8;i++){ hh[i]=f2bf(v[i]); ll[i]=f2bf(v[i]-bf2f(hh[i])); }
  ushort4 h0,h1,l0,l1;
  h0.x=hh[0];h0.y=hh[1];h0.z=hh[2];h0.w=hh[3];
  h1.x=hh[4];h1.y=hh[5];h1.z=hh[6];h1.w=hh[7];
  l0.x=ll[0];l0.y=ll[1];l0.z=ll[2];l0.w=ll[3];
  l1.x=ll[4];l1.y=ll[5];l1.z=ll[6];l1.w=ll[7];
  *(ushort4*)&hi[idx]=h0; *(ushort4*)&hi[idx+4]=h1;
  *(ushort4*)&lo[idx]=l0; *(ushort4*)&lo[idx+4]=l1;
}

// ---------------- transpose+cast weights: z=0,1,2 -> WcatT3 (Wq|Wk|Wv), z=3 -> WrT hi+lo, z=4 -> WoT
__global__ void wtrans(const float* __restrict__ Wq, const float* __restrict__ Wk,
                       const float* __restrict__ Wv, const float* __restrict__ Wr,
                       const float* __restrict__ Wo,
                       unsigned short* __restrict__ WcatT3, unsigned short* __restrict__ WrThi,
                       unsigned short* __restrict__ WrTlo, unsigned short* __restrict__ WoT){
  __shared__ float tile[32][33];
  int z = blockIdx.z;
  const float* src = (z==0)?Wq:(z==1)?Wk:(z==2)?Wv:(z==3)?Wr:Wo;
  int c0 = blockIdx.x*32;   // out-col block
  int k0 = blockIdx.y*32;   // in-row block
  int tx = threadIdx.x, ty = threadIdx.y; // 32 x 8
#pragma unroll
  for(int r=0;r<32;r+=8)
    tile[ty+r][tx] = src[(size_t)(k0+ty+r)*1024 + c0 + tx];
  __syncthreads();
#pragma unroll
  for(int r=0;r<32;r+=8){
    int c = c0 + ty + r;
    int k = k0 + tx;
    float v = tile[tx][ty+r];
    if(z < 3){
      WcatT3[((size_t)(z*1024 + c))*1024 + k] = f2bf(v);
    } else if(z == 3){
      unsigned short hv = f2bf(v);
      WrThi[(size_t)c*1024 + k] = hv;
      WrTlo[(size_t)c*1024 + k] = f2bf(v - bf2f(hv));
    } else {
      WoT[(size_t)c*1024 + k] = f2bf(v);
    }
  }
}

// ---------------- plain bf16 MFMA GEMM: C[M][N] = A[M][K] * BT[N][K]^T  (128x128 tile, BK=32)
__launch_bounds__(256)
__global__ void gemm_bf16(const unsigned short* __restrict__ A,
                          const unsigned short* __restrict__ BT,
                          float* __restrict__ C, int M, int N, int K){
  __shared__ unsigned short As[128][40];
  __shared__ unsigned short Bs[128][40];
  int tid = threadIdx.x;
  int mBase = blockIdx.y*128, nBase = blockIdx.x*128;
  int w = tid>>6, lane = tid&63, wr = w>>1, wc = w&1;
  int kg = lane>>4, l15 = lane&15;
  f32x4 acc[4][4];
#pragma unroll
  for(int i=0;i<4;i++)
#pragma unroll
    for(int j=0;j<4;j++) acc[i][j] = (f32x4){0.f,0.f,0.f,0.f};
  int ldRow = tid>>2, ldK = (tid&3)*8;
  for(int kb=0; kb<K; kb+=32){
    *(int4*)&As[ldRow   ][ldK] = *(const int4*)&A [(size_t)(mBase+ldRow   )*K + kb+ldK];
    *(int4*)&As[ldRow+64][ldK] = *(const int4*)&A [(size_t)(mBase+ldRow+64)*K + kb+ldK];
    *(int4*)&Bs[ldRow   ][ldK] = *(const int4*)&BT[(size_t)(nBase+ldRow   )*K + kb+ldK];
    *(int4*)&Bs[ldRow+64][ldK] = *(const int4*)&BT[(size_t)(nBase+ldRow+64)*K + kb+ldK];
    __syncthreads();
    s16x8 afr[4], bfr[4];
#pragma unroll
    for(int f=0;f<4;f++){
      afr[f] = *(const s16x8*)&As[wr*64 + f*16 + l15][kg*8];
      bfr[f] = *(const s16x8*)&Bs[wc*64 + f*16 + l15][kg*8];
    }
#pragma unroll
    for(int fm=0;fm<4;fm++)
#pragma unroll
      for(int fn=0;fn<4;fn++)
        acc[fm][fn] = __builtin_amdgcn_mfma_f32_16x16x32_bf16(afr[fm], bfr[fn], acc[fm][fn], 0,0,0);
    __syncthreads();
  }
#pragma unroll
  for(int fm=0;fm<4;fm++)
#pragma unroll
    for(int fn=0;fn<4;fn++){
      int col = nBase + wc*64 + fn*16 + l15;
      int row = mBase + wr*64 + fm*16 + kg*4;
#pragma unroll
      for(int r=0;r<4;r++) C[(size_t)(row+r)*N + col] = acc[fm][fn][r];
    }
}

// ---------------- 3-term split-bf16 GEMM (~f32 accuracy) for router logits
__launch_bounds__(256)
__global__ void gemm_bf16_3t(const unsigned short* __restrict__ Ah, const unsigned short* __restrict__ Al,
                             const unsigned short* __restrict__ Bh, const unsigned short* __restrict__ Bl,
                             float* __restrict__ C, int M, int N, int K){
  __shared__ unsigned short Ash[128][40], Asl[128][40], Bsh[128][40], Bsl[128][40];
  int tid = threadIdx.x;
  int mBase = blockIdx.y*128, nBase = blockIdx.x*128;
  int w = tid>>6, lane = tid&63, wr = w>>1, wc = w&1;
  int kg = lane>>4, l15 = lane&15;
  f32x4 acc[4][4];
#pragma unroll
  for(int i=0;i<4;i++)
#pragma unroll
    for(int j=0;j<4;j++) acc[i][j] = (f32x4){0.f,0.f,0.f,0.f};
  int ldRow = tid>>2, ldK = (tid&3)*8;
  for(int kb=0; kb<K; kb+=32){
    *(int4*)&Ash[ldRow   ][ldK] = *(const int4*)&Ah[(size_t)(mBase+ldRow   )*K + kb+ldK];
    *(int4*)&Ash[ldRow+64][ldK] = *(const int4*)&Ah[(size_t)(mBase+ldRow+64)*K + kb+ldK];
    *(int4*)&Asl[ldRow   ][ldK] = *(const int4*)&Al[(size_t)(mBase+ldRow   )*K + kb+ldK];
    *(int4*)&Asl[ldRow+64][ldK] = *(const int4*)&Al[(size_t)(mBase+ldRow+64)*K + kb+ldK];
    *(int4*)&Bsh[ldRow   ][ldK] = *(const int4*)&Bh[(size_t)(nBase+ldRow   )*K + kb+ldK];
    *(int4*)&Bsh[ldRow+64][ldK] = *(const int4*)&Bh[(size_t)(nBase+ldRow+64)*K + kb+ldK];
    *(int4*)&Bsl[ldRow   ][ldK] = *(const int4*)&Bl[(size_t)(nBase+ldRow   )*K + kb+ldK];
    *(int4*)&Bsl[ldRow+64][ldK] = *(const int4*)&Bl[(size_t)(nBase+ldRow+64)*K + kb+ldK];
    __syncthreads();
    s16x8 ah[4], al[4], bh[4], bl[4];
#pragma unroll
    for(int f=0;f<4;f++){
      ah[f] = *(const s16x8*)&Ash[wr*64 + f*16 + l15][kg*8];
      al[f] = *(const s16x8*)&Asl[wr*64 + f*16 + l15][kg*8];
      bh[f] = *(const s16x8*)&Bsh[wc*64 + f*16 + l15][kg*8];
      bl[f] = *(const s16x8*)&Bsl[wc*64 + f*16 + l15][kg*8];
    }
#pragma unroll
    for(int fm=0;fm<4;fm++)
#pragma unroll
      for(int fn=0;fn<4;fn++){
        acc[fm][fn] = __builtin_amdgcn_mfma_f32_16x16x32_bf16(ah[fm], bh[fn], acc[fm][fn], 0,0,0);
        acc[fm][fn] = __builtin_amdgcn_mfma_f32_16x16x32_bf16(ah[fm], bl[fn], acc[fm][fn], 0,0,0);
        acc[fm][fn] = __builtin_amdgcn_mfma_f32_16x16x32_bf16(al[fm], bh[fn], acc[fm][fn], 0,0,0);
      }
    __syncthreads();
  }
#pragma unroll
  for(int fm=0;fm<4;fm++)
#pragma unroll
    for(int fn=0;fn<4;fn++){
      int col = nBase + wc*64 + fn*16 + l15;
      int row = mBase + wr*64 + fm*16 + kg*4;
#pragma unroll
      for(int r=0;r<4;r++) C[(size_t)(row+r)*N + col] = acc[fm][fn][r];
    }
}

// ---------------- f_head = -exp(A_log)*softplus(hs@Wa + dt_bias)  (exact f32)
__global__ void fhead_k(const float* __restrict__ X, const float* __restrict__ Wa,
                        const float* __restrict__ A_log, const float* __restrict__ dtb,
                        float* __restrict__ fh){
  __shared__ float xs[1024];
  int n = blockIdx.x, tid = threadIdx.x;   // 256 threads
  *(float4*)&xs[tid*4] = *(const float4*)&X[(size_t)n*1024 + tid*4];
  __syncthreads();
  int h = tid>>5, l = tid&31;
  float s = 0.f;
  for(int k=l;k<1024;k+=32) s += xs[k]*Wa[(size_t)k*8 + h];
  s += __shfl_xor(s,1); s += __shfl_xor(s,2); s += __shfl_xor(s,4);
  s += __shfl_xor(s,8); s += __shfl_xor(s,16);
  if(l==0){
    float z = s + dtb[h];
    float sp = (z > 20.f) ? z : log1pf(expf(z));
    fh[(size_t)n*8 + h] = -expf(A_log[h]) * sp;
  }
}

// ---------------- per-(token,head): silu+rmsnorm q/k, silu v, sigmoid router, top-32, gates
__launch_bounds__(128)
__global__ void postproc(const float* __restrict__ C1, const float* __restrict__ R,
                         const float* __restrict__ fh, const float* __restrict__ qw,
                         const float* __restrict__ kw,
                         float* __restrict__ Qd, float* __restrict__ Wt,
                         float* __restrict__ Fd, float* __restrict__ Vd){
  __shared__ float sc[128];
  __shared__ float red[2];
  int blk = blockIdx.x;
  int n = blk>>3, h = blk&7;
  int i = threadIdx.x;                // 0..127
  int b = n>>10, t = n&1023;
  size_t base = ((size_t)(b*H_ + h)*T_ + t)*128 + i;
  size_t cb = (size_t)n*3072;
  float qraw = C1[cb + h*128 + i];
  float kraw = C1[cb + 1024 + h*128 + i];
  float vraw = C1[cb + 2048 + h*128 + i];
  float rlog = R[(size_t)n*1024 + h*128 + i];
  float qs = qraw/(1.f+expf(-qraw));
  float ks = kraw/(1.f+expf(-kraw));
  float vv = vraw/(1.f+expf(-vraw));
  float si = 1.f/(1.f+expf(-rlog));
  sc[i] = si;
  __syncthreads();
  int cnt = 0;
  for(int j=0;j<128;j++){ float sj = sc[j]; cnt += (sj>si) || (sj==si && j<i); }
  bool sel = cnt < 32;   // stable top-32 (ties -> lower index), matches lax.top_k
  float x;
  // rms(q)
  x = qs*qs;
  x+=__shfl_xor(x,1);x+=__shfl_xor(x,2);x+=__shfl_xor(x,4);x+=__shfl_xor(x,8);x+=__shfl_xor(x,16);x+=__shfl_xor(x,32);
  __syncthreads(); if((i&63)==0) red[i>>6]=x; __syncthreads();
  float qn = qs * rsqrtf((red[0]+red[1])/128.f + 1e-5f) * qw[i];
  // rms(k)
  x = ks*ks;
  x+=__shfl_xor(x,1);x+=__shfl_xor(x,2);x+=__shfl_xor(x,4);x+=__shfl_xor(x,8);x+=__shfl_xor(x,16);x+=__shfl_xor(x,32);
  __syncthreads(); if((i&63)==0) red[i>>6]=x; __syncthreads();
  float kn = ks * rsqrtf((red[0]+red[1])/128.f + 1e-5f) * kw[i];
  // topk weight sum
  x = sel ? si : 0.f;
  x+=__shfl_xor(x,1);x+=__shfl_xor(x,2);x+=__shfl_xor(x,4);x+=__shfl_xor(x,8);x+=__shfl_xor(x,16);x+=__shfl_xor(x,32);
  __syncthreads(); if((i&63)==0) red[i>>6]=x; __syncthreads();
  float wsum = red[0]+red[1];
  float wgt = sel ? si/(wsum + 1e-9f) : 0.f;
  float f = fh[(size_t)n*8 + h] * wgt;       // log decay for this slot
  Qd[base] = qn;
  Wt[base] = (1.f - expf(f)) * kn;           // write gate s * k
  Fd[base] = f;
  Vd[base] = vv;
}

// ---------------- phase 1: per chunk (C=32): inclusive cumsum F (in-place), E = exp(Ftot), dS = Khat^T V
__launch_bounds__(256)
__global__ void chunk_sum(float* __restrict__ Fd, const float* __restrict__ Wt,
                          const float* __restrict__ Vd, float* __restrict__ dS,
                          float* __restrict__ E){
  __shared__ float Fc[32][128];
  __shared__ float Kh[32][128];
  __shared__ float Vs[32][128];
  int blk = blockIdx.x, bh = blk>>5, c = blk&31;
  int tid = threadIdx.x;
  size_t fbase = ((size_t)bh*T_ + (size_t)c*32)*128;
  for(int e=tid;e<4096;e+=256){ Fc[e>>7][e&127] = Fd[fbase+e]; Vs[e>>7][e&127] = Vd[fbase+e]; }
  __syncthreads();
  if(tid < 128){
    float a = 0.f;
    for(int t2=0;t2<32;t2++){ a += Fc[t2][tid]; Fc[t2][tid] = a; }
  }
  __syncthreads();
  for(int e=tid;e<4096;e+=256){
    int t2=e>>7, i=e&127;
    float fc = Fc[t2][i];
    Fd[fbase+e] = fc;                                  // in-place cumsum
    Kh[t2][i] = Wt[fbase+e] * expf(Fc[31][i] - fc);    // exponent <= 0, safe
  }
  if(tid < 128) E[((size_t)bh*32 + c)*128 + tid] = expf(Fc[31][tid]);
  __syncthreads();
  int ti = (tid>>4)*8, tj = (tid&15)*8;
  float acc[8][8];
#pragma unroll
  for(int a=0;a<8;a++)
#pragma unroll
    for(int b2=0;b2<8;b2++) acc[a][b2]=0.f;
  for(int t2=0;t2<32;t2++){
    float kr[8], vr[8];
#pragma unroll
    for(int a=0;a<8;a++){ kr[a]=Kh[t2][ti+a]; vr[a]=Vs[t2][tj+a]; }
#pragma unroll
    for(int a=0;a<8;a++)
#pragma unroll
      for(int b2=0;b2<8;b2++) acc[a][b2] += kr[a]*vr[b2];
  }
  size_t dbase = (size_t)blk*16384;
#pragma unroll
  for(int a=0;a<8;a++)
    for(int b2=0;b2<8;b2+=4){
      float4 o4 = make_float4(acc[a][b2],acc[a][b2+1],acc[a][b2+2],acc[a][b2+3]);
      *(float4*)&dS[dbase + (size_t)(ti+a)*128 + tj+b2] = o4;
    }
}

// ---------------- phase 2: inter-chunk scan; dS buffer becomes Sstart in-place
__global__ void scan_k(float* __restrict__ dS, const float* __restrict__ E){
  int g = blockIdx.x*256 + threadIdx.x;   // 0..262143 : (bh, i*128+j)
  int bh = g>>14, e = g&16383, i = e>>7;
  float S = 0.f;
  for(int c=0;c<32;c++){
    size_t off = ((size_t)(bh*32 + c))*16384 + e;
    float d  = dS[off];
    float Ec = E[((size_t)(bh*32 + c))*128 + i];
    dS[off] = S;          // state at chunk start
    S = Ec*S + d;
  }
}

// ---------------- phase 3: per chunk outputs O = qt @ Sstart + tril(qt kt^T) @ V
__launch_bounds__(256)
__global__ void chunk_out(const float* __restrict__ Qd, const float* __restrict__ Wt,
                          const float* __restrict__ Fd, const float* __restrict__ Vd,
                          const float* __restrict__ Sst, float* __restrict__ O){
  __shared__ float qt[32][128];
  __shared__ float kt[32][128];
  __shared__ float Vs[32][128];
  __shared__ float Amat[32][32];
  __shared__ float Ss[16][128];
  int blk = blockIdx.x, bh = blk>>5, c = blk&31;
  int b = bh>>3, h = bh&7;
  int tid = threadIdx.x;
  size_t fbase = ((size_t)bh*T_ + (size_t)c*32)*128;
  for(int e=tid;e<4096;e+=256){
    int t2=e>>7, i=e&127;
    float fc = Fd[fbase+e];
    qt[t2][i] = Qd[fbase+e]*expf(fc);
    kt[t2][i] = Wt[fbase+e]*expf(-fc);   // bounded by chunk=32 analysis (<= ~e^60)
    Vs[t2][i] = Vd[fbase+e];
  }
  __syncthreads();
  {
    int t2 = tid>>3, tg = (tid&7)*4;
    float a0=0,a1=0,a2=0,a3=0;
    for(int k=0;k<128;k++){
      float qv = qt[t2][k];
      a0 += qv*kt[tg+0][k]; a1 += qv*kt[tg+1][k];
      a2 += qv*kt[tg+2][k]; a3 += qv*kt[tg+3][k];
    }
    Amat[t2][tg+0] = (tg+0<=t2)?a0:0.f;
    Amat[t2][tg+1] = (tg+1<=t2)?a1:0.f;
    Amat[t2][tg+2] = (tg+2<=t2)?a2:0.f;
    Amat[t2][tg+3] = (tg+3<=t2)?a3:0.f;
  }
  int tt = tid>>3, jg = (tid&7)*16;
  float acc[16];
#pragma unroll
  for(int j=0;j<16;j++) acc[j]=0.f;
  size_t sbase = (size_t)blk*16384;
  for(int kb=0;kb<128;kb+=16){
    __syncthreads();
    for(int e=tid;e<2048;e+=256) Ss[e>>7][e&127] = Sst[sbase + (size_t)kb*128 + e];
    __syncthreads();
#pragma unroll
    for(int kk=0;kk<16;kk++){
      float qv = qt[tt][kb+kk];
#pragma unroll
      for(int j=0;j<16;j++) acc[j] += qv*Ss[kk][jg+j];
    }
  }
  __syncthreads();
  for(int u=0;u<32;u++){
    float av = Amat[tt][u];
#pragma unroll
    for(int j=0;j<16;j++) acc[j] += av*Vs[u][jg+j];
  }
  int tglob = c*32 + tt;
  size_t obase = ((size_t)(b*T_ + tglob))*1024 + h*128 + jg;
#pragma unroll
  for(int j=0;j<16;j+=4){
    float4 o4 = make_float4(acc[j],acc[j+1],acc[j+2],acc[j+3]);
    *(float4*)&O[obase + j] = o4;
  }
}

// ---------------- final g-RMSNorm over D=1024 + cast bf16 for output GEMM
__global__ void gnorm_k(const float* __restrict__ Ob, const float* __restrict__ gw,
                        unsigned short* __restrict__ On){
  __shared__ float red[4];
  int n = blockIdx.x, tid = threadIdx.x;   // 256 threads
  size_t base = (size_t)n*1024 + tid*4;
  float4 x = *(const float4*)&Ob[base];
  float ss = x.x*x.x + x.y*x.y + x.z*x.z + x.w*x.w;
  ss+=__shfl_xor(ss,1);ss+=__shfl_xor(ss,2);ss+=__shfl_xor(ss,4);
  ss+=__shfl_xor(ss,8);ss+=__shfl_xor(ss,16);ss+=__shfl_xor(ss,32);
  if((tid&63)==0) red[tid>>6]=ss;
  __syncthreads();
  float sc = rsqrtf((red[0]+red[1]+red[2]+red[3])/1024.f + 1e-5f);
  float4 g = *(const float4*)&gw[tid*4];
  ushort4 o4;
  o4.x=f2bf(x.x*sc*g.x); o4.y=f2bf(x.y*sc*g.y);
  o4.z=f2bf(x.z*sc*g.z); o4.w=f2bf(x.w*sc*g.w);
  *(ushort4*)&On[base]=o4;
}

extern "C" void kernel_launch(void* const* d_in, const int* in_sizes, int n_in,
                              void* d_out, int out_size, void* d_ws, size_t ws_size,
                              hipStream_t stream){
  const float* hs   = (const float*)d_in[0];
  const float* Wq   = (const float*)d_in[1];
  const float* Wk   = (const float*)d_in[2];
  const float* Wv   = (const float*)d_in[3];
  const float* Wr   = (const float*)d_in[4];
  const float* Wa   = (const float*)d_in[5];
  const float* A_log= (const float*)d_in[6];
  const float* dtb  = (const float*)d_in[7];
  const float* qw   = (const float*)d_in[8];
  const float* kw   = (const float*)d_in[9];
  const float* gw   = (const float*)d_in[10];
  const float* Wo   = (const float*)d_in[11];
  float* out = (float*)d_out;

  char* wsp = (char*)d_ws;
  size_t off = 0;
  auto alloc = [&](size_t bytes)->void*{ void* p = wsp + off; off += (bytes + 255) & ~(size_t)255; return p; };
  unsigned short* Xhi    = (unsigned short*)alloc(2048ull*1024*2);
  unsigned short* Xlo    = (unsigned short*)alloc(2048ull*1024*2);
  unsigned short* WcatT3 = (unsigned short*)alloc(3072ull*1024*2);
  unsigned short* WrThi  = (unsigned short*)alloc(1024ull*1024*2);
  unsigned short* WrTlo  = (unsigned short*)alloc(1024ull*1024*2);
  unsigned short* WoT    = (unsigned short*)alloc(1024ull*1024*2);
  float* C1 = (float*)alloc(2048ull*3072*4);
  float* R  = (float*)alloc(2048ull*1024*4);
  float* fh = (float*)alloc(2048ull*8*4);
  float* Qd = (float*)alloc(16ull*1024*128*4);
  float* Wt = (float*)alloc(16ull*1024*128*4);
  float* Fd = (float*)alloc(16ull*1024*128*4);
  float* Vd = (float*)alloc(16ull*1024*128*4);
  float* E  = (float*)alloc(16ull*32*128*4);
  float* dS = (float*)alloc(16ull*32*16384*4);
  float* Ob = (float*)alloc(2048ull*1024*4);
  unsigned short* On = (unsigned short*)alloc(2048ull*1024*2);
  (void)ws_size; (void)in_sizes; (void)n_in; (void)out_size;

  cast_hs    <<<dim3(1024),        dim3(256),   0, stream>>>(hs, Xhi, Xlo);
  wtrans     <<<dim3(32,32,5),     dim3(32,8),  0, stream>>>(Wq,Wk,Wv,Wr,Wo, WcatT3,WrThi,WrTlo,WoT);
  gemm_bf16  <<<dim3(24,16),       dim3(256),   0, stream>>>(Xhi, WcatT3, C1, 2048, 3072, 1024);
  gemm_bf16_3t<<<dim3(8,16),       dim3(256),   0, stream>>>(Xhi, Xlo, WrThi, WrTlo, R, 2048, 1024, 1024);
  fhead_k    <<<dim3(2048),        dim3(256),   0, stream>>>(hs, Wa, A_log, dtb, fh);
  postproc   <<<dim3(16384),       dim3(128),   0, stream>>>(C1, R, fh, qw, kw, Qd, Wt, Fd, Vd);
  chunk_sum  <<<dim3(512),         dim3(256),   0, stream>>>(Fd, Wt, Vd, dS, E);
  scan_k     <<<dim3(1024),        dim3(256),   0, stream>>>(dS, E);
  chunk_out  <<<dim3(512),         dim3(256),   0, stream>>>(Qd, Wt, Fd, Vd, dS, Ob);
  gnorm_k    <<<dim3(2048),        dim3(256),   0, stream>>>(Ob, gw, On);
  gemm_bf16  <<<dim3(8,16),        dim3(256),   0, stream>>>(On, WoT, out, 2048, 1024, 1024);
}

// Round 2
// 346.256 us; speedup vs baseline: 1.0095x; 1.0095x over previous
//
#include <hip/hip_runtime.h>
#include <stdint.h>
#include <stddef.h>

#define H_ 8
#define T_ 1024

typedef __attribute__((ext_vector_type(8))) short s16x8;
typedef __attribute__((ext_vector_type(4))) float f32x4;
typedef __attribute__((ext_vector_type(16))) float f32x16;

static __device__ __forceinline__ unsigned short f2bf(float f){
  unsigned u = __float_as_uint(f);
  u += 0x7fffu + ((u >> 16) & 1u);          // round-to-nearest-even
  return (unsigned short)(u >> 16);
}
static __device__ __forceinline__ float bf2f(unsigned short b){
  return __uint_as_float(((unsigned)b) << 16);
}
// async global->LDS 16B (m97 pattern; HW: wave-uniform base + lane*16)
static __device__ __forceinline__ void gl_lds16(const unsigned short* g, unsigned short* l){
  __builtin_amdgcn_global_load_lds((const __attribute__((address_space(1))) unsigned int*)g,
                                   (__attribute__((address_space(3))) unsigned int*)l,
                                   16, 0, 0);
}

// ---------------- cast hidden_states to bf16 hi + lo (split for precise router GEMM)
__global__ void cast_hs(const float* __restrict__ X, unsigned short* __restrict__ hi,
                        unsigned short* __restrict__ lo){
  size_t idx = ((size_t)blockIdx.x * 256 + threadIdx.x) * 8;
  float4 a = *(const float4*)(X + idx);
  float4 b = *(const float4*)(X + idx + 4);
  float v[8] = {a.x,a.y,a.z,a.w,b.x,b.y,b.z,b.w};
  unsigned short hh[8], ll[8];
#pragma unroll
  for(int i=0;i<8;i++){ hh[i]=f2bf(v[i]); ll[i]=f2bf(v[i]-bf2f(hh[i])); }
  ushort4 h0,h1,l0,l1;
  h0.x=hh[0];h0.y=hh[1];h0.z=hh[2];h0.w=hh[3];
  h1.x=hh[4];h1.y=hh[5];h1.z=hh[6];h1.w=hh[7];
  l0.x=ll[0];l0.y=ll[1];l0.z=ll[2];l0.w=ll[3];
  l1.x=ll[4];l1.y=ll[5];l1.z=ll[6];l1.w=ll[7];
  *(ushort4*)&hi[idx]=h0; *(ushort4*)&hi[idx+4]=h1;
  *(ushort4*)&lo[idx]=l0; *(ushort4*)&lo[idx+4]=l1;
}

// ---------------- transpose+cast weights: z=0,1,2 -> WcatT3 (Wq|Wk|Wv), z=3 -> WrT hi+lo, z=4 -> WoT
__global__ void wtrans(const float* __restrict__ Wq, const float* __restrict__ Wk,
                       const float* __restrict__ Wv, const float* __restrict__ Wr,
                       const float* __restrict__ Wo,
                       unsigned short* __restrict__ WcatT3, unsigned short* __restrict__ WrThi,
                       unsigned short* __restrict__ WrTlo, unsigned short* __restrict__ WoT){
  __shared__ float tile[32][33];
  int z = blockIdx.z;
  const float* src = (z==0)?Wq:(z==1)?Wk:(z==2)?Wv:(z==3)?Wr:Wo;
  int c0 = blockIdx.x*32;   // out-col block
  int k0 = blockIdx.y*32;   // in-row block
  int tx = threadIdx.x, ty = threadIdx.y; // 32 x 8
#pragma unroll
  for(int r=0;r<32;r+=8)
    tile[ty+r][tx] = src[(size_t)(k0+ty+r)*1024 + c0 + tx];
  __syncthreads();
#pragma unroll
  for(int r=0;r<32;r+=8){
    int c = c0 + ty + r;
    int k = k0 + tx;
    float v = tile[tx][ty+r];
    if(z < 3){
      WcatT3[((size_t)(z*1024 + c))*1024 + k] = f2bf(v);
    } else if(z == 3){
      unsigned short hv = f2bf(v);
      WrThi[(size_t)c*1024 + k] = hv;
      WrTlo[(size_t)c*1024 + k] = f2bf(v - bf2f(hv));
    } else {
      WoT[(size_t)c*1024 + k] = f2bf(v);
    }
  }
}

// ---------------- bf16 MFMA GEMM, m97-style global_load_lds staging
// C[M][N] = A[M][K] * BT[N][K]^T   (128x128 tile, BK=32)
__launch_bounds__(256)
__global__ void gemm_bf16(const unsigned short* __restrict__ A,
                          const unsigned short* __restrict__ BT,
                          float* __restrict__ C, int M, int N, int K){
  __shared__ unsigned short As[128*32];
  __shared__ unsigned short Bs[128*32];
  int tid = threadIdx.x;
  int mBase = blockIdx.y*128, nBase = blockIdx.x*128;
  int w = tid>>6, lane = tid&63, wr = w>>1, wc = w&1;
  int kg = lane>>4, l15 = lane&15;
  f32x4 acc[4][4];
#pragma unroll
  for(int i=0;i<4;i++)
#pragma unroll
    for(int j=0;j<4;j++) acc[i][j] = (f32x4){0.f,0.f,0.f,0.f};
  const unsigned short* gA = A + (size_t)(mBase + (tid>>2))*K + (tid&3)*8;
  const unsigned short* gB = BT + (size_t)(nBase + (tid>>2))*K + (tid&3)*8;
  for(int kb=0; kb<K; kb+=32){
    gl_lds16(gA + kb,                 &As[tid*8]);
    gl_lds16(gA + (size_t)64*K + kb,  &As[2048 + tid*8]);
    gl_lds16(gB + kb,                 &Bs[tid*8]);
    gl_lds16(gB + (size_t)64*K + kb,  &Bs[2048 + tid*8]);
    __syncthreads();
    s16x8 afr[4], bfr[4];
#pragma unroll
    for(int f=0;f<4;f++){
      afr[f] = *(const s16x8*)&As[(wr*64 + f*16 + l15)*32 + kg*8];
      bfr[f] = *(const s16x8*)&Bs[(wc*64 + f*16 + l15)*32 + kg*8];
    }
#pragma unroll
    for(int fm=0;fm<4;fm++)
#pragma unroll
      for(int fn=0;fn<4;fn++)
        acc[fm][fn] = __builtin_amdgcn_mfma_f32_16x16x32_bf16(afr[fm], bfr[fn], acc[fm][fn], 0,0,0);
    __syncthreads();
  }
#pragma unroll
  for(int fm=0;fm<4;fm++)
#pragma unroll
    for(int fn=0;fn<4;fn++){
      int col = nBase + wc*64 + fn*16 + l15;
      int row = mBase + wr*64 + fm*16 + kg*4;
#pragma unroll
      for(int r=0;r<4;r++) C[(size_t)(row+r)*N + col] = acc[fm][fn][r];
    }
}

// ---------------- 3-term split-bf16 GEMM (~f32 accuracy) for router logits
__launch_bounds__(256)
__global__ void gemm_bf16_3t(const unsigned short* __restrict__ Ah, const unsigned short* __restrict__ Al,
                             const unsigned short* __restrict__ Bh, const unsigned short* __restrict__ Bl,
                             float* __restrict__ C, int M, int N, int K){
  __shared__ unsigned short Ash[128*32], Asl[128*32], Bsh[128*32], Bsl[128*32];
  int tid = threadIdx.x;
  int mBase = blockIdx.y*128, nBase = blockIdx.x*128;
  int w = tid>>6, lane = tid&63, wr = w>>1, wc = w&1;
  int kg = lane>>4, l15 = lane&15;
  f32x4 acc[4][4];
#pragma unroll
  for(int i=0;i<4;i++)
#pragma unroll
    for(int j=0;j<4;j++) acc[i][j] = (f32x4){0.f,0.f,0.f,0.f};
  const unsigned short* gAh = Ah + (size_t)(mBase + (tid>>2))*K + (tid&3)*8;
  const unsigned short* gAl = Al + (size_t)(mBase + (tid>>2))*K + (tid&3)*8;
  const unsigned short* gBh = Bh + (size_t)(nBase + (tid>>2))*K + (tid&3)*8;
  const unsigned short* gBl = Bl + (size_t)(nBase + (tid>>2))*K + (tid&3)*8;
  for(int kb=0; kb<K; kb+=32){
    gl_lds16(gAh + kb,                &Ash[tid*8]);
    gl_lds16(gAh + (size_t)64*K + kb, &Ash[2048 + tid*8]);
    gl_lds16(gAl + kb,                &Asl[tid*8]);
    gl_lds16(gAl + (size_t)64*K + kb, &Asl[2048 + tid*8]);
    gl_lds16(gBh + kb,                &Bsh[tid*8]);
    gl_lds16(gBh + (size_t)64*K + kb, &Bsh[2048 + tid*8]);
    gl_lds16(gBl + kb,                &Bsl[tid*8]);
    gl_lds16(gBl + (size_t)64*K + kb, &Bsl[2048 + tid*8]);
    __syncthreads();
    s16x8 ah[4], al[4], bh[4], bl[4];
#pragma unroll
    for(int f=0;f<4;f++){
      ah[f] = *(const s16x8*)&Ash[(wr*64 + f*16 + l15)*32 + kg*8];
      al[f] = *(const s16x8*)&Asl[(wr*64 + f*16 + l15)*32 + kg*8];
      bh[f] = *(const s16x8*)&Bsh[(wc*64 + f*16 + l15)*32 + kg*8];
      bl[f] = *(const s16x8*)&Bsl[(wc*64 + f*16 + l15)*32 + kg*8];
    }
#pragma unroll
    for(int fm=0;fm<4;fm++)
#pragma unroll
      for(int fn=0;fn<4;fn++){
        acc[fm][fn] = __builtin_amdgcn_mfma_f32_16x16x32_bf16(ah[fm], bh[fn], acc[fm][fn], 0,0,0);
        acc[fm][fn] = __builtin_amdgcn_mfma_f32_16x16x32_bf16(ah[fm], bl[fn], acc[fm][fn], 0,0,0);
        acc[fm][fn] = __builtin_amdgcn_mfma_f32_16x16x32_bf16(al[fm], bh[fn], acc[fm][fn], 0,0,0);
      }
    __syncthreads();
  }
#pragma unroll
  for(int fm=0;fm<4;fm++)
#pragma unroll
    for(int fn=0;fn<4;fn++){
      int col = nBase + wc*64 + fn*16 + l15;
      int row = mBase + wr*64 + fm*16 + kg*4;
#pragma unroll
      for(int r=0;r<4;r++) C[(size_t)(row+r)*N + col] = acc[fm][fn][r];
    }
}

// ---------------- f_head = -exp(A_log)*softplus(hs@Wa + dt_bias)  (exact f32)
__global__ void fhead_k(const float* __restrict__ X, const float* __restrict__ Wa,
                        const float* __restrict__ A_log, const float* __restrict__ dtb,
                        float* __restrict__ fh){
  __shared__ float xs[1024];
  int n = blockIdx.x, tid = threadIdx.x;   // 256 threads
  *(float4*)&xs[tid*4] = *(const float4*)&X[(size_t)n*1024 + tid*4];
  __syncthreads();
  int h = tid>>5, l = tid&31;
  float s = 0.f;
  for(int k=l;k<1024;k+=32) s += xs[k]*Wa[(size_t)k*8 + h];
  s += __shfl_xor(s,1); s += __shfl_xor(s,2); s += __shfl_xor(s,4);
  s += __shfl_xor(s,8); s += __shfl_xor(s,16);
  if(l==0){
    float z = s + dtb[h];
    float sp = (z > 20.f) ? z : log1pf(expf(z));
    fh[(size_t)n*8 + h] = -expf(A_log[h]) * sp;
  }
}

// ---------------- per-(token,head): silu+rmsnorm q/k, silu v, sigmoid router, top-32, gates
__launch_bounds__(128)
__global__ void postproc(const float* __restrict__ C1, const float* __restrict__ R,
                         const float* __restrict__ fh, const float* __restrict__ qw,
                         const float* __restrict__ kw,
                         float* __restrict__ Qd, float* __restrict__ Wt,
                         float* __restrict__ Fd, float* __restrict__ Vd){
  __shared__ float sc[128];
  __shared__ float red[2];
  int blk = blockIdx.x;
  int n = blk>>3, h = blk&7;
  int i = threadIdx.x;                // 0..127
  int b = n>>10, t = n&1023;
  size_t base = ((size_t)(b*H_ + h)*T_ + t)*128 + i;
  size_t cb = (size_t)n*3072;
  float qraw = C1[cb + h*128 + i];
  float kraw = C1[cb + 1024 + h*128 + i];
  float vraw = C1[cb + 2048 + h*128 + i];
  float rlog = R[(size_t)n*1024 + h*128 + i];
  float qs = qraw/(1.f+expf(-qraw));
  float ks = kraw/(1.f+expf(-kraw));
  float vv = vraw/(1.f+expf(-vraw));
  float si = 1.f/(1.f+expf(-rlog));
  sc[i] = si;
  __syncthreads();
  int cnt = 0;
  for(int j=0;j<128;j++){ float sj = sc[j]; cnt += (sj>si) || (sj==si && j<i); }
  bool sel = cnt < 32;   // stable top-32 (ties -> lower index), matches lax.top_k
  float x;
  // rms(q)
  x = qs*qs;
  x+=__shfl_xor(x,1);x+=__shfl_xor(x,2);x+=__shfl_xor(x,4);x+=__shfl_xor(x,8);x+=__shfl_xor(x,16);x+=__shfl_xor(x,32);
  __syncthreads(); if((i&63)==0) red[i>>6]=x; __syncthreads();
  float qn = qs * rsqrtf((red[0]+red[1])/128.f + 1e-5f) * qw[i];
  // rms(k)
  x = ks*ks;
  x+=__shfl_xor(x,1);x+=__shfl_xor(x,2);x+=__shfl_xor(x,4);x+=__shfl_xor(x,8);x+=__shfl_xor(x,16);x+=__shfl_xor(x,32);
  __syncthreads(); if((i&63)==0) red[i>>6]=x; __syncthreads();
  float kn = ks * rsqrtf((red[0]+red[1])/128.f + 1e-5f) * kw[i];
  // topk weight sum
  x = sel ? si : 0.f;
  x+=__shfl_xor(x,1);x+=__shfl_xor(x,2);x+=__shfl_xor(x,4);x+=__shfl_xor(x,8);x+=__shfl_xor(x,16);x+=__shfl_xor(x,32);
  __syncthreads(); if((i&63)==0) red[i>>6]=x; __syncthreads();
  float wsum = red[0]+red[1];
  float wgt = sel ? si/(wsum + 1e-9f) : 0.f;
  float f = fh[(size_t)n*8 + h] * wgt;       // log decay for this slot
  Qd[base] = qn;
  Wt[base] = (1.f - expf(f)) * kn;           // write gate s * k
  Fd[base] = f;
  Vd[base] = vv;
}

// ---------------- phase 1: per chunk (C=32): inclusive cumsum F (in-place), E = exp(Ftot), dS = Khat^T V
// V read per-lane from global (L2) -> LDS pipe only carries Fc/Kh.
__launch_bounds__(256)
__global__ void chunk_sum(float* __restrict__ Fd, const float* __restrict__ Wt,
                          const float* __restrict__ Vd, float* __restrict__ dS,
                          float* __restrict__ E){
  __shared__ float Fc[32][132];
  __shared__ float Kh[32][132];
  int blk = blockIdx.x, bh = blk>>5, c = blk&31;
  int tid = threadIdx.x;
  int w = tid>>6, lane = tid&63;
  size_t fbase = ((size_t)bh*T_ + (size_t)c*32)*128;
  // load F (float4, coalesced)
#pragma unroll
  for(int v=0; v<4; v++){
    int e = v*1024 + tid*4;
    int t2 = e>>7, i0 = e&127;
    float4 f4 = *(const float4*)&Fd[fbase + e];
    *(float4*)&Fc[t2][i0] = f4;
  }
  __syncthreads();
  if(tid < 128){
    float a = 0.f;
    for(int t2=0;t2<32;t2++){ a += Fc[t2][tid]; Fc[t2][tid] = a; }
  }
  __syncthreads();
#pragma unroll
  for(int v=0; v<4; v++){
    int e = v*1024 + tid*4;
    int t2 = e>>7, i0 = e&127;
    float4 fc4 = *(const float4*)&Fc[t2][i0];
    *(float4*)&Fd[fbase + e] = fc4;                    // in-place cumsum
    float4 ft  = *(const float4*)&Fc[31][i0];
    float4 w4  = *(const float4*)&Wt[fbase + e];
    float4 kh;
    kh.x = w4.x * expf(ft.x - fc4.x);
    kh.y = w4.y * expf(ft.y - fc4.y);
    kh.z = w4.z * expf(ft.z - fc4.z);
    kh.w = w4.w * expf(ft.w - fc4.w);
    *(float4*)&Kh[t2][i0] = kh;
  }
  if(tid < 128) E[((size_t)bh*32 + c)*128 + tid] = expf(Fc[31][tid]);
  __syncthreads();
  // dS = Kh^T V : thread = (w, ig=lane>>3, jg=lane&7); i = w*32+ig*4+a; j = jg*4+32q
  int ig = lane>>3, jg = lane&7;
  const float* Vp = Vd + fbase;
  f32x4 acc[4][4];
#pragma unroll
  for(int a=0;a<4;a++)
#pragma unroll
    for(int q=0;q<4;q++) acc[a][q] = (f32x4){0.f,0.f,0.f,0.f};
#pragma unroll 4
  for(int t2=0;t2<32;t2++){
    float4 kq = *(const float4*)&Kh[t2][w*32 + ig*4];
    float4 v0 = *(const float4*)&Vp[t2*128 + jg*4];
    float4 v1 = *(const float4*)&Vp[t2*128 + jg*4 + 32];
    float4 v2 = *(const float4*)&Vp[t2*128 + jg*4 + 64];
    float4 v3 = *(const float4*)&Vp[t2*128 + jg*4 + 96];
    float kk[4] = {kq.x,kq.y,kq.z,kq.w};
#pragma unroll
    for(int a=0;a<4;a++){
      acc[a][0] += kk[a]*(f32x4){v0.x,v0.y,v0.z,v0.w};
      acc[a][1] += kk[a]*(f32x4){v1.x,v1.y,v1.z,v1.w};
      acc[a][2] += kk[a]*(f32x4){v2.x,v2.y,v2.z,v2.w};
      acc[a][3] += kk[a]*(f32x4){v3.x,v3.y,v3.z,v3.w};
    }
  }
  size_t dbase = (size_t)blk*16384;
#pragma unroll
  for(int a=0;a<4;a++)
#pragma unroll
    for(int q=0;q<4;q++)
      *(f32x4*)&dS[dbase + (size_t)(w*32 + ig*4 + a)*128 + jg*4 + 32*q] = acc[a][q];
}

// ---------------- phase 2: inter-chunk scan (float4); dS buffer becomes Sstart in-place
__global__ void scan_k(float* __restrict__ dS, const float* __restrict__ E){
  int g = blockIdx.x*256 + threadIdx.x;   // 65536 threads: (bh, float4 index)
  int bh = g>>12;
  int e4 = (g&4095)*4;
  int i = e4>>7;
  float4 S = make_float4(0.f,0.f,0.f,0.f);
  for(int c=0;c<32;c++){
    size_t off = ((size_t)(bh*32 + c))*16384 + e4;
    float4 d  = *(const float4*)&dS[off];
    float Ec = E[((size_t)(bh*32 + c))*128 + i];
    *(float4*)&dS[off] = S;          // state at chunk start
    S.x = Ec*S.x + d.x;
    S.y = Ec*S.y + d.y;
    S.z = Ec*S.z + d.z;
    S.w = Ec*S.w + d.w;
  }
}

// ---------------- phase 3: per chunk outputs O = qt @ Sstart + tril(qt kt^T) @ V
// S and V read per-lane from global (L2). Amat via wave-0 bf16 MFMA (hi/lo split).
__launch_bounds__(256)
__global__ void chunk_out(const float* __restrict__ Qd, const float* __restrict__ Wt,
                          const float* __restrict__ Fd, const float* __restrict__ Vd,
                          const float* __restrict__ Sst, float* __restrict__ O){
  __shared__ float qtT[128][33];
  __shared__ float Amat[32][33];
  int blk = blockIdx.x, bh = blk>>5, c = blk&31;
  int b = bh>>3, h = bh&7;
  int tid = threadIdx.x;
  int w = tid>>6, lane = tid&63;
  size_t fbase = ((size_t)bh*T_ + (size_t)c*32)*128;
  // phase 0: build qtT[k][tok] = Qd*exp(fc)
#pragma unroll
  for(int v=0; v<4; v++){
    int e = v*1024 + tid*4;
    int t2 = e>>7, i0 = e&127;
    float4 q4 = *(const float4*)&Qd[fbase + e];
    float4 f4 = *(const float4*)&Fd[fbase + e];
    qtT[i0+0][t2] = q4.x * expf(f4.x);
    qtT[i0+1][t2] = q4.y * expf(f4.y);
    qtT[i0+2][t2] = q4.z * expf(f4.z);
    qtT[i0+3][t2] = q4.w * expf(f4.w);
  }
  __syncthreads();
  // wave 0: Amat = tril(qt @ kt^T) via MFMA 32x32x16 bf16, hi/lo 2-term split
  if(w == 0){
    f32x16 am;
#pragma unroll
    for(int r=0;r<16;r++) am[r] = 0.f;
    int rq = lane & 31;            // tok (A-side) == s (B-side) row index for this lane
    int ksl = (lane>>5)*8;
#pragma unroll 2
    for(int step=0; step<8; step++){
      int ko = step*16 + ksl;
      float4 qa = *(const float4*)&Qd[fbase + rq*128 + ko];
      float4 qb = *(const float4*)&Qd[fbase + rq*128 + ko + 4];
      float4 fa = *(const float4*)&Fd[fbase + rq*128 + ko];
      float4 fb = *(const float4*)&Fd[fbase + rq*128 + ko + 4];
      float4 wa = *(const float4*)&Wt[fbase + rq*128 + ko];
      float4 wb = *(const float4*)&Wt[fbase + rq*128 + ko + 4];
      float qv[8] = {qa.x,qa.y,qa.z,qa.w,qb.x,qb.y,qb.z,qb.w};
      float fv[8] = {fa.x,fa.y,fa.z,fa.w,fb.x,fb.y,fb.z,fb.w};
      float wv[8] = {wa.x,wa.y,wa.z,wa.w,wb.x,wb.y,wb.z,wb.w};
      s16x8 aqh, aql, bkh, bkl;
#pragma unroll
      for(int j=0;j<8;j++){
        float ef = expf(fv[j]);
        float qt = qv[j]*ef;
        float kt = wv[j]*expf(-fv[j]);
        unsigned short qh = f2bf(qt);
        unsigned short kh = f2bf(kt);
        aqh[j] = (short)qh; aql[j] = (short)f2bf(qt - bf2f(qh));
        bkh[j] = (short)kh; bkl[j] = (short)f2bf(kt - bf2f(kh));
      }
      am = __builtin_amdgcn_mfma_f32_32x32x16_bf16(aqh, bkh, am, 0,0,0);
      am = __builtin_amdgcn_mfma_f32_32x32x16_bf16(aqh, bkl, am, 0,0,0);
      am = __builtin_amdgcn_mfma_f32_32x32x16_bf16(aql, bkh, am, 0,0,0);
    }
#pragma unroll
    for(int r=0;r<16;r++){
      int row = (r&3) + 8*(r>>2) + 4*(lane>>5);   // tok
      int col = lane & 31;                        // s
      Amat[row][col] = (col <= row) ? am[r] : 0.f;
    }
  }
  // qS: all waves; thread = (w, t2=lane>>3, cgr=lane&7); tok = w*8+t2; cols = cgr*4 + 32q
  int t2 = lane>>3, cgr = lane&7;
  int tok = w*8 + t2;
  const float* Sp = Sst + (size_t)blk*16384;
  f32x4 acc[4];
#pragma unroll
  for(int q=0;q<4;q++) acc[q] = (f32x4){0.f,0.f,0.f,0.f};
#pragma unroll 4
  for(int kk=0; kk<128; kk++){
    float qv = qtT[kk][tok];
    float4 s0 = *(const float4*)&Sp[kk*128 + cgr*4];
    float4 s1 = *(const float4*)&Sp[kk*128 + cgr*4 + 32];
    float4 s2 = *(const float4*)&Sp[kk*128 + cgr*4 + 64];
    float4 s3 = *(const float4*)&Sp[kk*128 + cgr*4 + 96];
    acc[0] += qv*(f32x4){s0.x,s0.y,s0.z,s0.w};
    acc[1] += qv*(f32x4){s1.x,s1.y,s1.z,s1.w};
    acc[2] += qv*(f32x4){s2.x,s2.y,s2.z,s2.w};
    acc[3] += qv*(f32x4){s3.x,s3.y,s3.z,s3.w};
  }
  __syncthreads();
  // AV: o += Amat[tok][u] * V[u][col]
  const float* Vp = Vd + fbase;
#pragma unroll 4
  for(int u=0; u<32; u++){
    float av = Amat[tok][u];
    float4 v0 = *(const float4*)&Vp[u*128 + cgr*4];
    float4 v1 = *(const float4*)&Vp[u*128 + cgr*4 + 32];
    float4 v2 = *(const float4*)&Vp[u*128 + cgr*4 + 64];
    float4 v3 = *(const float4*)&Vp[u*128 + cgr*4 + 96];
    acc[0] += av*(f32x4){v0.x,v0.y,v0.z,v0.w};
    acc[1] += av*(f32x4){v1.x,v1.y,v1.z,v1.w};
    acc[2] += av*(f32x4){v2.x,v2.y,v2.z,v2.w};
    acc[3] += av*(f32x4){v3.x,v3.y,v3.z,v3.w};
  }
  size_t obase = ((size_t)(b*T_ + c*32 + tok))*1024 + h*128 + cgr*4;
#pragma unroll
  for(int q=0;q<4;q++)
    *(f32x4*)&O[obase + 32*q] = acc[q];
}

// ---------------- final g-RMSNorm over D=1024 + cast bf16 for output GEMM
__global__ void gnorm_k(const float* __restrict__ Ob, const float* __restrict__ gw,
                        unsigned short* __restrict__ On){
  __shared__ float red[4];
  int n = blockIdx.x, tid = threadIdx.x;   // 256 threads
  size_t base = (size_t)n*1024 + tid*4;
  float4 x = *(const float4*)&Ob[base];
  float ss = x.x*x.x + x.y*x.y + x.z*x.z + x.w*x.w;
  ss+=__shfl_xor(ss,1);ss+=__shfl_xor(ss,2);ss+=__shfl_xor(ss,4);
  ss+=__shfl_xor(ss,8);ss+=__shfl_xor(ss,16);ss+=__shfl_xor(ss,32);
  if((tid&63)==0) red[tid>>6]=ss;
  __syncthreads();
  float sc = rsqrtf((red[0]+red[1]+red[2]+red[3])/1024.f + 1e-5f);
  float4 g = *(const float4*)&gw[tid*4];
  ushort4 o4;
  o4.x=f2bf(x.x*sc*g.x); o4.y=f2bf(x.y*sc*g.y);
  o4.z=f2bf(x.z*sc*g.z); o4.w=f2bf(x.w*sc*g.w);
  *(ushort4*)&On[base]=o4;
}

extern "C" void kernel_launch(void* const* d_in, const int* in_sizes, int n_in,
                              void* d_out, int out_size, void* d_ws, size_t ws_size,
                              hipStream_t stream){
  const float* hs   = (const float*)d_in[0];
  const float* Wq   = (const float*)d_in[1];
  const float* Wk   = (const float*)d_in[2];
  const float* Wv   = (const float*)d_in[3];
  const float* Wr   = (const float*)d_in[4];
  const float* Wa   = (const float*)d_in[5];
  const float* A_log= (const float*)d_in[6];
  const float* dtb  = (const float*)d_in[7];
  const float* qw   = (const float*)d_in[8];
  const float* kw   = (const float*)d_in[9];
  const float* gw   = (const float*)d_in[10];
  const float* Wo   = (const float*)d_in[11];
  float* out = (float*)d_out;

  char* wsp = (char*)d_ws;
  size_t off = 0;
  auto alloc = [&](size_t bytes)->void*{ void* p = wsp + off; off += (bytes + 255) & ~(size_t)255; return p; };
  unsigned short* Xhi    = (unsigned short*)alloc(2048ull*1024*2);
  unsigned short* Xlo    = (unsigned short*)alloc(2048ull*1024*2);
  unsigned short* WcatT3 = (unsigned short*)alloc(3072ull*1024*2);
  unsigned short* WrThi  = (unsigned short*)alloc(1024ull*1024*2);
  unsigned short* WrTlo  = (unsigned short*)alloc(1024ull*1024*2);
  unsigned short* WoT    = (unsigned short*)alloc(1024ull*1024*2);
  float* C1 = (float*)alloc(2048ull*3072*4);
  float* R  = (float*)alloc(2048ull*1024*4);
  float* fh = (float*)alloc(2048ull*8*4);
  float* Qd = (float*)alloc(16ull*1024*128*4);
  float* Wt = (float*)alloc(16ull*1024*128*4);
  float* Fd = (float*)alloc(16ull*1024*128*4);
  float* Vd = (float*)alloc(16ull*1024*128*4);
  float* E  = (float*)alloc(16ull*32*128*4);
  float* dS = (float*)alloc(16ull*32*16384*4);
  float* Ob = (float*)alloc(2048ull*1024*4);
  unsigned short* On = (unsigned short*)alloc(2048ull*1024*2);
  (void)ws_size; (void)in_sizes; (void)n_in; (void)out_size;

  cast_hs    <<<dim3(1024),        dim3(256),   0, stream>>>(hs, Xhi, Xlo);
  wtrans     <<<dim3(32,32,5),     dim3(32,8),  0, stream>>>(Wq,Wk,Wv,Wr,Wo, WcatT3,WrThi,WrTlo,WoT);
  gemm_bf16  <<<dim3(24,16),       dim3(256),   0, stream>>>(Xhi, WcatT3, C1, 2048, 3072, 1024);
  gemm_bf16_3t<<<dim3(8,16),       dim3(256),   0, stream>>>(Xhi, Xlo, WrThi, WrTlo, R, 2048, 1024, 1024);
  fhead_k    <<<dim3(2048),        dim3(256),   0, stream>>>(hs, Wa, A_log, dtb, fh);
  postproc   <<<dim3(16384),       dim3(128),   0, stream>>>(C1, R, fh, qw, kw, Qd, Wt, Fd, Vd);
  chunk_sum  <<<dim3(512),         dim3(256),   0, stream>>>(Fd, Wt, Vd, dS, E);
  scan_k     <<<dim3(256),         dim3(256),   0, stream>>>(dS, E);
  chunk_out  <<<dim3(512),         dim3(256),   0, stream>>>(Qd, Wt, Fd, Vd, dS, Ob);
  gnorm_k    <<<dim3(2048),        dim3(256),   0, stream>>>(Ob, gw, On);
  gemm_bf16  <<<dim3(8,16),        dim3(256),   0, stream>>>(On, WoT, out, 2048, 1024, 1024);
}

// Round 3
// 297.820 us; speedup vs baseline: 1.1737x; 1.1626x over previous
//
#include <hip/hip_runtime.h>
#include <stdint.h>
#include <stddef.h>

#define H_ 8
#define T_ 1024

typedef __attribute__((ext_vector_type(8))) short s16x8;
typedef __attribute__((ext_vector_type(4))) float f32x4;
typedef __attribute__((ext_vector_type(16))) float f32x16;

static __device__ __forceinline__ unsigned short f2bf(float f){
  unsigned u = __float_as_uint(f);
  u += 0x7fffu + ((u >> 16) & 1u);          // round-to-nearest-even
  return (unsigned short)(u >> 16);
}
static __device__ __forceinline__ float bf2f(unsigned short b){
  return __uint_as_float(((unsigned)b) << 16);
}
static __device__ __forceinline__ unsigned int pack_hl(float x){
  unsigned short h = f2bf(x);
  unsigned short l = f2bf(x - bf2f(h));
  return ((unsigned int)h << 16) | l;
}
// async global->LDS 16B (m97 pattern)
static __device__ __forceinline__ void gl_lds16(const unsigned short* g, unsigned short* l){
  __builtin_amdgcn_global_load_lds((const __attribute__((address_space(1))) unsigned int*)g,
                                   (__attribute__((address_space(3))) unsigned int*)l,
                                   16, 0, 0);
}

// ---------------- cast hidden_states to bf16 hi + lo
__global__ void cast_hs(const float* __restrict__ X, unsigned short* __restrict__ hi,
                        unsigned short* __restrict__ lo){
  size_t idx = ((size_t)blockIdx.x * 256 + threadIdx.x) * 8;
  float4 a = *(const float4*)(X + idx);
  float4 b = *(const float4*)(X + idx + 4);
  float v[8] = {a.x,a.y,a.z,a.w,b.x,b.y,b.z,b.w};
  unsigned short hh[8], ll[8];
#pragma unroll
  for(int i=0;i<8;i++){ hh[i]=f2bf(v[i]); ll[i]=f2bf(v[i]-bf2f(hh[i])); }
  ushort4 h0,h1,l0,l1;
  h0.x=hh[0];h0.y=hh[1];h0.z=hh[2];h0.w=hh[3];
  h1.x=hh[4];h1.y=hh[5];h1.z=hh[6];h1.w=hh[7];
  l0.x=ll[0];l0.y=ll[1];l0.z=ll[2];l0.w=ll[3];
  l1.x=ll[4];l1.y=ll[5];l1.z=ll[6];l1.w=ll[7];
  *(ushort4*)&hi[idx]=h0; *(ushort4*)&hi[idx+4]=h1;
  *(ushort4*)&lo[idx]=l0; *(ushort4*)&lo[idx+4]=l1;
}

// ---------------- transpose+cast weights
__global__ void wtrans(const float* __restrict__ Wq, const float* __restrict__ Wk,
                       const float* __restrict__ Wv, const float* __restrict__ Wr,
                       const float* __restrict__ Wo,
                       unsigned short* __restrict__ WcatT3, unsigned short* __restrict__ WrThi,
                       unsigned short* __restrict__ WrTlo, unsigned short* __restrict__ WoT){
  __shared__ float tile[32][33];
  int z = blockIdx.z;
  const float* src = (z==0)?Wq:(z==1)?Wk:(z==2)?Wv:(z==3)?Wr:Wo;
  int c0 = blockIdx.x*32;
  int k0 = blockIdx.y*32;
  int tx = threadIdx.x, ty = threadIdx.y; // 32 x 8
#pragma unroll
  for(int r=0;r<32;r+=8)
    tile[ty+r][tx] = src[(size_t)(k0+ty+r)*1024 + c0 + tx];
  __syncthreads();
#pragma unroll
  for(int r=0;r<32;r+=8){
    int c = c0 + ty + r;
    int k = k0 + tx;
    float v = tile[tx][ty+r];
    if(z < 3){
      WcatT3[((size_t)(z*1024 + c))*1024 + k] = f2bf(v);
    } else if(z == 3){
      unsigned short hv = f2bf(v);
      WrThi[(size_t)c*1024 + k] = hv;
      WrTlo[(size_t)c*1024 + k] = f2bf(v - bf2f(hv));
    } else {
      WoT[(size_t)c*1024 + k] = f2bf(v);
    }
  }
}

// ---------------- fused proj + router GEMM, one full-GPU launch (512 blocks)
// blocks 0..383: C1[2048][3072] = Xhi @ WcatT3^T (K=1024)
// blocks 384..511: R[2048][1024] = Xhi@WrThi^T + Xhi@WrTlo^T + Xlo@WrThi^T (K-concat 3072)
__launch_bounds__(256)
__global__ void gemm_fused(const unsigned short* __restrict__ Xhi, const unsigned short* __restrict__ Xlo,
                           const unsigned short* __restrict__ WcatT3, const unsigned short* __restrict__ WrThi,
                           const unsigned short* __restrict__ WrTlo,
                           float* __restrict__ C1, float* __restrict__ R){
  __shared__ unsigned short As[128*32];
  __shared__ unsigned short Bs[128*32];
  int blk = blockIdx.x;
  bool router = (blk >= 384);
  int bx, by, N, nseg;
  float* Cout;
  if(!router){ bx = blk%24; by = blk/24; N = 3072; nseg = 1; Cout = C1; }
  else { int rb = blk-384; bx = rb%8; by = rb/8; N = 1024; nseg = 3; Cout = R; }
  int tid = threadIdx.x;
  int mBase = by*128, nBase = bx*128;
  int w = tid>>6, lane = tid&63, wr = w>>1, wc = w&1;
  int kg = lane>>4, l15 = lane&15;
  f32x4 acc[4][4];
#pragma unroll
  for(int i=0;i<4;i++)
#pragma unroll
    for(int j=0;j<4;j++) acc[i][j] = (f32x4){0.f,0.f,0.f,0.f};
  size_t aoff = (size_t)(mBase + (tid>>2))*1024 + (tid&3)*8;
  size_t boff = (size_t)(nBase + (tid>>2))*1024 + (tid&3)*8;
  for(int s=0; s<3; s++){
    if(s >= nseg) break;
    const unsigned short* Ap = (s==2) ? Xlo : Xhi;
    const unsigned short* Bp = router ? ((s==1) ? WrTlo : WrThi) : WcatT3;
    const unsigned short* gA = Ap + aoff;
    const unsigned short* gB = Bp + boff;
    for(int kb=0; kb<1024; kb+=32){
      gl_lds16(gA + kb,                    &As[tid*8]);
      gl_lds16(gA + (size_t)64*1024 + kb,  &As[2048 + tid*8]);
      gl_lds16(gB + kb,                    &Bs[tid*8]);
      gl_lds16(gB + (size_t)64*1024 + kb,  &Bs[2048 + tid*8]);
      __syncthreads();
      s16x8 afr[4], bfr[4];
#pragma unroll
      for(int f=0;f<4;f++){
        afr[f] = *(const s16x8*)&As[(wr*64 + f*16 + l15)*32 + kg*8];
        bfr[f] = *(const s16x8*)&Bs[(wc*64 + f*16 + l15)*32 + kg*8];
      }
#pragma unroll
      for(int fm=0;fm<4;fm++)
#pragma unroll
        for(int fn=0;fn<4;fn++)
          acc[fm][fn] = __builtin_amdgcn_mfma_f32_16x16x32_bf16(afr[fm], bfr[fn], acc[fm][fn], 0,0,0);
      __syncthreads();
    }
  }
#pragma unroll
  for(int fm=0;fm<4;fm++)
#pragma unroll
    for(int fn=0;fn<4;fn++){
      int col = nBase + wc*64 + fn*16 + l15;
      int row = mBase + wr*64 + fm*16 + kg*4;
#pragma unroll
      for(int r=0;r<4;r++) Cout[(size_t)(row+r)*N + col] = acc[fm][fn][r];
    }
}

// ---------------- plain bf16 MFMA GEMM (output GEMM)
__launch_bounds__(256)
__global__ void gemm_bf16(const unsigned short* __restrict__ A,
                          const unsigned short* __restrict__ BT,
                          float* __restrict__ C, int M, int N, int K){
  __shared__ unsigned short As[128*32];
  __shared__ unsigned short Bs[128*32];
  int tid = threadIdx.x;
  int mBase = blockIdx.y*128, nBase = blockIdx.x*128;
  int w = tid>>6, lane = tid&63, wr = w>>1, wc = w&1;
  int kg = lane>>4, l15 = lane&15;
  f32x4 acc[4][4];
#pragma unroll
  for(int i=0;i<4;i++)
#pragma unroll
    for(int j=0;j<4;j++) acc[i][j] = (f32x4){0.f,0.f,0.f,0.f};
  const unsigned short* gA = A + (size_t)(mBase + (tid>>2))*K + (tid&3)*8;
  const unsigned short* gB = BT + (size_t)(nBase + (tid>>2))*K + (tid&3)*8;
  for(int kb=0; kb<K; kb+=32){
    gl_lds16(gA + kb,                 &As[tid*8]);
    gl_lds16(gA + (size_t)64*K + kb,  &As[2048 + tid*8]);
    gl_lds16(gB + kb,                 &Bs[tid*8]);
    gl_lds16(gB + (size_t)64*K + kb,  &Bs[2048 + tid*8]);
    __syncthreads();
    s16x8 afr[4], bfr[4];
#pragma unroll
    for(int f=0;f<4;f++){
      afr[f] = *(const s16x8*)&As[(wr*64 + f*16 + l15)*32 + kg*8];
      bfr[f] = *(const s16x8*)&Bs[(wc*64 + f*16 + l15)*32 + kg*8];
    }
#pragma unroll
    for(int fm=0;fm<4;fm++)
#pragma unroll
      for(int fn=0;fn<4;fn++)
        acc[fm][fn] = __builtin_amdgcn_mfma_f32_16x16x32_bf16(afr[fm], bfr[fn], acc[fm][fn], 0,0,0);
    __syncthreads();
  }
#pragma unroll
  for(int fm=0;fm<4;fm++)
#pragma unroll
    for(int fn=0;fn<4;fn++){
      int col = nBase + wc*64 + fn*16 + l15;
      int row = mBase + wr*64 + fm*16 + kg*4;
#pragma unroll
      for(int r=0;r<4;r++) C[(size_t)(row+r)*N + col] = acc[fm][fn][r];
    }
}

// ---------------- f_head = -exp(A_log)*softplus(hs@Wa + dt_bias)
__global__ void fhead_k(const float* __restrict__ X, const float* __restrict__ Wa,
                        const float* __restrict__ A_log, const float* __restrict__ dtb,
                        float* __restrict__ fh){
  __shared__ float xs[1024];
  int n = blockIdx.x, tid = threadIdx.x;
  *(float4*)&xs[tid*4] = *(const float4*)&X[(size_t)n*1024 + tid*4];
  __syncthreads();
  int h = tid>>5, l = tid&31;
  float s = 0.f;
  for(int k=l;k<1024;k+=32) s += xs[k]*Wa[(size_t)k*8 + h];
  s += __shfl_xor(s,1); s += __shfl_xor(s,2); s += __shfl_xor(s,4);
  s += __shfl_xor(s,8); s += __shfl_xor(s,16);
  if(l==0){
    float z = s + dtb[h];
    float sp = (z > 20.f) ? z : log1pf(expf(z));
    fh[(size_t)n*8 + h] = -expf(A_log[h]) * sp;
  }
}

// ---------------- per-(token,head) postproc
__launch_bounds__(128)
__global__ void postproc(const float* __restrict__ C1, const float* __restrict__ R,
                         const float* __restrict__ fh, const float* __restrict__ qw,
                         const float* __restrict__ kw,
                         float* __restrict__ Qd, float* __restrict__ Wt,
                         float* __restrict__ Fd, float* __restrict__ Vd){
  __shared__ float sc[128];
  __shared__ float red[2];
  int blk = blockIdx.x;
  int n = blk>>3, h = blk&7;
  int i = threadIdx.x;
  int b = n>>10, t = n&1023;
  size_t base = ((size_t)(b*H_ + h)*T_ + t)*128 + i;
  size_t cb = (size_t)n*3072;
  float qraw = C1[cb + h*128 + i];
  float kraw = C1[cb + 1024 + h*128 + i];
  float vraw = C1[cb + 2048 + h*128 + i];
  float rlog = R[(size_t)n*1024 + h*128 + i];
  float qs = qraw/(1.f+expf(-qraw));
  float ks = kraw/(1.f+expf(-kraw));
  float vv = vraw/(1.f+expf(-vraw));
  float si = 1.f/(1.f+expf(-rlog));
  sc[i] = si;
  __syncthreads();
  int cnt = 0;
#pragma unroll 8
  for(int j4=0;j4<128;j4+=4){
    float4 s4 = *(const float4*)&sc[j4];
    cnt += (s4.x>si) || (s4.x==si && (j4+0)<i);
    cnt += (s4.y>si) || (s4.y==si && (j4+1)<i);
    cnt += (s4.z>si) || (s4.z==si && (j4+2)<i);
    cnt += (s4.w>si) || (s4.w==si && (j4+3)<i);
  }
  bool sel = cnt < 32;   // stable top-32, matches lax.top_k
  float x;
  x = qs*qs;
  x+=__shfl_xor(x,1);x+=__shfl_xor(x,2);x+=__shfl_xor(x,4);x+=__shfl_xor(x,8);x+=__shfl_xor(x,16);x+=__shfl_xor(x,32);
  __syncthreads(); if((i&63)==0) red[i>>6]=x; __syncthreads();
  float qn = qs * rsqrtf((red[0]+red[1])/128.f + 1e-5f) * qw[i];
  x = ks*ks;
  x+=__shfl_xor(x,1);x+=__shfl_xor(x,2);x+=__shfl_xor(x,4);x+=__shfl_xor(x,8);x+=__shfl_xor(x,16);x+=__shfl_xor(x,32);
  __syncthreads(); if((i&63)==0) red[i>>6]=x; __syncthreads();
  float kn = ks * rsqrtf((red[0]+red[1])/128.f + 1e-5f) * kw[i];
  x = sel ? si : 0.f;
  x+=__shfl_xor(x,1);x+=__shfl_xor(x,2);x+=__shfl_xor(x,4);x+=__shfl_xor(x,8);x+=__shfl_xor(x,16);x+=__shfl_xor(x,32);
  __syncthreads(); if((i&63)==0) red[i>>6]=x; __syncthreads();
  float wsum = red[0]+red[1];
  float wgt = sel ? si/(wsum + 1e-9f) : 0.f;
  float f = fh[(size_t)n*8 + h] * wgt;
  Qd[base] = qn;
  Wt[base] = (1.f - expf(f)) * kn;
  Fd[base] = f;
  Vd[base] = vv;
}

// ---------------- phase 1: per chunk: cumsum F in-place, E, dS^T = (Khat^T V)^T
// NOTE: emits TRANSPOSED chunk summaries dS_T[j(vdim)][i(kdim)] so downstream
// fragments need no transpose.
__launch_bounds__(256)
__global__ void chunk_sum(float* __restrict__ Fd, const float* __restrict__ Wt,
                          const float* __restrict__ Vd, float* __restrict__ dS,
                          float* __restrict__ E){
  __shared__ float Fc[32][132];
  __shared__ float Kh[32][132];
  int blk = blockIdx.x, bh = blk>>5, c = blk&31;
  int tid = threadIdx.x;
  int w = tid>>6, lane = tid&63;
  size_t fbase = ((size_t)bh*T_ + (size_t)c*32)*128;
#pragma unroll
  for(int v=0; v<4; v++){
    int e = v*1024 + tid*4;
    int t2 = e>>7, i0 = e&127;
    float4 f4 = *(const float4*)&Fd[fbase + e];
    *(float4*)&Fc[t2][i0] = f4;
  }
  __syncthreads();
  if(tid < 128){
    float a = 0.f;
    for(int t2=0;t2<32;t2++){ a += Fc[t2][tid]; Fc[t2][tid] = a; }
  }
  __syncthreads();
#pragma unroll
  for(int v=0; v<4; v++){
    int e = v*1024 + tid*4;
    int t2 = e>>7, i0 = e&127;
    float4 fc4 = *(const float4*)&Fc[t2][i0];
    *(float4*)&Fd[fbase + e] = fc4;
    float4 ft  = *(const float4*)&Fc[31][i0];
    float4 w4  = *(const float4*)&Wt[fbase + e];
    float4 kh;
    kh.x = w4.x * expf(ft.x - fc4.x);
    kh.y = w4.y * expf(ft.y - fc4.y);
    kh.z = w4.z * expf(ft.z - fc4.z);
    kh.w = w4.w * expf(ft.w - fc4.w);
    *(float4*)&Kh[t2][i0] = kh;
  }
  if(tid < 128) E[((size_t)bh*32 + c)*128 + tid] = expf(Fc[31][tid]);
  __syncthreads();
  int ig = lane>>3, jg = lane&7;
  const float* Vp = Vd + fbase;
  f32x4 acc[4][4];
#pragma unroll
  for(int a=0;a<4;a++)
#pragma unroll
    for(int q=0;q<4;q++) acc[a][q] = (f32x4){0.f,0.f,0.f,0.f};
#pragma unroll 4
  for(int t2=0;t2<32;t2++){
    float4 kq = *(const float4*)&Kh[t2][w*32 + ig*4];
    float4 v0 = *(const float4*)&Vp[t2*128 + jg*4];
    float4 v1 = *(const float4*)&Vp[t2*128 + jg*4 + 32];
    float4 v2 = *(const float4*)&Vp[t2*128 + jg*4 + 64];
    float4 v3 = *(const float4*)&Vp[t2*128 + jg*4 + 96];
    float kk[4] = {kq.x,kq.y,kq.z,kq.w};
#pragma unroll
    for(int a=0;a<4;a++){
      acc[a][0] += kk[a]*(f32x4){v0.x,v0.y,v0.z,v0.w};
      acc[a][1] += kk[a]*(f32x4){v1.x,v1.y,v1.z,v1.w};
      acc[a][2] += kk[a]*(f32x4){v2.x,v2.y,v2.z,v2.w};
      acc[a][3] += kk[a]*(f32x4){v3.x,v3.y,v3.z,v3.w};
    }
  }
  // transpose-write: dS_T[j][i], i = w*32+ig*4+a (kdim), j = jg*4+32q+jj (vdim)
  size_t dbase = (size_t)blk*16384;
#pragma unroll
  for(int q=0;q<4;q++)
#pragma unroll
    for(int jj=0;jj<4;jj++){
      float4 o4 = make_float4(acc[0][q][jj],acc[1][q][jj],acc[2][q][jj],acc[3][q][jj]);
      *(float4*)&dS[dbase + (size_t)(jg*4 + 32*q + jj)*128 + w*32 + ig*4] = o4;
    }
}

// ---------------- phase 2: inter-chunk scan on dS_T; becomes S_T at chunk start
__global__ void scan_k(float* __restrict__ dS, const float* __restrict__ E){
  int g = blockIdx.x*256 + threadIdx.x;   // 65536 threads: (bh, float4 idx)
  int bh = g>>12;
  int e4 = (g&4095)*4;
  int i0 = e4 & 127;                      // kdim (decay index), 4 consecutive
  float4 S = make_float4(0.f,0.f,0.f,0.f);
  for(int c=0;c<32;c++){
    size_t off = ((size_t)(bh*32 + c))*16384 + e4;
    float4 d   = *(const float4*)&dS[off];
    float4 Ec  = *(const float4*)&E[((size_t)(bh*32 + c))*128 + i0];
    *(float4*)&dS[off] = S;
    S.x = Ec.x*S.x + d.x;
    S.y = Ec.y*S.y + d.y;
    S.z = Ec.z*S.z + d.z;
    S.w = Ec.w*S.w + d.w;
  }
}

// ---------------- phase 3: O = qt @ S + tril(qt kt^T) @ V, full MFMA
__launch_bounds__(256)
__global__ void chunk_out(const float* __restrict__ Qd, const float* __restrict__ Wt,
                          const float* __restrict__ Fd, const float* __restrict__ Vd,
                          const float* __restrict__ ST, float* __restrict__ O){
  __shared__ unsigned int qtP[32][132];   // packed bf16 hi|lo, [tok][k]
  __shared__ unsigned int ktP[32][132];
  __shared__ unsigned int Vt[128][36];    // packed, [vdim][tok]
  __shared__ float Amat[32][40];          // tril(qt kt^T), f32
  int blk = blockIdx.x, bh = blk>>5, c = blk&31;
  int b = bh>>3, h = bh&7;
  int tid = threadIdx.x, w = tid>>6, lane = tid&63;
  int m = lane&31, hi = lane>>5;
  size_t fbase = ((size_t)bh*T_ + (size_t)c*32)*128;
  // prep qtP / ktP
#pragma unroll
  for(int p=0;p<4;p++){
    int e = p*1024 + tid*4;
    int t2 = e>>7, i0 = e&127;
    float4 f4 = *(const float4*)&Fd[fbase + e];
    float4 q4 = *(const float4*)&Qd[fbase + e];
    float4 w4 = *(const float4*)&Wt[fbase + e];
    float fv[4] = {f4.x,f4.y,f4.z,f4.w};
    float qv[4] = {q4.x,q4.y,q4.z,q4.w};
    float wv[4] = {w4.x,w4.y,w4.z,w4.w};
    uint4 qp, kp;
    unsigned int qa[4], ka[4];
#pragma unroll
    for(int j=0;j<4;j++){
      float ef = expf(fv[j]);
      qa[j] = pack_hl(qv[j]*ef);
      ka[j] = pack_hl(wv[j]/ef);
    }
    qp.x=qa[0]; qp.y=qa[1]; qp.z=qa[2]; qp.w=qa[3];
    kp.x=ka[0]; kp.y=ka[1]; kp.z=ka[2]; kp.w=ka[3];
    *(uint4*)&qtP[t2][i0] = qp;
    *(uint4*)&ktP[t2][i0] = kp;
  }
  // prep Vt (transposed V, packed): thread reads column n over 16 tokens
  {
    int n = tid&127, th = (tid>>7)*16;
    unsigned int vp[16];
#pragma unroll
    for(int j=0;j<16;j++) vp[j] = pack_hl(Vd[fbase + (size_t)(th+j)*128 + n]);
#pragma unroll
    for(int j=0;j<16;j+=4){
      uint4 v4; v4.x=vp[j]; v4.y=vp[j+1]; v4.z=vp[j+2]; v4.w=vp[j+3];
      *(uint4*)&Vt[n][th+j] = v4;
    }
  }
  __syncthreads();
  // wave 0: Amat = tril(qt @ kt^T) via 24 MFMA
  if(w == 0){
    f32x16 am;
#pragma unroll
    for(int r=0;r<16;r++) am[r] = 0.f;
#pragma unroll
    for(int s=0;s<8;s++){
      int ko = s*16 + hi*8;
      uint4 qa = *(const uint4*)&qtP[m][ko];
      uint4 qb = *(const uint4*)&qtP[m][ko+4];
      uint4 ka = *(const uint4*)&ktP[m][ko];
      uint4 kb = *(const uint4*)&ktP[m][ko+4];
      s16x8 qh, ql, kh, kl;
      unsigned int qw_[8] = {qa.x,qa.y,qa.z,qa.w,qb.x,qb.y,qb.z,qb.w};
      unsigned int kw_[8] = {ka.x,ka.y,ka.z,ka.w,kb.x,kb.y,kb.z,kb.w};
#pragma unroll
      for(int j=0;j<8;j++){
        qh[j]=(short)(qw_[j]>>16); ql[j]=(short)(qw_[j]&0xffff);
        kh[j]=(short)(kw_[j]>>16); kl[j]=(short)(kw_[j]&0xffff);
      }
      am = __builtin_amdgcn_mfma_f32_32x32x16_bf16(qh, kh, am, 0,0,0);
      am = __builtin_amdgcn_mfma_f32_32x32x16_bf16(qh, kl, am, 0,0,0);
      am = __builtin_amdgcn_mfma_f32_32x32x16_bf16(ql, kh, am, 0,0,0);
    }
#pragma unroll
    for(int r=0;r<16;r++){
      int rm = (r&3) + 8*(r>>2) + 4*hi;   // token row
      Amat[rm][m] = (m <= rm) ? am[r] : 0.f;   // m = u (slot col)
    }
  }
  // qt @ S: all waves; wave w covers output cols n = w*32 + m
  f32x16 oacc;
#pragma unroll
  for(int r=0;r<16;r++) oacc[r] = 0.f;
  const float* Sp = ST + (size_t)blk*16384 + (size_t)(w*32 + m)*128;
#pragma unroll
  for(int s=0;s<8;s++){
    int ko = s*16 + hi*8;
    uint4 qa = *(const uint4*)&qtP[m][ko];
    uint4 qb = *(const uint4*)&qtP[m][ko+4];
    s16x8 qh, ql;
    unsigned int qw_[8] = {qa.x,qa.y,qa.z,qa.w,qb.x,qb.y,qb.z,qb.w};
#pragma unroll
    for(int j=0;j<8;j++){ qh[j]=(short)(qw_[j]>>16); ql[j]=(short)(qw_[j]&0xffff); }
    float4 s0 = *(const float4*)&Sp[ko];
    float4 s1 = *(const float4*)&Sp[ko+4];
    float sv[8] = {s0.x,s0.y,s0.z,s0.w,s1.x,s1.y,s1.z,s1.w};
    s16x8 sh, sl;
#pragma unroll
    for(int j=0;j<8;j++){
      unsigned short hh = f2bf(sv[j]);
      sh[j] = (short)hh; sl[j] = (short)f2bf(sv[j]-bf2f(hh));
    }
    oacc = __builtin_amdgcn_mfma_f32_32x32x16_bf16(qh, sh, oacc, 0,0,0);
    oacc = __builtin_amdgcn_mfma_f32_32x32x16_bf16(qh, sl, oacc, 0,0,0);
    oacc = __builtin_amdgcn_mfma_f32_32x32x16_bf16(ql, sh, oacc, 0,0,0);
  }
  __syncthreads();   // Amat ready
  // + tril(qt kt^T) @ V : K=32 (2 steps)
#pragma unroll
  for(int s=0;s<2;s++){
    int uo = s*16 + hi*8;
    float4 a0 = *(const float4*)&Amat[m][uo];
    float4 a1 = *(const float4*)&Amat[m][uo+4];
    float av[8] = {a0.x,a0.y,a0.z,a0.w,a1.x,a1.y,a1.z,a1.w};
    s16x8 ah, al;
#pragma unroll
    for(int j=0;j<8;j++){
      unsigned short hh = f2bf(av[j]);
      ah[j] = (short)hh; al[j] = (short)f2bf(av[j]-bf2f(hh));
    }
    uint4 v0 = *(const uint4*)&Vt[w*32 + m][uo];
    uint4 v1 = *(const uint4*)&Vt[w*32 + m][uo+4];
    unsigned int vw[8] = {v0.x,v0.y,v0.z,v0.w,v1.x,v1.y,v1.z,v1.w};
    s16x8 vh, vl;
#pragma unroll
    for(int j=0;j<8;j++){ vh[j]=(short)(vw[j]>>16); vl[j]=(short)(vw[j]&0xffff); }
    oacc = __builtin_amdgcn_mfma_f32_32x32x16_bf16(ah, vh, oacc, 0,0,0);
    oacc = __builtin_amdgcn_mfma_f32_32x32x16_bf16(ah, vl, oacc, 0,0,0);
    oacc = __builtin_amdgcn_mfma_f32_32x32x16_bf16(al, vh, oacc, 0,0,0);
  }
  // epilogue
#pragma unroll
  for(int r=0;r<16;r++){
    int tok = (r&3) + 8*(r>>2) + 4*hi;
    O[((size_t)(b*T_ + c*32 + tok))*1024 + h*128 + w*32 + m] = oacc[r];
  }
}

// ---------------- final g-RMSNorm + cast bf16
__global__ void gnorm_k(const float* __restrict__ Ob, const float* __restrict__ gw,
                        unsigned short* __restrict__ On){
  __shared__ float red[4];
  int n = blockIdx.x, tid = threadIdx.x;
  size_t base = (size_t)n*1024 + tid*4;
  float4 x = *(const float4*)&Ob[base];
  float ss = x.x*x.x + x.y*x.y + x.z*x.z + x.w*x.w;
  ss+=__shfl_xor(ss,1);ss+=__shfl_xor(ss,2);ss+=__shfl_xor(ss,4);
  ss+=__shfl_xor(ss,8);ss+=__shfl_xor(ss,16);ss+=__shfl_xor(ss,32);
  if((tid&63)==0) red[tid>>6]=ss;
  __syncthreads();
  float sc = rsqrtf((red[0]+red[1]+red[2]+red[3])/1024.f + 1e-5f);
  float4 g = *(const float4*)&gw[tid*4];
  ushort4 o4;
  o4.x=f2bf(x.x*sc*g.x); o4.y=f2bf(x.y*sc*g.y);
  o4.z=f2bf(x.z*sc*g.z); o4.w=f2bf(x.w*sc*g.w);
  *(ushort4*)&On[base]=o4;
}

extern "C" void kernel_launch(void* const* d_in, const int* in_sizes, int n_in,
                              void* d_out, int out_size, void* d_ws, size_t ws_size,
                              hipStream_t stream){
  const float* hs   = (const float*)d_in[0];
  const float* Wq   = (const float*)d_in[1];
  const float* Wk   = (const float*)d_in[2];
  const float* Wv   = (const float*)d_in[3];
  const float* Wr   = (const float*)d_in[4];
  const float* Wa   = (const float*)d_in[5];
  const float* A_log= (const float*)d_in[6];
  const float* dtb  = (const float*)d_in[7];
  const float* qw   = (const float*)d_in[8];
  const float* kw   = (const float*)d_in[9];
  const float* gw   = (const float*)d_in[10];
  const float* Wo   = (const float*)d_in[11];
  float* out = (float*)d_out;

  char* wsp = (char*)d_ws;
  size_t off = 0;
  auto alloc = [&](size_t bytes)->void*{ void* p = wsp + off; off += (bytes + 255) & ~(size_t)255; return p; };
  unsigned short* Xhi    = (unsigned short*)alloc(2048ull*1024*2);
  unsigned short* Xlo    = (unsigned short*)alloc(2048ull*1024*2);
  unsigned short* WcatT3 = (unsigned short*)alloc(3072ull*1024*2);
  unsigned short* WrThi  = (unsigned short*)alloc(1024ull*1024*2);
  unsigned short* WrTlo  = (unsigned short*)alloc(1024ull*1024*2);
  unsigned short* WoT    = (unsigned short*)alloc(1024ull*1024*2);
  float* C1 = (float*)alloc(2048ull*3072*4);
  float* R  = (float*)alloc(2048ull*1024*4);
  float* fh = (float*)alloc(2048ull*8*4);
  float* Qd = (float*)alloc(16ull*1024*128*4);
  float* Wt = (float*)alloc(16ull*1024*128*4);
  float* Fd = (float*)alloc(16ull*1024*128*4);
  float* Vd = (float*)alloc(16ull*1024*128*4);
  float* E  = (float*)alloc(16ull*32*128*4);
  float* dS = (float*)alloc(16ull*32*16384*4);
  float* Ob = (float*)alloc(2048ull*1024*4);
  unsigned short* On = (unsigned short*)alloc(2048ull*1024*2);
  (void)ws_size; (void)in_sizes; (void)n_in; (void)out_size;

  cast_hs    <<<dim3(1024),        dim3(256),   0, stream>>>(hs, Xhi, Xlo);
  wtrans     <<<dim3(32,32,5),     dim3(32,8),  0, stream>>>(Wq,Wk,Wv,Wr,Wo, WcatT3,WrThi,WrTlo,WoT);
  gemm_fused <<<dim3(512),         dim3(256),   0, stream>>>(Xhi, Xlo, WcatT3, WrThi, WrTlo, C1, R);
  fhead_k    <<<dim3(2048),        dim3(256),   0, stream>>>(hs, Wa, A_log, dtb, fh);
  postproc   <<<dim3(16384),       dim3(128),   0, stream>>>(C1, R, fh, qw, kw, Qd, Wt, Fd, Vd);
  chunk_sum  <<<dim3(512),         dim3(256),   0, stream>>>(Fd, Wt, Vd, dS, E);
  scan_k     <<<dim3(256),         dim3(256),   0, stream>>>(dS, E);
  chunk_out  <<<dim3(512),         dim3(256),   0, stream>>>(Qd, Wt, Fd, Vd, dS, Ob);
  gnorm_k    <<<dim3(2048),        dim3(256),   0, stream>>>(Ob, gw, On);
  gemm_bf16  <<<dim3(8,16),        dim3(256),   0, stream>>>(On, WoT, out, 2048, 1024, 1024);
}

// Round 4
// 264.198 us; speedup vs baseline: 1.3231x; 1.1273x over previous
//
#include <hip/hip_runtime.h>
#include <stdint.h>
#include <stddef.h>

#define H_ 8
#define T_ 1024

typedef __attribute__((ext_vector_type(8))) short s16x8;
typedef __attribute__((ext_vector_type(4))) float f32x4;
typedef __attribute__((ext_vector_type(16))) float f32x16;

static __device__ __forceinline__ unsigned short f2bf(float f){
  unsigned u = __float_as_uint(f);
  u += 0x7fffu + ((u >> 16) & 1u);          // round-to-nearest-even
  return (unsigned short)(u >> 16);
}
static __device__ __forceinline__ float bf2f(unsigned short b){
  return __uint_as_float(((unsigned)b) << 16);
}
static __device__ __forceinline__ unsigned int pack_hl(float x){
  unsigned short h = f2bf(x);
  unsigned short l = f2bf(x - bf2f(h));
  return ((unsigned int)h << 16) | l;
}
// async global->LDS 16B (m97 pattern)
static __device__ __forceinline__ void gl_lds16(const unsigned short* g, unsigned short* l){
  __builtin_amdgcn_global_load_lds((const __attribute__((address_space(1))) unsigned int*)g,
                                   (__attribute__((address_space(3))) unsigned int*)l,
                                   16, 0, 0);
}

// ---------------- prep: cast hs to bf16 hi+lo AND f_head (fused, both read hs row)
__global__ void prep_k(const float* __restrict__ X, const float* __restrict__ Wa,
                       const float* __restrict__ A_log, const float* __restrict__ dtb,
                       unsigned short* __restrict__ hi, unsigned short* __restrict__ lo,
                       float* __restrict__ fh){
  __shared__ float xs[1024];
  int n = blockIdx.x, tid = threadIdx.x;   // 256 threads
  size_t base = (size_t)n*1024 + tid*4;
  float4 x = *(const float4*)&X[base];
  *(float4*)&xs[tid*4] = x;
  float v[4] = {x.x,x.y,x.z,x.w};
  ushort4 h4, l4;
  unsigned short hh[4], ll[4];
#pragma unroll
  for(int j=0;j<4;j++){ hh[j]=f2bf(v[j]); ll[j]=f2bf(v[j]-bf2f(hh[j])); }
  h4.x=hh[0];h4.y=hh[1];h4.z=hh[2];h4.w=hh[3];
  l4.x=ll[0];l4.y=ll[1];l4.z=ll[2];l4.w=ll[3];
  *(ushort4*)&hi[base] = h4;
  *(ushort4*)&lo[base] = l4;
  __syncthreads();
  int h = tid>>5, l = tid&31;
  float s = 0.f;
  for(int k=l;k<1024;k+=32) s += xs[k]*Wa[(size_t)k*8 + h];
  s += __shfl_xor(s,1); s += __shfl_xor(s,2); s += __shfl_xor(s,4);
  s += __shfl_xor(s,8); s += __shfl_xor(s,16);
  if(l==0){
    float z = s + dtb[h];
    float sp = (z > 20.f) ? z : log1pf(expf(z));
    fh[(size_t)n*8 + h] = -expf(A_log[h]) * sp;
  }
}

// ---------------- transpose+cast weights
__global__ void wtrans(const float* __restrict__ Wq, const float* __restrict__ Wk,
                       const float* __restrict__ Wv, const float* __restrict__ Wr,
                       const float* __restrict__ Wo,
                       unsigned short* __restrict__ WcatT3, unsigned short* __restrict__ WrThi,
                       unsigned short* __restrict__ WrTlo, unsigned short* __restrict__ WoT){
  __shared__ float tile[32][33];
  int z = blockIdx.z;
  const float* src = (z==0)?Wq:(z==1)?Wk:(z==2)?Wv:(z==3)?Wr:Wo;
  int c0 = blockIdx.x*32;
  int k0 = blockIdx.y*32;
  int tx = threadIdx.x, ty = threadIdx.y; // 32 x 8
#pragma unroll
  for(int r=0;r<32;r+=8)
    tile[ty+r][tx] = src[(size_t)(k0+ty+r)*1024 + c0 + tx];
  __syncthreads();
#pragma unroll
  for(int r=0;r<32;r+=8){
    int c = c0 + ty + r;
    int k = k0 + tx;
    float v = tile[tx][ty+r];
    if(z < 3){
      WcatT3[((size_t)(z*1024 + c))*1024 + k] = f2bf(v);
    } else if(z == 3){
      unsigned short hv = f2bf(v);
      WrThi[(size_t)c*1024 + k] = hv;
      WrTlo[(size_t)c*1024 + k] = f2bf(v - bf2f(hv));
    } else {
      WoT[(size_t)c*1024 + k] = f2bf(v);
    }
  }
}

// ---------------- fused proj + router GEMM, 768 UNIFORM blocks (K=1024 each)
// logical blocks 0..383: C1[2048][3072] = Xhi @ WcatT3^T
// logical blocks 384..767: router seg s=0..2 -> Rp[s][2048][1024] partials
//   (s0: Xhi@WrThi^T, s1: Xhi@WrTlo^T, s2: Xlo@WrThi^T)
// LDS source-pre-swizzle: chunk c stored at c^((row>>1)&3); reads XOR the same.
__launch_bounds__(256)
__global__ void gemm_fused(const unsigned short* __restrict__ Xhi, const unsigned short* __restrict__ Xlo,
                           const unsigned short* __restrict__ WcatT3, const unsigned short* __restrict__ WrThi,
                           const unsigned short* __restrict__ WrTlo,
                           float* __restrict__ C1, float* __restrict__ Rp){
  __shared__ unsigned short As[128*32];
  __shared__ unsigned short Bs[128*32];
  int bid = blockIdx.x;
  int blk = (bid&7)*96 + (bid>>3);        // XCD-contiguous chunks (768%8==0, bijective)
  const unsigned short *Ap, *Bp;
  float* Cout;
  int bx, by, N;
  if(blk < 384){
    bx = blk%24; by = blk/24; N = 3072;
    Ap = Xhi; Bp = WcatT3; Cout = C1;
  } else {
    int rb = blk-384;
    int seg = rb>>7, t = rb&127;
    bx = t&7; by = t>>3; N = 1024;
    Ap = (seg==2) ? Xlo : Xhi;
    Bp = (seg==1) ? WrTlo : WrThi;
    Cout = Rp + (size_t)seg*2048*1024;
  }
  int tid = threadIdx.x;
  int mBase = by*128, nBase = bx*128;
  int w = tid>>6, lane = tid&63, wr = w>>1, wc = w&1;
  int kg = lane>>4, l15 = lane&15;
  f32x4 acc[4][4];
#pragma unroll
  for(int i=0;i<4;i++)
#pragma unroll
    for(int j=0;j<4;j++) acc[i][j] = (f32x4){0.f,0.f,0.f,0.f};
  int srow = tid>>2, scc = (tid&3) ^ ((srow>>1)&3);
  const unsigned short* gA = Ap + (size_t)(mBase + srow)*1024 + scc*8;
  const unsigned short* gB = Bp + (size_t)(nBase + srow)*1024 + scc*8;
  for(int kb=0; kb<1024; kb+=32){
    gl_lds16(gA + kb,                    &As[tid*8]);
    gl_lds16(gA + (size_t)64*1024 + kb,  &As[2048 + tid*8]);
    gl_lds16(gB + kb,                    &Bs[tid*8]);
    gl_lds16(gB + (size_t)64*1024 + kb,  &Bs[2048 + tid*8]);
    __syncthreads();
    s16x8 afr[4], bfr[4];
#pragma unroll
    for(int f=0;f<4;f++){
      int r = f*16 + l15;
      int xr = (kg ^ ((r>>1)&3))*8;
      afr[f] = *(const s16x8*)&As[(wr*64 + r)*32 + xr];
      bfr[f] = *(const s16x8*)&Bs[(wc*64 + r)*32 + xr];
    }
#pragma unroll
    for(int fm=0;fm<4;fm++)
#pragma unroll
      for(int fn=0;fn<4;fn++)
        acc[fm][fn] = __builtin_amdgcn_mfma_f32_16x16x32_bf16(afr[fm], bfr[fn], acc[fm][fn], 0,0,0);
    __syncthreads();
  }
#pragma unroll
  for(int fm=0;fm<4;fm++)
#pragma unroll
    for(int fn=0;fn<4;fn++){
      int col = nBase + wc*64 + fn*16 + l15;
      int row = mBase + wr*64 + fm*16 + kg*4;
#pragma unroll
      for(int r=0;r<4;r++) Cout[(size_t)(row+r)*N + col] = acc[fm][fn][r];
    }
}

// ---------------- output GEMM: 128x64 tiles, 256 blocks (M=2048,N=1024,K=1024)
__launch_bounds__(256)
__global__ void gemm_out(const unsigned short* __restrict__ A,
                         const unsigned short* __restrict__ BT,
                         float* __restrict__ C){
  __shared__ unsigned short As[128*32];
  __shared__ unsigned short Bs[64*32];
  const int K = 1024, N = 1024;
  int tid = threadIdx.x;
  int mBase = blockIdx.y*128, nBase = blockIdx.x*64;
  int w = tid>>6, lane = tid&63;
  int mh = w>>1, nh = w&1;
  int kg = lane>>4, l15 = lane&15;
  f32x4 acc[4][2];
#pragma unroll
  for(int i=0;i<4;i++)
#pragma unroll
    for(int j=0;j<2;j++) acc[i][j] = (f32x4){0.f,0.f,0.f,0.f};
  int srow = tid>>2, scc = (tid&3) ^ ((srow>>1)&3);
  const unsigned short* gA = A  + (size_t)(mBase + srow)*K + scc*8;
  const unsigned short* gB = BT + (size_t)(nBase + srow)*K + scc*8;
  for(int kb=0; kb<K; kb+=32){
    gl_lds16(gA + kb,              &As[tid*8]);
    gl_lds16(gA + (size_t)64*K + kb, &As[2048 + tid*8]);
    gl_lds16(gB + kb,              &Bs[tid*8]);
    __syncthreads();
    s16x8 afr[4], bfr[2];
#pragma unroll
    for(int f=0;f<4;f++){
      int r = f*16 + l15;
      afr[f] = *(const s16x8*)&As[(mh*64 + r)*32 + (kg ^ ((r>>1)&3))*8];
    }
#pragma unroll
    for(int f=0;f<2;f++){
      int r = f*16 + l15;
      bfr[f] = *(const s16x8*)&Bs[(nh*32 + r)*32 + (kg ^ ((r>>1)&3))*8];
    }
#pragma unroll
    for(int fm=0;fm<4;fm++)
#pragma unroll
      for(int fn=0;fn<2;fn++)
        acc[fm][fn] = __builtin_amdgcn_mfma_f32_16x16x32_bf16(afr[fm], bfr[fn], acc[fm][fn], 0,0,0);
    __syncthreads();
  }
#pragma unroll
  for(int fm=0;fm<4;fm++)
#pragma unroll
    for(int fn=0;fn<2;fn++){
      int col = nBase + nh*32 + fn*16 + l15;
      int row = mBase + mh*64 + fm*16 + kg*4;
#pragma unroll
      for(int r=0;r<4;r++) C[(size_t)(row+r)*N + col] = acc[fm][fn][r];
    }
}

// ---------------- per-(token,head) postproc; 64-bit-key exact top-32 ranking
__launch_bounds__(128)
__global__ void postproc(const float* __restrict__ C1, const float* __restrict__ Rp,
                         const float* __restrict__ fh, const float* __restrict__ qw,
                         const float* __restrict__ kw,
                         float* __restrict__ Qd, float* __restrict__ Wt,
                         float* __restrict__ Fd, float* __restrict__ Vd){
  __shared__ unsigned long long keys[128];
  __shared__ float red[2];
  int blk = blockIdx.x;
  int n = blk>>3, h = blk&7;
  int i = threadIdx.x;
  int b = n>>10, t = n&1023;
  size_t base = ((size_t)(b*H_ + h)*T_ + t)*128 + i;
  size_t cb = (size_t)n*3072;
  size_t rb = (size_t)n*1024 + h*128 + i;
  float qraw = C1[cb + h*128 + i];
  float kraw = C1[cb + 1024 + h*128 + i];
  float vraw = C1[cb + 2048 + h*128 + i];
  float rlog = Rp[rb] + Rp[2048ull*1024 + rb] + Rp[2ull*2048*1024 + rb];
  float qs = qraw/(1.f+expf(-qraw));
  float ks = kraw/(1.f+expf(-kraw));
  float vv = vraw/(1.f+expf(-vraw));
  float si = 1.f/(1.f+expf(-rlog));
  // key: score bits (positive float -> monotone) then tie-break lower index wins
  unsigned long long ki = (((unsigned long long)__float_as_uint(si)) << 7) | (unsigned)(127 - i);
  keys[i] = ki;
  __syncthreads();
  int cnt = 0;
#pragma unroll 8
  for(int j=0;j<128;j+=2){
    ulonglong2 k2 = *(const ulonglong2*)&keys[j];
    cnt += (k2.x > ki);
    cnt += (k2.y > ki);
  }
  bool sel = cnt < 32;   // exact stable top-32 (ties -> lower index), matches lax.top_k
  float x;
  x = qs*qs;
  x+=__shfl_xor(x,1);x+=__shfl_xor(x,2);x+=__shfl_xor(x,4);x+=__shfl_xor(x,8);x+=__shfl_xor(x,16);x+=__shfl_xor(x,32);
  __syncthreads(); if((i&63)==0) red[i>>6]=x; __syncthreads();
  float qn = qs * rsqrtf((red[0]+red[1])/128.f + 1e-5f) * qw[i];
  x = ks*ks;
  x+=__shfl_xor(x,1);x+=__shfl_xor(x,2);x+=__shfl_xor(x,4);x+=__shfl_xor(x,8);x+=__shfl_xor(x,16);x+=__shfl_xor(x,32);
  __syncthreads(); if((i&63)==0) red[i>>6]=x; __syncthreads();
  float kn = ks * rsqrtf((red[0]+red[1])/128.f + 1e-5f) * kw[i];
  x = sel ? si : 0.f;
  x+=__shfl_xor(x,1);x+=__shfl_xor(x,2);x+=__shfl_xor(x,4);x+=__shfl_xor(x,8);x+=__shfl_xor(x,16);x+=__shfl_xor(x,32);
  __syncthreads(); if((i&63)==0) red[i>>6]=x; __syncthreads();
  float wsum = red[0]+red[1];
  float wgt = sel ? si/(wsum + 1e-9f) : 0.f;
  float f = fh[(size_t)n*8 + h] * wgt;
  Qd[base] = qn;
  Wt[base] = (1.f - expf(f)) * kn;
  Fd[base] = f;
  Vd[base] = vv;
}

// ---------------- phase 1: per chunk: cumsum F in-place, E, dS^T = (Khat^T V)^T
__launch_bounds__(256)
__global__ void chunk_sum(float* __restrict__ Fd, const float* __restrict__ Wt,
                          const float* __restrict__ Vd, float* __restrict__ dS,
                          float* __restrict__ E){
  __shared__ float Fc[32][132];
  __shared__ float Kh[32][132];
  int blk = blockIdx.x, bh = blk>>5, c = blk&31;
  int tid = threadIdx.x;
  int w = tid>>6, lane = tid&63;
  size_t fbase = ((size_t)bh*T_ + (size_t)c*32)*128;
#pragma unroll
  for(int v=0; v<4; v++){
    int e = v*1024 + tid*4;
    int t2 = e>>7, i0 = e&127;
    float4 f4 = *(const float4*)&Fd[fbase + e];
    *(float4*)&Fc[t2][i0] = f4;
  }
  __syncthreads();
  if(tid < 128){
    float a = 0.f;
    for(int t2=0;t2<32;t2++){ a += Fc[t2][tid]; Fc[t2][tid] = a; }
  }
  __syncthreads();
#pragma unroll
  for(int v=0; v<4; v++){
    int e = v*1024 + tid*4;
    int t2 = e>>7, i0 = e&127;
    float4 fc4 = *(const float4*)&Fc[t2][i0];
    *(float4*)&Fd[fbase + e] = fc4;
    float4 ft  = *(const float4*)&Fc[31][i0];
    float4 w4  = *(const float4*)&Wt[fbase + e];
    float4 kh;
    kh.x = w4.x * expf(ft.x - fc4.x);
    kh.y = w4.y * expf(ft.y - fc4.y);
    kh.z = w4.z * expf(ft.z - fc4.z);
    kh.w = w4.w * expf(ft.w - fc4.w);
    *(float4*)&Kh[t2][i0] = kh;
  }
  if(tid < 128) E[((size_t)bh*32 + c)*128 + tid] = expf(Fc[31][tid]);
  __syncthreads();
  int ig = lane>>3, jg = lane&7;
  const float* Vp = Vd + fbase;
  f32x4 acc[4][4];
#pragma unroll
  for(int a=0;a<4;a++)
#pragma unroll
    for(int q=0;q<4;q++) acc[a][q] = (f32x4){0.f,0.f,0.f,0.f};
#pragma unroll 4
  for(int t2=0;t2<32;t2++){
    float4 kq = *(const float4*)&Kh[t2][w*32 + ig*4];
    float4 v0 = *(const float4*)&Vp[t2*128 + jg*4];
    float4 v1 = *(const float4*)&Vp[t2*128 + jg*4 + 32];
    float4 v2 = *(const float4*)&Vp[t2*128 + jg*4 + 64];
    float4 v3 = *(const float4*)&Vp[t2*128 + jg*4 + 96];
    float kk[4] = {kq.x,kq.y,kq.z,kq.w};
#pragma unroll
    for(int a=0;a<4;a++){
      acc[a][0] += kk[a]*(f32x4){v0.x,v0.y,v0.z,v0.w};
      acc[a][1] += kk[a]*(f32x4){v1.x,v1.y,v1.z,v1.w};
      acc[a][2] += kk[a]*(f32x4){v2.x,v2.y,v2.z,v2.w};
      acc[a][3] += kk[a]*(f32x4){v3.x,v3.y,v3.z,v3.w};
    }
  }
  size_t dbase = (size_t)blk*16384;
#pragma unroll
  for(int q=0;q<4;q++)
#pragma unroll
    for(int jj=0;jj<4;jj++){
      float4 o4 = make_float4(acc[0][q][jj],acc[1][q][jj],acc[2][q][jj],acc[3][q][jj]);
      *(float4*)&dS[dbase + (size_t)(jg*4 + 32*q + jj)*128 + w*32 + ig*4] = o4;
    }
}

// ---------------- phase 2: inter-chunk scan on dS_T (scalar threads for TLP)
__global__ void scan_k(float* __restrict__ dS, const float* __restrict__ E){
  int g = blockIdx.x*256 + threadIdx.x;   // 262144 threads: (bh, element)
  int bh = g>>14, e = g&16383;
  int i = e&127;                          // kdim (decay index)
  float S = 0.f;
  for(int c=0;c<32;c++){
    size_t off = ((size_t)(bh*32 + c))*16384 + e;
    float d  = dS[off];
    float Ec = E[((size_t)(bh*32 + c))*128 + i];
    dS[off] = S;
    S = Ec*S + d;
  }
}

// ---------------- phase 3: O = qt @ S + tril(qt kt^T) @ V, full MFMA
__launch_bounds__(256)
__global__ void chunk_out(const float* __restrict__ Qd, const float* __restrict__ Wt,
                          const float* __restrict__ Fd, const float* __restrict__ Vd,
                          const float* __restrict__ ST, float* __restrict__ O){
  __shared__ unsigned int qtP[32][132];   // packed bf16 hi|lo, [tok][k]
  __shared__ unsigned int ktP[32][132];
  __shared__ unsigned int Vt[128][36];    // packed, [vdim][tok]
  __shared__ float Amat[32][40];          // tril(qt kt^T), f32
  int blk = blockIdx.x, bh = blk>>5, c = blk&31;
  int b = bh>>3, h = bh&7;
  int tid = threadIdx.x, w = tid>>6, lane = tid&63;
  int m = lane&31, hi = lane>>5;
  size_t fbase = ((size_t)bh*T_ + (size_t)c*32)*128;
#pragma unroll
  for(int p=0;p<4;p++){
    int e = p*1024 + tid*4;
    int t2 = e>>7, i0 = e&127;
    float4 f4 = *(const float4*)&Fd[fbase + e];
    float4 q4 = *(const float4*)&Qd[fbase + e];
    float4 w4 = *(const float4*)&Wt[fbase + e];
    float fv[4] = {f4.x,f4.y,f4.z,f4.w};
    float qv[4] = {q4.x,q4.y,q4.z,q4.w};
    float wv[4] = {w4.x,w4.y,w4.z,w4.w};
    uint4 qp, kp;
    unsigned int qa[4], ka[4];
#pragma unroll
    for(int j=0;j<4;j++){
      float ef = expf(fv[j]);
      qa[j] = pack_hl(qv[j]*ef);
      ka[j] = pack_hl(wv[j]/ef);
    }
    qp.x=qa[0]; qp.y=qa[1]; qp.z=qa[2]; qp.w=qa[3];
    kp.x=ka[0]; kp.y=ka[1]; kp.z=ka[2]; kp.w=ka[3];
    *(uint4*)&qtP[t2][i0] = qp;
    *(uint4*)&ktP[t2][i0] = kp;
  }
  {
    int n = tid&127, th = (tid>>7)*16;
    unsigned int vp[16];
#pragma unroll
    for(int j=0;j<16;j++) vp[j] = pack_hl(Vd[fbase + (size_t)(th+j)*128 + n]);
#pragma unroll
    for(int j=0;j<16;j+=4){
      uint4 v4; v4.x=vp[j]; v4.y=vp[j+1]; v4.z=vp[j+2]; v4.w=vp[j+3];
      *(uint4*)&Vt[n][th+j] = v4;
    }
  }
  __syncthreads();
  if(w == 0){
    f32x16 am;
#pragma unroll
    for(int r=0;r<16;r++) am[r] = 0.f;
#pragma unroll
    for(int s=0;s<8;s++){
      int ko = s*16 + hi*8;
      uint4 qa = *(const uint4*)&qtP[m][ko];
      uint4 qb = *(const uint4*)&qtP[m][ko+4];
      uint4 ka = *(const uint4*)&ktP[m][ko];
      uint4 kb = *(const uint4*)&ktP[m][ko+4];
      s16x8 qh, ql, kh, kl;
      unsigned int qw_[8] = {qa.x,qa.y,qa.z,qa.w,qb.x,qb.y,qb.z,qb.w};
      unsigned int kw_[8] = {ka.x,ka.y,ka.z,ka.w,kb.x,kb.y,kb.z,kb.w};
#pragma unroll
      for(int j=0;j<8;j++){
        qh[j]=(short)(qw_[j]>>16); ql[j]=(short)(qw_[j]&0xffff);
        kh[j]=(short)(kw_[j]>>16); kl[j]=(short)(kw_[j]&0xffff);
      }
      am = __builtin_amdgcn_mfma_f32_32x32x16_bf16(qh, kh, am, 0,0,0);
      am = __builtin_amdgcn_mfma_f32_32x32x16_bf16(qh, kl, am, 0,0,0);
      am = __builtin_amdgcn_mfma_f32_32x32x16_bf16(ql, kh, am, 0,0,0);
    }
#pragma unroll
    for(int r=0;r<16;r++){
      int rm = (r&3) + 8*(r>>2) + 4*hi;
      Amat[rm][m] = (m <= rm) ? am[r] : 0.f;
    }
  }
  f32x16 oacc;
#pragma unroll
  for(int r=0;r<16;r++) oacc[r] = 0.f;
  const float* Sp = ST + (size_t)blk*16384 + (size_t)(w*32 + m)*128;
#pragma unroll
  for(int s=0;s<8;s++){
    int ko = s*16 + hi*8;
    uint4 qa = *(const uint4*)&qtP[m][ko];
    uint4 qb = *(const uint4*)&qtP[m][ko+4];
    s16x8 qh, ql;
    unsigned int qw_[8] = {qa.x,qa.y,qa.z,qa.w,qb.x,qb.y,qb.z,qb.w};
#pragma unroll
    for(int j=0;j<8;j++){ qh[j]=(short)(qw_[j]>>16); ql[j]=(short)(qw_[j]&0xffff); }
    float4 s0 = *(const float4*)&Sp[ko];
    float4 s1 = *(const float4*)&Sp[ko+4];
    float sv[8] = {s0.x,s0.y,s0.z,s0.w,s1.x,s1.y,s1.z,s1.w};
    s16x8 sh, sl;
#pragma unroll
    for(int j=0;j<8;j++){
      unsigned short hh = f2bf(sv[j]);
      sh[j] = (short)hh; sl[j] = (short)f2bf(sv[j]-bf2f(hh));
    }
    oacc = __builtin_amdgcn_mfma_f32_32x32x16_bf16(qh, sh, oacc, 0,0,0);
    oacc = __builtin_amdgcn_mfma_f32_32x32x16_bf16(qh, sl, oacc, 0,0,0);
    oacc = __builtin_amdgcn_mfma_f32_32x32x16_bf16(ql, sh, oacc, 0,0,0);
  }
  __syncthreads();
#pragma unroll
  for(int s=0;s<2;s++){
    int uo = s*16 + hi*8;
    float4 a0 = *(const float4*)&Amat[m][uo];
    float4 a1 = *(const float4*)&Amat[m][uo+4];
    float av[8] = {a0.x,a0.y,a0.z,a0.w,a1.x,a1.y,a1.z,a1.w};
    s16x8 ah, al;
#pragma unroll
    for(int j=0;j<8;j++){
      unsigned short hh = f2bf(av[j]);
      ah[j] = (short)hh; al[j] = (short)f2bf(av[j]-bf2f(hh));
    }
    uint4 v0 = *(const uint4*)&Vt[w*32 + m][uo];
    uint4 v1 = *(const uint4*)&Vt[w*32 + m][uo+4];
    unsigned int vw[8] = {v0.x,v0.y,v0.z,v0.w,v1.x,v1.y,v1.z,v1.w};
    s16x8 vh, vl;
#pragma unroll
    for(int j=0;j<8;j++){ vh[j]=(short)(vw[j]>>16); vl[j]=(short)(vw[j]&0xffff); }
    oacc = __builtin_amdgcn_mfma_f32_32x32x16_bf16(ah, vh, oacc, 0,0,0);
    oacc = __builtin_amdgcn_mfma_f32_32x32x16_bf16(ah, vl, oacc, 0,0,0);
    oacc = __builtin_amdgcn_mfma_f32_32x32x16_bf16(al, vh, oacc, 0,0,0);
  }
#pragma unroll
  for(int r=0;r<16;r++){
    int tok = (r&3) + 8*(r>>2) + 4*hi;
    O[((size_t)(b*T_ + c*32 + tok))*1024 + h*128 + w*32 + m] = oacc[r];
  }
}

// ---------------- final g-RMSNorm + cast bf16
__global__ void gnorm_k(const float* __restrict__ Ob, const float* __restrict__ gw,
                        unsigned short* __restrict__ On){
  __shared__ float red[4];
  int n = blockIdx.x, tid = threadIdx.x;
  size_t base = (size_t)n*1024 + tid*4;
  float4 x = *(const float4*)&Ob[base];
  float ss = x.x*x.x + x.y*x.y + x.z*x.z + x.w*x.w;
  ss+=__shfl_xor(ss,1);ss+=__shfl_xor(ss,2);ss+=__shfl_xor(ss,4);
  ss+=__shfl_xor(ss,8);ss+=__shfl_xor(ss,16);ss+=__shfl_xor(ss,32);
  if((tid&63)==0) red[tid>>6]=ss;
  __syncthreads();
  float sc = rsqrtf((red[0]+red[1]+red[2]+red[3])/1024.f + 1e-5f);
  float4 g = *(const float4*)&gw[tid*4];
  ushort4 o4;
  o4.x=f2bf(x.x*sc*g.x); o4.y=f2bf(x.y*sc*g.y);
  o4.z=f2bf(x.z*sc*g.z); o4.w=f2bf(x.w*sc*g.w);
  *(ushort4*)&On[base]=o4;
}

extern "C" void kernel_launch(void* const* d_in, const int* in_sizes, int n_in,
                              void* d_out, int out_size, void* d_ws, size_t ws_size,
                              hipStream_t stream){
  const float* hs   = (const float*)d_in[0];
  const float* Wq   = (const float*)d_in[1];
  const float* Wk   = (const float*)d_in[2];
  const float* Wv   = (const float*)d_in[3];
  const float* Wr   = (const float*)d_in[4];
  const float* Wa   = (const float*)d_in[5];
  const float* A_log= (const float*)d_in[6];
  const float* dtb  = (const float*)d_in[7];
  const float* qw   = (const float*)d_in[8];
  const float* kw   = (const float*)d_in[9];
  const float* gw   = (const float*)d_in[10];
  const float* Wo   = (const float*)d_in[11];
  float* out = (float*)d_out;

  char* wsp = (char*)d_ws;
  size_t off = 0;
  auto alloc = [&](size_t bytes)->void*{ void* p = wsp + off; off += (bytes + 255) & ~(size_t)255; return p; };
  unsigned short* Xhi    = (unsigned short*)alloc(2048ull*1024*2);
  unsigned short* Xlo    = (unsigned short*)alloc(2048ull*1024*2);
  unsigned short* WcatT3 = (unsigned short*)alloc(3072ull*1024*2);
  unsigned short* WrThi  = (unsigned short*)alloc(1024ull*1024*2);
  unsigned short* WrTlo  = (unsigned short*)alloc(1024ull*1024*2);
  unsigned short* WoT    = (unsigned short*)alloc(1024ull*1024*2);
  float* C1 = (float*)alloc(2048ull*3072*4);
  float* fh = (float*)alloc(2048ull*8*4);
  float* Qd = (float*)alloc(16ull*1024*128*4);
  float* Wt = (float*)alloc(16ull*1024*128*4);
  float* Fd = (float*)alloc(16ull*1024*128*4);
  float* Vd = (float*)alloc(16ull*1024*128*4);
  float* E  = (float*)alloc(16ull*32*128*4);
  float* dS = (float*)alloc(16ull*32*16384*4);   // 33.5 MB; also aliased as Rp (25.2 MB)
  float* Ob = (float*)alloc(2048ull*1024*4);
  unsigned short* On = (unsigned short*)alloc(2048ull*1024*2);
  float* Rp = dS;   // router partials live in dS region (consumed by postproc before chunk_sum writes dS)
  (void)ws_size; (void)in_sizes; (void)n_in; (void)out_size;

  prep_k     <<<dim3(2048),        dim3(256),   0, stream>>>(hs, Wa, A_log, dtb, Xhi, Xlo, fh);
  wtrans     <<<dim3(32,32,5),     dim3(32,8),  0, stream>>>(Wq,Wk,Wv,Wr,Wo, WcatT3,WrThi,WrTlo,WoT);
  gemm_fused <<<dim3(768),         dim3(256),   0, stream>>>(Xhi, Xlo, WcatT3, WrThi, WrTlo, C1, Rp);
  postproc   <<<dim3(16384),       dim3(128),   0, stream>>>(C1, Rp, fh, qw, kw, Qd, Wt, Fd, Vd);
  chunk_sum  <<<dim3(512),         dim3(256),   0, stream>>>(Fd, Wt, Vd, dS, E);
  scan_k     <<<dim3(1024),        dim3(256),   0, stream>>>(dS, E);
  chunk_out  <<<dim3(512),         dim3(256),   0, stream>>>(Qd, Wt, Fd, Vd, dS, Ob);
  gnorm_k    <<<dim3(2048),        dim3(256),   0, stream>>>(Ob, gw, On);
  gemm_out   <<<dim3(16,16),       dim3(256),   0, stream>>>(On, WoT, out);
}

// Round 6
// 253.988 us; speedup vs baseline: 1.3763x; 1.0402x over previous
//
#include <hip/hip_runtime.h>
#include <stdint.h>
#include <stddef.h>

#define H_ 8
#define T_ 1024

typedef __attribute__((ext_vector_type(8))) short s16x8;
typedef __attribute__((ext_vector_type(4))) float f32x4;
typedef __attribute__((ext_vector_type(16))) float f32x16;

static __device__ __forceinline__ unsigned short f2bf(float f){
  unsigned u = __float_as_uint(f);
  u += 0x7fffu + ((u >> 16) & 1u);          // round-to-nearest-even
  return (unsigned short)(u >> 16);
}
static __device__ __forceinline__ float bf2f(unsigned short b){
  return __uint_as_float(((unsigned)b) << 16);
}
static __device__ __forceinline__ unsigned int pack_hl(float x){
  unsigned short h = f2bf(x);
  unsigned short l = f2bf(x - bf2f(h));
  return ((unsigned int)h << 16) | l;
}
// async global->LDS 16B (m97 pattern; HW: wave-uniform base + lane*16)
static __device__ __forceinline__ void gl_lds16(const unsigned short* g, unsigned short* l){
  __builtin_amdgcn_global_load_lds((const __attribute__((address_space(1))) unsigned int*)g,
                                   (__attribute__((address_space(3))) unsigned int*)l,
                                   16, 0, 0);
}

// ---------------- prep: cast hs to bf16 hi+lo AND f_head (fused)
__global__ void prep_k(const float* __restrict__ X, const float* __restrict__ Wa,
                       const float* __restrict__ A_log, const float* __restrict__ dtb,
                       unsigned short* __restrict__ hi, unsigned short* __restrict__ lo,
                       float* __restrict__ fh){
  __shared__ float xs[1024];
  int n = blockIdx.x, tid = threadIdx.x;   // 256 threads
  size_t base = (size_t)n*1024 + tid*4;
  float4 x = *(const float4*)&X[base];
  *(float4*)&xs[tid*4] = x;
  float v[4] = {x.x,x.y,x.z,x.w};
  ushort4 h4, l4;
  unsigned short hh[4], ll[4];
#pragma unroll
  for(int j=0;j<4;j++){ hh[j]=f2bf(v[j]); ll[j]=f2bf(v[j]-bf2f(hh[j])); }
  h4.x=hh[0];h4.y=hh[1];h4.z=hh[2];h4.w=hh[3];
  l4.x=ll[0];l4.y=ll[1];l4.z=ll[2];l4.w=ll[3];
  *(ushort4*)&hi[base] = h4;
  *(ushort4*)&lo[base] = l4;
  __syncthreads();
  int h = tid>>5, l = tid&31;
  float s = 0.f;
  for(int k=l;k<1024;k+=32) s += xs[k]*Wa[(size_t)k*8 + h];
  s += __shfl_xor(s,1); s += __shfl_xor(s,2); s += __shfl_xor(s,4);
  s += __shfl_xor(s,8); s += __shfl_xor(s,16);
  if(l==0){
    float z = s + dtb[h];
    float sp = (z > 20.f) ? z : log1pf(expf(z));
    fh[(size_t)n*8 + h] = -expf(A_log[h]) * sp;
  }
}

// ---------------- transpose+cast weights
__global__ void wtrans(const float* __restrict__ Wq, const float* __restrict__ Wk,
                       const float* __restrict__ Wv, const float* __restrict__ Wr,
                       const float* __restrict__ Wo,
                       unsigned short* __restrict__ WcatT3, unsigned short* __restrict__ WrThi,
                       unsigned short* __restrict__ WrTlo, unsigned short* __restrict__ WoT){
  __shared__ float tile[32][33];
  int z = blockIdx.z;
  const float* src = (z==0)?Wq:(z==1)?Wk:(z==2)?Wv:(z==3)?Wr:Wo;
  int c0 = blockIdx.x*32;
  int k0 = blockIdx.y*32;
  int tx = threadIdx.x, ty = threadIdx.y; // 32 x 8
#pragma unroll
  for(int r=0;r<32;r+=8)
    tile[ty+r][tx] = src[(size_t)(k0+ty+r)*1024 + c0 + tx];
  __syncthreads();
#pragma unroll
  for(int r=0;r<32;r+=8){
    int c = c0 + ty + r;
    int k = k0 + tx;
    float v = tile[tx][ty+r];
    if(z < 3){
      WcatT3[((size_t)(z*1024 + c))*1024 + k] = f2bf(v);
    } else if(z == 3){
      unsigned short hv = f2bf(v);
      WrThi[(size_t)c*1024 + k] = hv;
      WrTlo[(size_t)c*1024 + k] = f2bf(v - bf2f(hv));
    } else {
      WoT[(size_t)c*1024 + k] = f2bf(v);
    }
  }
}

// ---------------- fused proj + router GEMM, 768 uniform blocks, BK=64
// LDS layout: row-major 64-wide rows; 16B chunk slot = c8 ^ (row&7) (involution,
// applied on BOTH pre-swizzled global source and ds_read side). Conflict-free.
__launch_bounds__(256)
__global__ void gemm_fused(const unsigned short* __restrict__ Xhi, const unsigned short* __restrict__ Xlo,
                           const unsigned short* __restrict__ WcatT3, const unsigned short* __restrict__ WrThi,
                           const unsigned short* __restrict__ WrTlo,
                           float* __restrict__ C1, float* __restrict__ Rp){
  __shared__ unsigned short As[128*64];
  __shared__ unsigned short Bs[128*64];
  int bid = blockIdx.x;
  int blk = (bid&7)*96 + (bid>>3);        // XCD-contiguous (768%8==0, bijective)
  const unsigned short *Ap, *Bp;
  float* Cout;
  int bx, by, N;
  if(blk < 384){
    bx = blk%24; by = blk/24; N = 3072;
    Ap = Xhi; Bp = WcatT3; Cout = C1;
  } else {
    int rb = blk-384;
    int seg = rb>>7, t2 = rb&127;
    bx = t2&7; by = t2>>3; N = 1024;
    Ap = (seg==2) ? Xlo : Xhi;
    Bp = (seg==1) ? WrTlo : WrThi;
    Cout = Rp + (size_t)seg*2048*1024;
  }
  int tid = threadIdx.x;
  int mBase = by*128, nBase = bx*128;
  int w = tid>>6, lane = tid&63, wr = w>>1, wc = w&1;
  int kg = lane>>4, l15 = lane&15;
  f32x4 acc[4][4];
#pragma unroll
  for(int i=0;i<4;i++)
#pragma unroll
    for(int j=0;j<4;j++) acc[i][j] = (f32x4){0.f,0.f,0.f,0.f};
  size_t aoff[4], boff[4];
#pragma unroll
  for(int p=0;p<4;p++){
    int c = p*256 + tid;
    int row = c>>3, sc = c&7, c8 = sc ^ (row&7);
    aoff[p] = (size_t)(mBase+row)*1024 + c8*8;
    boff[p] = (size_t)(nBase+row)*1024 + c8*8;
  }
  for(int kb=0; kb<1024; kb+=64){
#pragma unroll
    for(int p=0;p<4;p++){
      gl_lds16(Ap + aoff[p] + kb, &As[(p*256+tid)*8]);
      gl_lds16(Bp + boff[p] + kb, &Bs[(p*256+tid)*8]);
    }
    __syncthreads();
#pragma unroll
    for(int kk=0;kk<2;kk++){
      s16x8 afr[4], bfr[4];
#pragma unroll
      for(int f=0;f<4;f++){
        int rA = wr*64 + f*16 + l15;
        int rB = wc*64 + f*16 + l15;
        int cA = (kk*4 + kg) ^ (rA&7);
        int cB = (kk*4 + kg) ^ (rB&7);
        afr[f] = *(const s16x8*)&As[rA*64 + cA*8];
        bfr[f] = *(const s16x8*)&Bs[rB*64 + cB*8];
      }
#pragma unroll
      for(int fm=0;fm<4;fm++)
#pragma unroll
        for(int fn=0;fn<4;fn++)
          acc[fm][fn] = __builtin_amdgcn_mfma_f32_16x16x32_bf16(afr[fm], bfr[fn], acc[fm][fn], 0,0,0);
    }
    __syncthreads();
  }
#pragma unroll
  for(int fm=0;fm<4;fm++)
#pragma unroll
    for(int fn=0;fn<4;fn++){
      int col = nBase + wc*64 + fn*16 + l15;
      int row = mBase + wr*64 + fm*16 + kg*4;
#pragma unroll
      for(int r=0;r<4;r++) Cout[(size_t)(row+r)*N + col] = acc[fm][fn][r];
    }
}

// ---------------- output GEMM: 128x64 tiles, BK=64, 256 blocks
__launch_bounds__(256)
__global__ void gemm_out(const unsigned short* __restrict__ A,
                         const unsigned short* __restrict__ BT,
                         float* __restrict__ C){
  __shared__ unsigned short As[128*64];
  __shared__ unsigned short Bs[64*64];
  const int K = 1024, N = 1024;
  int tid = threadIdx.x;
  int mBase = blockIdx.y*128, nBase = blockIdx.x*64;
  int w = tid>>6, lane = tid&63;
  int mh = w>>1, nh = w&1;
  int kg = lane>>4, l15 = lane&15;
  f32x4 acc[4][2];
#pragma unroll
  for(int i=0;i<4;i++)
#pragma unroll
    for(int j=0;j<2;j++) acc[i][j] = (f32x4){0.f,0.f,0.f,0.f};
  size_t aoff[4], boff[2];
#pragma unroll
  for(int p=0;p<4;p++){
    int c = p*256 + tid;
    int row = c>>3, sc = c&7, c8 = sc ^ (row&7);
    aoff[p] = (size_t)(mBase+row)*K + c8*8;
  }
#pragma unroll
  for(int p=0;p<2;p++){
    int c = p*256 + tid;
    int row = c>>3, sc = c&7, c8 = sc ^ (row&7);
    boff[p] = (size_t)(nBase+row)*K + c8*8;
  }
  for(int kb=0; kb<K; kb+=64){
#pragma unroll
    for(int p=0;p<4;p++) gl_lds16(A + aoff[p] + kb, &As[(p*256+tid)*8]);
#pragma unroll
    for(int p=0;p<2;p++) gl_lds16(BT + boff[p] + kb, &Bs[(p*256+tid)*8]);
    __syncthreads();
#pragma unroll
    for(int kk=0;kk<2;kk++){
      s16x8 afr[4], bfr[2];
#pragma unroll
      for(int f=0;f<4;f++){
        int r = mh*64 + f*16 + l15;
        afr[f] = *(const s16x8*)&As[r*64 + ((kk*4+kg) ^ (r&7))*8];
      }
#pragma unroll
      for(int f=0;f<2;f++){
        int r = nh*32 + f*16 + l15;
        bfr[f] = *(const s16x8*)&Bs[r*64 + ((kk*4+kg) ^ (r&7))*8];
      }
#pragma unroll
      for(int fm=0;fm<4;fm++)
#pragma unroll
        for(int fn=0;fn<2;fn++)
          acc[fm][fn] = __builtin_amdgcn_mfma_f32_16x16x32_bf16(afr[fm], bfr[fn], acc[fm][fn], 0,0,0);
    }
    __syncthreads();
  }
#pragma unroll
  for(int fm=0;fm<4;fm++)
#pragma unroll
    for(int fn=0;fn<2;fn++){
      int col = nBase + nh*32 + fn*16 + l15;
      int row = mBase + mh*64 + fm*16 + kg*4;
#pragma unroll
      for(int r=0;r<4;r++) C[(size_t)(row+r)*N + col] = acc[fm][fn][r];
    }
}

// ---------------- postproc: token-per-block (2048 x 256); head = 32-lane group
__launch_bounds__(256)
__global__ void postproc(const float* __restrict__ C1, const float* __restrict__ Rp,
                         const float* __restrict__ fh, const float* __restrict__ qw,
                         const float* __restrict__ kw,
                         float* __restrict__ Qd, float* __restrict__ Wt,
                         float* __restrict__ Fd, float* __restrict__ Vd){
  __shared__ unsigned long long keys[8][128];
  int n = blockIdx.x;                 // token index (b*1024 + t)
  int t = threadIdx.x;                // 256
  int b = n>>10, tt = n&1023;
  int h = t>>5;                       // head 0..7 (32-lane group within wave halves)
  int i0 = (t&31)*4;                  // 4 consecutive slots
  size_t cb = (size_t)n*3072;
  size_t rbase = (size_t)n*1024 + h*128 + i0;
  float4 q4 = *(const float4*)&C1[cb + h*128 + i0];
  float4 k4 = *(const float4*)&C1[cb + 1024 + h*128 + i0];
  float4 v4 = *(const float4*)&C1[cb + 2048 + h*128 + i0];
  float4 r0 = *(const float4*)&Rp[rbase];
  float4 r1 = *(const float4*)&Rp[2048ull*1024 + rbase];
  float4 r2 = *(const float4*)&Rp[2ull*2048*1024 + rbase];
  float qv[4] = {q4.x,q4.y,q4.z,q4.w};
  float kv[4] = {k4.x,k4.y,k4.z,k4.w};
  float vv4[4] = {v4.x,v4.y,v4.z,v4.w};
  float rl[4] = {r0.x+r1.x+r2.x, r0.y+r1.y+r2.y, r0.z+r1.z+r2.z, r0.w+r1.w+r2.w};
  float qs[4], ks[4], vv[4], si[4];
  unsigned long long ki[4];
#pragma unroll
  for(int j=0;j<4;j++){
    qs[j] = qv[j]/(1.f+expf(-qv[j]));
    ks[j] = kv[j]/(1.f+expf(-kv[j]));
    vv[j] = vv4[j]/(1.f+expf(-vv4[j]));
    si[j] = 1.f/(1.f+expf(-rl[j]));
    ki[j] = (((unsigned long long)__float_as_uint(si[j])) << 7) | (unsigned)(127 - (i0+j));
    keys[h][i0+j] = ki[j];
  }
  __syncthreads();
  int cnt[4] = {0,0,0,0};
#pragma unroll 4
  for(int j=0;j<128;j+=2){
    ulonglong2 k2 = *(const ulonglong2*)&keys[h][j];
#pragma unroll
    for(int m=0;m<4;m++){
      cnt[m] += (k2.x > ki[m]);
      cnt[m] += (k2.y > ki[m]);
    }
  }
  bool sel[4];
#pragma unroll
  for(int m=0;m<4;m++) sel[m] = cnt[m] < 32;   // exact stable top-32
  // per-head reductions over the 32-lane group
  float x;
  x = qs[0]*qs[0]+qs[1]*qs[1]+qs[2]*qs[2]+qs[3]*qs[3];
  x+=__shfl_xor(x,1);x+=__shfl_xor(x,2);x+=__shfl_xor(x,4);x+=__shfl_xor(x,8);x+=__shfl_xor(x,16);
  float qrms = rsqrtf(x/128.f + 1e-5f);
  x = ks[0]*ks[0]+ks[1]*ks[1]+ks[2]*ks[2]+ks[3]*ks[3];
  x+=__shfl_xor(x,1);x+=__shfl_xor(x,2);x+=__shfl_xor(x,4);x+=__shfl_xor(x,8);x+=__shfl_xor(x,16);
  float krms = rsqrtf(x/128.f + 1e-5f);
  x = (sel[0]?si[0]:0.f)+(sel[1]?si[1]:0.f)+(sel[2]?si[2]:0.f)+(sel[3]?si[3]:0.f);
  x+=__shfl_xor(x,1);x+=__shfl_xor(x,2);x+=__shfl_xor(x,4);x+=__shfl_xor(x,8);x+=__shfl_xor(x,16);
  float winv = 1.f/(x + 1e-9f);
  float fhv = fh[(size_t)n*8 + h];
  size_t base = ((size_t)((b*H_ + h)*T_) + tt)*128 + i0;
  float4 qo, wo, fo, vo;
  float qd[4], wd[4], fd[4];
#pragma unroll
  for(int j=0;j<4;j++){
    float wgt = sel[j] ? si[j]*winv : 0.f;
    float f = fhv * wgt;
    qd[j] = qs[j]*qrms*qw[i0+j];
    wd[j] = (1.f - expf(f)) * (ks[j]*krms*kw[i0+j]);
    fd[j] = f;
  }
  qo.x=qd[0];qo.y=qd[1];qo.z=qd[2];qo.w=qd[3];
  wo.x=wd[0];wo.y=wd[1];wo.z=wd[2];wo.w=wd[3];
  fo.x=fd[0];fo.y=fd[1];fo.z=fd[2];fo.w=fd[3];
  vo.x=vv[0];vo.y=vv[1];vo.z=vv[2];vo.w=vv[3];
  *(float4*)&Qd[base] = qo;
  *(float4*)&Wt[base] = wo;
  *(float4*)&Fd[base] = fo;
  *(float4*)&Vd[base] = vo;
}

// ---------------- phase 1: per chunk: cumsum F in-place, E, dS^T = (Khat^T V)^T
__launch_bounds__(256)
__global__ void chunk_sum(float* __restrict__ Fd, const float* __restrict__ Wt,
                          const float* __restrict__ Vd, float* __restrict__ dS,
                          float* __restrict__ E){
  __shared__ float Fc[32][132];
  __shared__ float Kh[32][132];
  int blk = blockIdx.x, bh = blk>>5, c = blk&31;
  int tid = threadIdx.x;
  int w = tid>>6, lane = tid&63;
  size_t fbase = ((size_t)bh*T_ + (size_t)c*32)*128;
#pragma unroll
  for(int v=0; v<4; v++){
    int e = v*1024 + tid*4;
    int t2 = e>>7, i0 = e&127;
    float4 f4 = *(const float4*)&Fd[fbase + e];
    *(float4*)&Fc[t2][i0] = f4;
  }
  __syncthreads();
  if(tid < 128){
    float a = 0.f;
    for(int t2=0;t2<32;t2++){ a += Fc[t2][tid]; Fc[t2][tid] = a; }
  }
  __syncthreads();
#pragma unroll
  for(int v=0; v<4; v++){
    int e = v*1024 + tid*4;
    int t2 = e>>7, i0 = e&127;
    float4 fc4 = *(const float4*)&Fc[t2][i0];
    *(float4*)&Fd[fbase + e] = fc4;
    float4 ft  = *(const float4*)&Fc[31][i0];
    float4 w4  = *(const float4*)&Wt[fbase + e];
    float4 kh;
    kh.x = w4.x * expf(ft.x - fc4.x);
    kh.y = w4.y * expf(ft.y - fc4.y);
    kh.z = w4.z * expf(ft.z - fc4.z);
    kh.w = w4.w * expf(ft.w - fc4.w);
    *(float4*)&Kh[t2][i0] = kh;
  }
  if(tid < 128) E[((size_t)bh*32 + c)*128 + tid] = expf(Fc[31][tid]);
  __syncthreads();
  int ig = lane>>3, jg = lane&7;
  const float* Vp = Vd + fbase;
  f32x4 acc[4][4];
#pragma unroll
  for(int a=0;a<4;a++)
#pragma unroll
    for(int q=0;q<4;q++) acc[a][q] = (f32x4){0.f,0.f,0.f,0.f};
#pragma unroll 4
  for(int t2=0;t2<32;t2++){
    float4 kq = *(const float4*)&Kh[t2][w*32 + ig*4];
    float4 v0 = *(const float4*)&Vp[t2*128 + jg*4];
    float4 v1 = *(const float4*)&Vp[t2*128 + jg*4 + 32];
    float4 v2 = *(const float4*)&Vp[t2*128 + jg*4 + 64];
    float4 v3 = *(const float4*)&Vp[t2*128 + jg*4 + 96];
    float kk[4] = {kq.x,kq.y,kq.z,kq.w};
#pragma unroll
    for(int a=0;a<4;a++){
      acc[a][0] += kk[a]*(f32x4){v0.x,v0.y,v0.z,v0.w};
      acc[a][1] += kk[a]*(f32x4){v1.x,v1.y,v1.z,v1.w};
      acc[a][2] += kk[a]*(f32x4){v2.x,v2.y,v2.z,v2.w};
      acc[a][3] += kk[a]*(f32x4){v3.x,v3.y,v3.z,v3.w};
    }
  }
  size_t dbase = (size_t)blk*16384;
#pragma unroll
  for(int q=0;q<4;q++)
#pragma unroll
    for(int jj=0;jj<4;jj++){
      float4 o4 = make_float4(acc[0][q][jj],acc[1][q][jj],acc[2][q][jj],acc[3][q][jj]);
      *(float4*)&dS[dbase + (size_t)(jg*4 + 32*q + jj)*128 + w*32 + ig*4] = o4;
    }
}

// ---------------- phase 2: inter-chunk scan on dS_T (float4, 16 waves/CU TLP)
__global__ void scan_k(float* __restrict__ dS, const float* __restrict__ E){
  int g = blockIdx.x*256 + threadIdx.x;   // 65536 threads: (bh, float4 idx)
  int bh = g>>12;
  int e4 = (g&4095)*4;
  int i0 = e4 & 127;                      // kdim (decay index), 4 consecutive
  float4 S = make_float4(0.f,0.f,0.f,0.f);
  for(int c=0;c<32;c++){
    size_t off = ((size_t)(bh*32 + c))*16384 + e4;
    float4 d   = *(const float4*)&dS[off];
    float4 Ec  = *(const float4*)&E[((size_t)(bh*32 + c))*128 + i0];
    *(float4*)&dS[off] = S;
    S.x = Ec.x*S.x + d.x;
    S.y = Ec.y*S.y + d.y;
    S.z = Ec.z*S.z + d.z;
    S.w = Ec.w*S.w + d.w;
  }
}

// ---------------- phase 3: O = qt @ S + tril(qt kt^T) @ V, full MFMA
__launch_bounds__(256)
__global__ void chunk_out(const float* __restrict__ Qd, const float* __restrict__ Wt,
                          const float* __restrict__ Fd, const float* __restrict__ Vd,
                          const float* __restrict__ ST, float* __restrict__ O){
  __shared__ unsigned int qtP[32][132];   // packed bf16 hi|lo, [tok][k]
  __shared__ unsigned int ktP[32][132];
  __shared__ unsigned int Vt[128][36];    // packed, [vdim][tok]
  __shared__ float Amat[32][40];          // tril(qt kt^T), f32
  int blk = blockIdx.x, bh = blk>>5, c = blk&31;
  int b = bh>>3, h = bh&7;
  int tid = threadIdx.x, w = tid>>6, lane = tid&63;
  int m = lane&31, hi = lane>>5;
  size_t fbase = ((size_t)bh*T_ + (size_t)c*32)*128;
#pragma unroll
  for(int p=0;p<4;p++){
    int e = p*1024 + tid*4;
    int t2 = e>>7, i0 = e&127;
    float4 f4 = *(const float4*)&Fd[fbase + e];
    float4 q4 = *(const float4*)&Qd[fbase + e];
    float4 w4 = *(const float4*)&Wt[fbase + e];
    float fv[4] = {f4.x,f4.y,f4.z,f4.w};
    float qv[4] = {q4.x,q4.y,q4.z,q4.w};
    float wv[4] = {w4.x,w4.y,w4.z,w4.w};
    uint4 qp, kp;
    unsigned int qa[4], ka[4];
#pragma unroll
    for(int j=0;j<4;j++){
      float ef = expf(fv[j]);
      qa[j] = pack_hl(qv[j]*ef);
      ka[j] = pack_hl(wv[j]/ef);
    }
    qp.x=qa[0]; qp.y=qa[1]; qp.z=qa[2]; qp.w=qa[3];
    kp.x=ka[0]; kp.y=ka[1]; kp.z=ka[2]; kp.w=ka[3];
    *(uint4*)&qtP[t2][i0] = qp;
    *(uint4*)&ktP[t2][i0] = kp;
  }
  {
    int n = tid&127, th = (tid>>7)*16;
    unsigned int vp[16];
#pragma unroll
    for(int j=0;j<16;j++) vp[j] = pack_hl(Vd[fbase + (size_t)(th+j)*128 + n]);
#pragma unroll
    for(int j=0;j<16;j+=4){
      uint4 v4; v4.x=vp[j]; v4.y=vp[j+1]; v4.z=vp[j+2]; v4.w=vp[j+3];
      *(uint4*)&Vt[n][th+j] = v4;
    }
  }
  __syncthreads();
  if(w == 0){
    f32x16 am;
#pragma unroll
    for(int r=0;r<16;r++) am[r] = 0.f;
#pragma unroll
    for(int s=0;s<8;s++){
      int ko = s*16 + hi*8;
      uint4 qa = *(const uint4*)&qtP[m][ko];
      uint4 qb = *(const uint4*)&qtP[m][ko+4];
      uint4 ka = *(const uint4*)&ktP[m][ko];
      uint4 kb = *(const uint4*)&ktP[m][ko+4];
      s16x8 qh, ql, kh, kl;
      unsigned int qw_[8] = {qa.x,qa.y,qa.z,qa.w,qb.x,qb.y,qb.z,qb.w};
      unsigned int kw_[8] = {ka.x,ka.y,ka.z,ka.w,kb.x,kb.y,kb.z,kb.w};
#pragma unroll
      for(int j=0;j<8;j++){
        qh[j]=(short)(qw_[j]>>16); ql[j]=(short)(qw_[j]&0xffff);
        kh[j]=(short)(kw_[j]>>16); kl[j]=(short)(kw_[j]&0xffff);
      }
      am = __builtin_amdgcn_mfma_f32_32x32x16_bf16(qh, kh, am, 0,0,0);
      am = __builtin_amdgcn_mfma_f32_32x32x16_bf16(qh, kl, am, 0,0,0);
      am = __builtin_amdgcn_mfma_f32_32x32x16_bf16(ql, kh, am, 0,0,0);
    }
#pragma unroll
    for(int r=0;r<16;r++){
      int rm = (r&3) + 8*(r>>2) + 4*hi;
      Amat[rm][m] = (m <= rm) ? am[r] : 0.f;
    }
  }
  f32x16 oacc;
#pragma unroll
  for(int r=0;r<16;r++) oacc[r] = 0.f;
  const float* Sp = ST + (size_t)blk*16384 + (size_t)(w*32 + m)*128;
#pragma unroll
  for(int s=0;s<8;s++){
    int ko = s*16 + hi*8;
    uint4 qa = *(const uint4*)&qtP[m][ko];
    uint4 qb = *(const uint4*)&qtP[m][ko+4];
    s16x8 qh, ql;
    unsigned int qw_[8] = {qa.x,qa.y,qa.z,qa.w,qb.x,qb.y,qb.z,qb.w};
#pragma unroll
    for(int j=0;j<8;j++){ qh[j]=(short)(qw_[j]>>16); ql[j]=(short)(qw_[j]&0xffff); }
    float4 s0 = *(const float4*)&Sp[ko];
    float4 s1 = *(const float4*)&Sp[ko+4];
    float sv[8] = {s0.x,s0.y,s0.z,s0.w,s1.x,s1.y,s1.z,s1.w};
    s16x8 sh, sl;
#pragma unroll
    for(int j=0;j<8;j++){
      unsigned short hh = f2bf(sv[j]);
      sh[j] = (short)hh; sl[j] = (short)f2bf(sv[j]-bf2f(hh));
    }
    oacc = __builtin_amdgcn_mfma_f32_32x32x16_bf16(qh, sh, oacc, 0,0,0);
    oacc = __builtin_amdgcn_mfma_f32_32x32x16_bf16(qh, sl, oacc, 0,0,0);
    oacc = __builtin_amdgcn_mfma_f32_32x32x16_bf16(ql, sh, oacc, 0,0,0);
  }
  __syncthreads();
#pragma unroll
  for(int s=0;s<2;s++){
    int uo = s*16 + hi*8;
    float4 a0 = *(const float4*)&Amat[m][uo];
    float4 a1 = *(const float4*)&Amat[m][uo+4];
    float av[8] = {a0.x,a0.y,a0.z,a0.w,a1.x,a1.y,a1.z,a1.w};
    s16x8 ah, al;
#pragma unroll
    for(int j=0;j<8;j++){
      unsigned short hh = f2bf(av[j]);
      ah[j] = (short)hh; al[j] = (short)f2bf(av[j]-bf2f(hh));
    }
    uint4 v0 = *(const uint4*)&Vt[w*32 + m][uo];
    uint4 v1 = *(const uint4*)&Vt[w*32 + m][uo+4];
    unsigned int vw[8] = {v0.x,v0.y,v0.z,v0.w,v1.x,v1.y,v1.z,v1.w};
    s16x8 vh, vl;
#pragma unroll
    for(int j=0;j<8;j++){ vh[j]=(short)(vw[j]>>16); vl[j]=(short)(vw[j]&0xffff); }
    oacc = __builtin_amdgcn_mfma_f32_32x32x16_bf16(ah, vh, oacc, 0,0,0);
    oacc = __builtin_amdgcn_mfma_f32_32x32x16_bf16(ah, vl, oacc, 0,0,0);
    oacc = __builtin_amdgcn_mfma_f32_32x32x16_bf16(al, vh, oacc, 0,0,0);
  }
#pragma unroll
  for(int r=0;r<16;r++){
    int tok = (r&3) + 8*(r>>2) + 4*hi;
    O[((size_t)(b*T_ + c*32 + tok))*1024 + h*128 + w*32 + m] = oacc[r];
  }
}

// ---------------- final g-RMSNorm + cast bf16
__global__ void gnorm_k(const float* __restrict__ Ob, const float* __restrict__ gw,
                        unsigned short* __restrict__ On){
  __shared__ float red[4];
  int n = blockIdx.x, tid = threadIdx.x;
  size_t base = (size_t)n*1024 + tid*4;
  float4 x = *(const float4*)&Ob[base];
  float ss = x.x*x.x + x.y*x.y + x.z*x.z + x.w*x.w;
  ss+=__shfl_xor(ss,1);ss+=__shfl_xor(ss,2);ss+=__shfl_xor(ss,4);
  ss+=__shfl_xor(ss,8);ss+=__shfl_xor(ss,16);ss+=__shfl_xor(ss,32);
  if((tid&63)==0) red[tid>>6]=ss;
  __syncthreads();
  float sc = rsqrtf((red[0]+red[1]+red[2]+red[3])/1024.f + 1e-5f);
  float4 g = *(const float4*)&gw[tid*4];
  ushort4 o4;
  o4.x=f2bf(x.x*sc*g.x); o4.y=f2bf(x.y*sc*g.y);
  o4.z=f2bf(x.z*sc*g.z); o4.w=f2bf(x.w*sc*g.w);
  *(ushort4*)&On[base]=o4;
}

extern "C" void kernel_launch(void* const* d_in, const int* in_sizes, int n_in,
                              void* d_out, int out_size, void* d_ws, size_t ws_size,
                              hipStream_t stream){
  const float* hs   = (const float*)d_in[0];
  const float* Wq   = (const float*)d_in[1];
  const float* Wk   = (const float*)d_in[2];
  const float* Wv   = (const float*)d_in[3];
  const float* Wr   = (const float*)d_in[4];
  const float* Wa   = (const float*)d_in[5];
  const float* A_log= (const float*)d_in[6];
  const float* dtb  = (const float*)d_in[7];
  const float* qw   = (const float*)d_in[8];
  const float* kw   = (const float*)d_in[9];
  const float* gw   = (const float*)d_in[10];
  const float* Wo   = (const float*)d_in[11];
  float* out = (float*)d_out;

  char* wsp = (char*)d_ws;
  size_t off = 0;
  auto alloc = [&](size_t bytes)->void*{ void* p = wsp + off; off += (bytes + 255) & ~(size_t)255; return p; };
  unsigned short* Xhi    = (unsigned short*)alloc(2048ull*1024*2);
  unsigned short* Xlo    = (unsigned short*)alloc(2048ull*1024*2);
  unsigned short* WcatT3 = (unsigned short*)alloc(3072ull*1024*2);
  unsigned short* WrThi  = (unsigned short*)alloc(1024ull*1024*2);
  unsigned short* WrTlo  = (unsigned short*)alloc(1024ull*1024*2);
  unsigned short* WoT    = (unsigned short*)alloc(1024ull*1024*2);
  float* C1 = (float*)alloc(2048ull*3072*4);
  float* fh = (float*)alloc(2048ull*8*4);
  float* Qd = (float*)alloc(16ull*1024*128*4);
  float* Wt = (float*)alloc(16ull*1024*128*4);
  float* Fd = (float*)alloc(16ull*1024*128*4);
  float* Vd = (float*)alloc(16ull*1024*128*4);
  float* E  = (float*)alloc(16ull*32*128*4);
  float* dS = (float*)alloc(16ull*32*16384*4);   // 33.5 MB; aliased as Rp (25.2 MB)
  float* Ob = (float*)alloc(2048ull*1024*4);
  unsigned short* On = (unsigned short*)alloc(2048ull*1024*2);
  float* Rp = dS;   // router partials live in dS region (consumed before chunk_sum writes dS)
  (void)ws_size; (void)in_sizes; (void)n_in; (void)out_size;

  prep_k     <<<dim3(2048),        dim3(256),   0, stream>>>(hs, Wa, A_log, dtb, Xhi, Xlo, fh);
  wtrans     <<<dim3(32,32,5),     dim3(32,8),  0, stream>>>(Wq,Wk,Wv,Wr,Wo, WcatT3,WrThi,WrTlo,WoT);
  gemm_fused <<<dim3(768),         dim3(256),   0, stream>>>(Xhi, Xlo, WcatT3, WrThi, WrTlo, C1, Rp);
  postproc   <<<dim3(2048),        dim3(256),   0, stream>>>(C1, Rp, fh, qw, kw, Qd, Wt, Fd, Vd);
  chunk_sum  <<<dim3(512),         dim3(256),   0, stream>>>(Fd, Wt, Vd, dS, E);
  scan_k     <<<dim3(256),         dim3(256),   0, stream>>>(dS, E);
  chunk_out  <<<dim3(512),         dim3(256),   0, stream>>>(Qd, Wt, Fd, Vd, dS, Ob);
  gnorm_k    <<<dim3(2048),        dim3(256),   0, stream>>>(Ob, gw, On);
  gemm_out   <<<dim3(16,16),       dim3(256),   0, stream>>>(On, WoT, out);
}

// Round 7
// 251.081 us; speedup vs baseline: 1.3922x; 1.0116x over previous
//
#include <hip/hip_runtime.h>
#include <stdint.h>
#include <stddef.h>

#define H_ 8
#define T_ 1024

typedef __attribute__((ext_vector_type(8))) short s16x8;
typedef __attribute__((ext_vector_type(4))) float f32x4;
typedef __attribute__((ext_vector_type(16))) float f32x16;

static __device__ __forceinline__ unsigned short f2bf(float f){
  unsigned u = __float_as_uint(f);
  u += 0x7fffu + ((u >> 16) & 1u);          // round-to-nearest-even
  return (unsigned short)(u >> 16);
}
static __device__ __forceinline__ float bf2f(unsigned short b){
  return __uint_as_float(((unsigned)b) << 16);
}
static __device__ __forceinline__ unsigned int pack_hl(float x){
  unsigned short h = f2bf(x);
  unsigned short l = f2bf(x - bf2f(h));
  return ((unsigned int)h << 16) | l;
}
// async global->LDS 16B (m97 pattern; HW: wave-uniform base + lane*16)
static __device__ __forceinline__ void gl_lds16(const unsigned short* g, unsigned short* l){
  __builtin_amdgcn_global_load_lds((const __attribute__((address_space(1))) unsigned int*)g,
                                   (__attribute__((address_space(3))) unsigned int*)l,
                                   16, 0, 0);
}

// ---------------- prep: cast hs to bf16 hi+lo AND f_head (fused)
__global__ void prep_k(const float* __restrict__ X, const float* __restrict__ Wa,
                       const float* __restrict__ A_log, const float* __restrict__ dtb,
                       unsigned short* __restrict__ hi, unsigned short* __restrict__ lo,
                       float* __restrict__ fh){
  __shared__ float xs[1024];
  int n = blockIdx.x, tid = threadIdx.x;   // 256 threads
  size_t base = (size_t)n*1024 + tid*4;
  float4 x = *(const float4*)&X[base];
  *(float4*)&xs[tid*4] = x;
  float v[4] = {x.x,x.y,x.z,x.w};
  ushort4 h4, l4;
  unsigned short hh[4], ll[4];
#pragma unroll
  for(int j=0;j<4;j++){ hh[j]=f2bf(v[j]); ll[j]=f2bf(v[j]-bf2f(hh[j])); }
  h4.x=hh[0];h4.y=hh[1];h4.z=hh[2];h4.w=hh[3];
  l4.x=ll[0];l4.y=ll[1];l4.z=ll[2];l4.w=ll[3];
  *(ushort4*)&hi[base] = h4;
  *(ushort4*)&lo[base] = l4;
  __syncthreads();
  int h = tid>>5, l = tid&31;
  float s = 0.f;
  for(int k=l;k<1024;k+=32) s += xs[k]*Wa[(size_t)k*8 + h];
  s += __shfl_xor(s,1); s += __shfl_xor(s,2); s += __shfl_xor(s,4);
  s += __shfl_xor(s,8); s += __shfl_xor(s,16);
  if(l==0){
    float z = s + dtb[h];
    float sp = (z > 20.f) ? z : log1pf(expf(z));
    fh[(size_t)n*8 + h] = -expf(A_log[h]) * sp;
  }
}

// ---------------- transpose+cast weights
__global__ void wtrans(const float* __restrict__ Wq, const float* __restrict__ Wk,
                       const float* __restrict__ Wv, const float* __restrict__ Wr,
                       const float* __restrict__ Wo,
                       unsigned short* __restrict__ WcatT3, unsigned short* __restrict__ WrThi,
                       unsigned short* __restrict__ WrTlo, unsigned short* __restrict__ WoT){
  __shared__ float tile[32][33];
  int z = blockIdx.z;
  const float* src = (z==0)?Wq:(z==1)?Wk:(z==2)?Wv:(z==3)?Wr:Wo;
  int c0 = blockIdx.x*32;
  int k0 = blockIdx.y*32;
  int tx = threadIdx.x, ty = threadIdx.y; // 32 x 8
#pragma unroll
  for(int r=0;r<32;r+=8)
    tile[ty+r][tx] = src[(size_t)(k0+ty+r)*1024 + c0 + tx];
  __syncthreads();
#pragma unroll
  for(int r=0;r<32;r+=8){
    int c = c0 + ty + r;
    int k = k0 + tx;
    float v = tile[tx][ty+r];
    if(z < 3){
      WcatT3[((size_t)(z*1024 + c))*1024 + k] = f2bf(v);
    } else if(z == 3){
      unsigned short hv = f2bf(v);
      WrThi[(size_t)c*1024 + k] = hv;
      WrTlo[(size_t)c*1024 + k] = f2bf(v - bf2f(hv));
    } else {
      WoT[(size_t)c*1024 + k] = f2bf(v);
    }
  }
}

// ---------------- fused proj + router GEMM, 768 uniform blocks, BK=64
__launch_bounds__(256)
__global__ void gemm_fused(const unsigned short* __restrict__ Xhi, const unsigned short* __restrict__ Xlo,
                           const unsigned short* __restrict__ WcatT3, const unsigned short* __restrict__ WrThi,
                           const unsigned short* __restrict__ WrTlo,
                           float* __restrict__ C1, float* __restrict__ Rp){
  __shared__ unsigned short As[128*64];
  __shared__ unsigned short Bs[128*64];
  int bid = blockIdx.x;
  int blk = (bid&7)*96 + (bid>>3);        // XCD-contiguous (768%8==0, bijective)
  const unsigned short *Ap, *Bp;
  float* Cout;
  int bx, by, N;
  if(blk < 384){
    bx = blk%24; by = blk/24; N = 3072;
    Ap = Xhi; Bp = WcatT3; Cout = C1;
  } else {
    int rb = blk-384;
    int seg = rb>>7, t2 = rb&127;
    bx = t2&7; by = t2>>3; N = 1024;
    Ap = (seg==2) ? Xlo : Xhi;
    Bp = (seg==1) ? WrTlo : WrThi;
    Cout = Rp + (size_t)seg*2048*1024;
  }
  int tid = threadIdx.x;
  int mBase = by*128, nBase = bx*128;
  int w = tid>>6, lane = tid&63, wr = w>>1, wc = w&1;
  int kg = lane>>4, l15 = lane&15;
  f32x4 acc[4][4];
#pragma unroll
  for(int i=0;i<4;i++)
#pragma unroll
    for(int j=0;j<4;j++) acc[i][j] = (f32x4){0.f,0.f,0.f,0.f};
  size_t aoff[4], boff[4];
#pragma unroll
  for(int p=0;p<4;p++){
    int c = p*256 + tid;
    int row = c>>3, sc = c&7, c8 = sc ^ (row&7);
    aoff[p] = (size_t)(mBase+row)*1024 + c8*8;
    boff[p] = (size_t)(nBase+row)*1024 + c8*8;
  }
  for(int kb=0; kb<1024; kb+=64){
#pragma unroll
    for(int p=0;p<4;p++){
      gl_lds16(Ap + aoff[p] + kb, &As[(p*256+tid)*8]);
      gl_lds16(Bp + boff[p] + kb, &Bs[(p*256+tid)*8]);
    }
    __syncthreads();
#pragma unroll
    for(int kk=0;kk<2;kk++){
      s16x8 afr[4], bfr[4];
#pragma unroll
      for(int f=0;f<4;f++){
        int rA = wr*64 + f*16 + l15;
        int rB = wc*64 + f*16 + l15;
        int cA = (kk*4 + kg) ^ (rA&7);
        int cB = (kk*4 + kg) ^ (rB&7);
        afr[f] = *(const s16x8*)&As[rA*64 + cA*8];
        bfr[f] = *(const s16x8*)&Bs[rB*64 + cB*8];
      }
#pragma unroll
      for(int fm=0;fm<4;fm++)
#pragma unroll
        for(int fn=0;fn<4;fn++)
          acc[fm][fn] = __builtin_amdgcn_mfma_f32_16x16x32_bf16(afr[fm], bfr[fn], acc[fm][fn], 0,0,0);
    }
    __syncthreads();
  }
#pragma unroll
  for(int fm=0;fm<4;fm++)
#pragma unroll
    for(int fn=0;fn<4;fn++){
      int col = nBase + wc*64 + fn*16 + l15;
      int row = mBase + wr*64 + fm*16 + kg*4;
#pragma unroll
      for(int r=0;r<4;r++) Cout[(size_t)(row+r)*N + col] = acc[fm][fn][r];
    }
}

// ---------------- output GEMM: 128x64 tiles, BK=64, 256 blocks
__launch_bounds__(256)
__global__ void gemm_out(const unsigned short* __restrict__ A,
                         const unsigned short* __restrict__ BT,
                         float* __restrict__ C){
  __shared__ unsigned short As[128*64];
  __shared__ unsigned short Bs[64*64];
  const int K = 1024, N = 1024;
  int tid = threadIdx.x;
  int mBase = blockIdx.y*128, nBase = blockIdx.x*64;
  int w = tid>>6, lane = tid&63;
  int mh = w>>1, nh = w&1;
  int kg = lane>>4, l15 = lane&15;
  f32x4 acc[4][2];
#pragma unroll
  for(int i=0;i<4;i++)
#pragma unroll
    for(int j=0;j<2;j++) acc[i][j] = (f32x4){0.f,0.f,0.f,0.f};
  size_t aoff[4], boff[2];
#pragma unroll
  for(int p=0;p<4;p++){
    int c = p*256 + tid;
    int row = c>>3, sc = c&7, c8 = sc ^ (row&7);
    aoff[p] = (size_t)(mBase+row)*K + c8*8;
  }
#pragma unroll
  for(int p=0;p<2;p++){
    int c = p*256 + tid;
    int row = c>>3, sc = c&7, c8 = sc ^ (row&7);
    boff[p] = (size_t)(nBase+row)*K + c8*8;
  }
  for(int kb=0; kb<K; kb+=64){
#pragma unroll
    for(int p=0;p<4;p++) gl_lds16(A + aoff[p] + kb, &As[(p*256+tid)*8]);
#pragma unroll
    for(int p=0;p<2;p++) gl_lds16(BT + boff[p] + kb, &Bs[(p*256+tid)*8]);
    __syncthreads();
#pragma unroll
    for(int kk=0;kk<2;kk++){
      s16x8 afr[4], bfr[2];
#pragma unroll
      for(int f=0;f<4;f++){
        int r = mh*64 + f*16 + l15;
        afr[f] = *(const s16x8*)&As[r*64 + ((kk*4+kg) ^ (r&7))*8];
      }
#pragma unroll
      for(int f=0;f<2;f++){
        int r = nh*32 + f*16 + l15;
        bfr[f] = *(const s16x8*)&Bs[r*64 + ((kk*4+kg) ^ (r&7))*8];
      }
#pragma unroll
      for(int fm=0;fm<4;fm++)
#pragma unroll
        for(int fn=0;fn<2;fn++)
          acc[fm][fn] = __builtin_amdgcn_mfma_f32_16x16x32_bf16(afr[fm], bfr[fn], acc[fm][fn], 0,0,0);
    }
    __syncthreads();
  }
#pragma unroll
  for(int fm=0;fm<4;fm++)
#pragma unroll
    for(int fn=0;fn<2;fn++){
      int col = nBase + nh*32 + fn*16 + l15;
      int row = mBase + mh*64 + fm*16 + kg*4;
#pragma unroll
      for(int r=0;r<4;r++) C[(size_t)(row+r)*N + col] = acc[fm][fn][r];
    }
}

// ---------------- FUSED postproc + chunk_sum: one block per (b,h,chunk)
// silu/rms/top32/gates -> F cumsum -> Kh,Vs (LDS) -> dS^T outer product.
// Top-32 keys: u32 = (score bits & ~127) | (127-slot). Sigmoid scores > 0 so
// bit pattern is order-monotone; 7-bit mantissa truncation only affects pairs
// within ~8e-6 (numerically nil); exact stable tie-break preserved.
__launch_bounds__(256)
__global__ void pp_sum(const float* __restrict__ C1, const float* __restrict__ Rp,
                       const float* __restrict__ fh, const float* __restrict__ qw,
                       const float* __restrict__ kw,
                       float* __restrict__ Qd, float* __restrict__ Wt,
                       float* __restrict__ Fd, float* __restrict__ Vd,
                       float* __restrict__ dS, float* __restrict__ E){
  __shared__ unsigned scU[32][128];   // 16 KB keys
  __shared__ float Fc[32][132];
  __shared__ float Kh[32][132];
  __shared__ float Vs[32][132];
  int blk = blockIdx.x, bh = blk>>5, c = blk&31;
  int b = bh>>3, h = bh&7;
  int tid = threadIdx.x;
  int g = tid>>5, i0 = (tid&31)*4;
  int n0 = b*1024 + c*32;
  size_t fbase = ((size_t)bh*T_ + (size_t)c*32)*128;
  float si_r[4][4];
  unsigned ki_r[4][4];
  // pass 1: router scores -> keys
#pragma unroll
  for(int v=0; v<4; v++){
    int t2 = v*8 + g;
    size_t rb = (size_t)(n0 + t2)*1024 + h*128 + i0;
    float4 r0 = *(const float4*)&Rp[rb];
    float4 r1 = *(const float4*)&Rp[2048ull*1024 + rb];
    float4 r2 = *(const float4*)&Rp[2ull*2048*1024 + rb];
    float rl[4] = {r0.x+r1.x+r2.x, r0.y+r1.y+r2.y, r0.z+r1.z+r2.z, r0.w+r1.w+r2.w};
#pragma unroll
    for(int j=0;j<4;j++){
      float si = 1.f/(1.f+expf(-rl[j]));
      si_r[v][j] = si;
      ki_r[v][j] = (__float_as_uint(si) & ~127u) | (unsigned)(127 - (i0+j));
      scU[t2][i0+j] = ki_r[v][j];
    }
  }
  __syncthreads();
  // pass 2: silu/rank/rms/gates
#pragma unroll
  for(int v=0; v<4; v++){
    int t2 = v*8 + g;
    int n = n0 + t2;
    size_t cb = (size_t)n*3072 + h*128 + i0;
    float4 q4 = *(const float4*)&C1[cb];
    float4 k4 = *(const float4*)&C1[cb + 1024];
    float4 v4 = *(const float4*)&C1[cb + 2048];
    float qv[4]={q4.x,q4.y,q4.z,q4.w}, kv[4]={k4.x,k4.y,k4.z,k4.w}, vraw[4]={v4.x,v4.y,v4.z,v4.w};
    float qs[4], ks[4], vv[4];
#pragma unroll
    for(int j=0;j<4;j++){
      qs[j] = qv[j]/(1.f+expf(-qv[j]));
      ks[j] = kv[j]/(1.f+expf(-kv[j]));
      vv[j] = vraw[j]/(1.f+expf(-vraw[j]));
    }
    int cnt[4]={0,0,0,0};
#pragma unroll 4
    for(int j=0;j<128;j+=4){
      uint4 kk4 = *(const uint4*)&scU[t2][j];
      unsigned kk[4]={kk4.x,kk4.y,kk4.z,kk4.w};
#pragma unroll
      for(int m=0;m<4;m++)
        cnt[m] += (int)(kk[0]>ki_r[v][m]) + (int)(kk[1]>ki_r[v][m])
                + (int)(kk[2]>ki_r[v][m]) + (int)(kk[3]>ki_r[v][m]);
    }
    bool sel[4];
#pragma unroll
    for(int m=0;m<4;m++) sel[m] = cnt[m] < 32;
    float x;
    x = qs[0]*qs[0]+qs[1]*qs[1]+qs[2]*qs[2]+qs[3]*qs[3];
    x+=__shfl_xor(x,1);x+=__shfl_xor(x,2);x+=__shfl_xor(x,4);x+=__shfl_xor(x,8);x+=__shfl_xor(x,16);
    float qrms = rsqrtf(x/128.f + 1e-5f);
    x = ks[0]*ks[0]+ks[1]*ks[1]+ks[2]*ks[2]+ks[3]*ks[3];
    x+=__shfl_xor(x,1);x+=__shfl_xor(x,2);x+=__shfl_xor(x,4);x+=__shfl_xor(x,8);x+=__shfl_xor(x,16);
    float krms = rsqrtf(x/128.f + 1e-5f);
    x = (sel[0]?si_r[v][0]:0.f)+(sel[1]?si_r[v][1]:0.f)+(sel[2]?si_r[v][2]:0.f)+(sel[3]?si_r[v][3]:0.f);
    x+=__shfl_xor(x,1);x+=__shfl_xor(x,2);x+=__shfl_xor(x,4);x+=__shfl_xor(x,8);x+=__shfl_xor(x,16);
    float winv = 1.f/(x + 1e-9f);
    float fhv = fh[(size_t)n*8 + h];
    float qd[4], wd[4], fd[4];
#pragma unroll
    for(int j=0;j<4;j++){
      float wgt = sel[j] ? si_r[v][j]*winv : 0.f;
      float f = fhv * wgt;
      qd[j] = qs[j]*qrms*qw[i0+j];
      wd[j] = (1.f - expf(f)) * (ks[j]*krms*kw[i0+j]);
      fd[j] = f;
    }
    size_t basev = fbase + (size_t)t2*128 + i0;
    float4 qo; qo.x=qd[0];qo.y=qd[1];qo.z=qd[2];qo.w=qd[3];
    float4 wo; wo.x=wd[0];wo.y=wd[1];wo.z=wd[2];wo.w=wd[3];
    float4 vo; vo.x=vv[0];vo.y=vv[1];vo.z=vv[2];vo.w=vv[3];
    *(float4*)&Qd[basev] = qo;
    *(float4*)&Wt[basev] = wo;
    *(float4*)&Vd[basev] = vo;
    *(float4*)&Fc[t2][i0] = make_float4(fd[0],fd[1],fd[2],fd[3]);
    *(float4*)&Kh[t2][i0] = wo;
    *(float4*)&Vs[t2][i0] = vo;
  }
  __syncthreads();
  // cumsum F over tokens (column per thread)
  if(tid < 128){
    float a = 0.f;
    for(int t2=0;t2<32;t2++){ a += Fc[t2][tid]; Fc[t2][tid] = a; }
  }
  __syncthreads();
  // write Fd (cumsum), scale Kh by exp(Ftot - fc), write E
#pragma unroll
  for(int v=0; v<4; v++){
    int e = v*1024 + tid*4;
    int t2 = e>>7, i2 = e&127;
    float4 fc4 = *(const float4*)&Fc[t2][i2];
    *(float4*)&Fd[fbase + e] = fc4;
    float4 ft  = *(const float4*)&Fc[31][i2];
    float4 kh  = *(const float4*)&Kh[t2][i2];
    kh.x *= expf(ft.x - fc4.x);
    kh.y *= expf(ft.y - fc4.y);
    kh.z *= expf(ft.z - fc4.z);
    kh.w *= expf(ft.w - fc4.w);
    *(float4*)&Kh[t2][i2] = kh;
  }
  if(tid < 128) E[((size_t)bh*32 + c)*128 + tid] = expf(Fc[31][tid]);
  __syncthreads();
  // dS^T = (Kh^T Vs)^T
  int w = tid>>6, lane = tid&63;
  int ig = lane>>3, jg = lane&7;
  f32x4 acc[4][4];
#pragma unroll
  for(int a=0;a<4;a++)
#pragma unroll
    for(int q=0;q<4;q++) acc[a][q] = (f32x4){0.f,0.f,0.f,0.f};
#pragma unroll 4
  for(int t2=0;t2<32;t2++){
    float4 kq = *(const float4*)&Kh[t2][w*32 + ig*4];
    float4 v0 = *(const float4*)&Vs[t2][jg*4];
    float4 v1 = *(const float4*)&Vs[t2][jg*4 + 32];
    float4 v2 = *(const float4*)&Vs[t2][jg*4 + 64];
    float4 v3 = *(const float4*)&Vs[t2][jg*4 + 96];
    float kk[4] = {kq.x,kq.y,kq.z,kq.w};
#pragma unroll
    for(int a=0;a<4;a++){
      acc[a][0] += kk[a]*(f32x4){v0.x,v0.y,v0.z,v0.w};
      acc[a][1] += kk[a]*(f32x4){v1.x,v1.y,v1.z,v1.w};
      acc[a][2] += kk[a]*(f32x4){v2.x,v2.y,v2.z,v2.w};
      acc[a][3] += kk[a]*(f32x4){v3.x,v3.y,v3.z,v3.w};
    }
  }
  size_t dbase = (size_t)blk*16384;
#pragma unroll
  for(int q=0;q<4;q++)
#pragma unroll
    for(int jj=0;jj<4;jj++){
      float4 o4 = make_float4(acc[0][q][jj],acc[1][q][jj],acc[2][q][jj],acc[3][q][jj]);
      *(float4*)&dS[dbase + (size_t)(jg*4 + 32*q + jj)*128 + w*32 + ig*4] = o4;
    }
}

// ---------------- phase 2: inter-chunk scan on dS_T (float4 + manual prefetch)
__global__ void scan_k(float* __restrict__ dS, const float* __restrict__ E){
  int g = blockIdx.x*256 + threadIdx.x;   // 65536 threads: (bh, float4 idx)
  int bh = g>>12;
  int e4 = (g&4095)*4;
  int i0 = e4 & 127;
  size_t base  = (size_t)bh*32*16384 + e4;
  size_t ebase = (size_t)bh*32*128 + i0;
  float4 S = make_float4(0.f,0.f,0.f,0.f);
  float4 d  = *(const float4*)&dS[base];
  float4 Ec = *(const float4*)&E[ebase];
  for(int c=0;c<32;c++){
    float4 dn = make_float4(0,0,0,0), En = make_float4(0,0,0,0);
    if(c < 31){
      dn = *(const float4*)&dS[base + (size_t)(c+1)*16384];
      En = *(const float4*)&E[ebase + (size_t)(c+1)*128];
    }
    *(float4*)&dS[base + (size_t)c*16384] = S;
    S.x = Ec.x*S.x + d.x;
    S.y = Ec.y*S.y + d.y;
    S.z = Ec.z*S.z + d.z;
    S.w = Ec.w*S.w + d.w;
    d = dn; Ec = En;
  }
}

// ---------------- phase 3: O = qt @ S + tril(qt kt^T) @ V, full MFMA
__launch_bounds__(256)
__global__ void chunk_out(const float* __restrict__ Qd, const float* __restrict__ Wt,
                          const float* __restrict__ Fd, const float* __restrict__ Vd,
                          const float* __restrict__ ST, float* __restrict__ O){
  __shared__ unsigned int qtP[32][132];   // packed bf16 hi|lo, [tok][k]
  __shared__ unsigned int ktP[32][132];
  __shared__ unsigned int Vt[128][36];    // packed, [vdim][tok]
  __shared__ float Amat[32][40];          // tril(qt kt^T), f32
  int blk = blockIdx.x, bh = blk>>5, c = blk&31;
  int b = bh>>3, h = bh&7;
  int tid = threadIdx.x, w = tid>>6, lane = tid&63;
  int m = lane&31, hi = lane>>5;
  size_t fbase = ((size_t)bh*T_ + (size_t)c*32)*128;
#pragma unroll
  for(int p=0;p<4;p++){
    int e = p*1024 + tid*4;
    int t2 = e>>7, i0 = e&127;
    float4 f4 = *(const float4*)&Fd[fbase + e];
    float4 q4 = *(const float4*)&Qd[fbase + e];
    float4 w4 = *(const float4*)&Wt[fbase + e];
    float fv[4] = {f4.x,f4.y,f4.z,f4.w};
    float qv[4] = {q4.x,q4.y,q4.z,q4.w};
    float wv[4] = {w4.x,w4.y,w4.z,w4.w};
    uint4 qp, kp;
    unsigned int qa[4], ka[4];
#pragma unroll
    for(int j=0;j<4;j++){
      float ef = expf(fv[j]);
      qa[j] = pack_hl(qv[j]*ef);
      ka[j] = pack_hl(wv[j]/ef);
    }
    qp.x=qa[0]; qp.y=qa[1]; qp.z=qa[2]; qp.w=qa[3];
    kp.x=ka[0]; kp.y=ka[1]; kp.z=ka[2]; kp.w=ka[3];
    *(uint4*)&qtP[t2][i0] = qp;
    *(uint4*)&ktP[t2][i0] = kp;
  }
  {
    int n = tid&127, th = (tid>>7)*16;
    unsigned int vp[16];
#pragma unroll
    for(int j=0;j<16;j++) vp[j] = pack_hl(Vd[fbase + (size_t)(th+j)*128 + n]);
#pragma unroll
    for(int j=0;j<16;j+=4){
      uint4 v4; v4.x=vp[j]; v4.y=vp[j+1]; v4.z=vp[j+2]; v4.w=vp[j+3];
      *(uint4*)&Vt[n][th+j] = v4;
    }
  }
  __syncthreads();
  if(w == 0){
    f32x16 am;
#pragma unroll
    for(int r=0;r<16;r++) am[r] = 0.f;
#pragma unroll
    for(int s=0;s<8;s++){
      int ko = s*16 + hi*8;
      uint4 qa = *(const uint4*)&qtP[m][ko];
      uint4 qb = *(const uint4*)&qtP[m][ko+4];
      uint4 ka = *(const uint4*)&ktP[m][ko];
      uint4 kb = *(const uint4*)&ktP[m][ko+4];
      s16x8 qh, ql, kh, kl;
      unsigned int qw_[8] = {qa.x,qa.y,qa.z,qa.w,qb.x,qb.y,qb.z,qb.w};
      unsigned int kw_[8] = {ka.x,ka.y,ka.z,ka.w,kb.x,kb.y,kb.z,kb.w};
#pragma unroll
      for(int j=0;j<8;j++){
        qh[j]=(short)(qw_[j]>>16); ql[j]=(short)(qw_[j]&0xffff);
        kh[j]=(short)(kw_[j]>>16); kl[j]=(short)(kw_[j]&0xffff);
      }
      am = __builtin_amdgcn_mfma_f32_32x32x16_bf16(qh, kh, am, 0,0,0);
      am = __builtin_amdgcn_mfma_f32_32x32x16_bf16(qh, kl, am, 0,0,0);
      am = __builtin_amdgcn_mfma_f32_32x32x16_bf16(ql, kh, am, 0,0,0);
    }
#pragma unroll
    for(int r=0;r<16;r++){
      int rm = (r&3) + 8*(r>>2) + 4*hi;
      Amat[rm][m] = (m <= rm) ? am[r] : 0.f;
    }
  }
  f32x16 oacc;
#pragma unroll
  for(int r=0;r<16;r++) oacc[r] = 0.f;
  const float* Sp = ST + (size_t)blk*16384 + (size_t)(w*32 + m)*128;
#pragma unroll
  for(int s=0;s<8;s++){
    int ko = s*16 + hi*8;
    uint4 qa = *(const uint4*)&qtP[m][ko];
    uint4 qb = *(const uint4*)&qtP[m][ko+4];
    s16x8 qh, ql;
    unsigned int qw_[8] = {qa.x,qa.y,qa.z,qa.w,qb.x,qb.y,qb.z,qb.w};
#pragma unroll
    for(int j=0;j<8;j++){ qh[j]=(short)(qw_[j]>>16); ql[j]=(short)(qw_[j]&0xffff); }
    float4 s0 = *(const float4*)&Sp[ko];
    float4 s1 = *(const float4*)&Sp[ko+4];
    float sv[8] = {s0.x,s0.y,s0.z,s0.w,s1.x,s1.y,s1.z,s1.w};
    s16x8 sh, sl;
#pragma unroll
    for(int j=0;j<8;j++){
      unsigned short hh = f2bf(sv[j]);
      sh[j] = (short)hh; sl[j] = (short)f2bf(sv[j]-bf2f(hh));
    }
    oacc = __builtin_amdgcn_mfma_f32_32x32x16_bf16(qh, sh, oacc, 0,0,0);
    oacc = __builtin_amdgcn_mfma_f32_32x32x16_bf16(qh, sl, oacc, 0,0,0);
    oacc = __builtin_amdgcn_mfma_f32_32x32x16_bf16(ql, sh, oacc, 0,0,0);
  }
  __syncthreads();
#pragma unroll
  for(int s=0;s<2;s++){
    int uo = s*16 + hi*8;
    float4 a0 = *(const float4*)&Amat[m][uo];
    float4 a1 = *(const float4*)&Amat[m][uo+4];
    float av[8] = {a0.x,a0.y,a0.z,a0.w,a1.x,a1.y,a1.z,a1.w};
    s16x8 ah, al;
#pragma unroll
    for(int j=0;j<8;j++){
      unsigned short hh = f2bf(av[j]);
      ah[j] = (short)hh; al[j] = (short)f2bf(av[j]-bf2f(hh));
    }
    uint4 v0 = *(const uint4*)&Vt[w*32 + m][uo];
    uint4 v1 = *(const uint4*)&Vt[w*32 + m][uo+4];
    unsigned int vw[8] = {v0.x,v0.y,v0.z,v0.w,v1.x,v1.y,v1.z,v1.w};
    s16x8 vh, vl;
#pragma unroll
    for(int j=0;j<8;j++){ vh[j]=(short)(vw[j]>>16); vl[j]=(short)(vw[j]&0xffff); }
    oacc = __builtin_amdgcn_mfma_f32_32x32x16_bf16(ah, vh, oacc, 0,0,0);
    oacc = __builtin_amdgcn_mfma_f32_32x32x16_bf16(ah, vl, oacc, 0,0,0);
    oacc = __builtin_amdgcn_mfma_f32_32x32x16_bf16(al, vh, oacc, 0,0,0);
  }
#pragma unroll
  for(int r=0;r<16;r++){
    int tok = (r&3) + 8*(r>>2) + 4*hi;
    O[((size_t)(b*T_ + c*32 + tok))*1024 + h*128 + w*32 + m] = oacc[r];
  }
}

// ---------------- final g-RMSNorm + cast bf16
__global__ void gnorm_k(const float* __restrict__ Ob, const float* __restrict__ gw,
                        unsigned short* __restrict__ On){
  __shared__ float red[4];
  int n = blockIdx.x, tid = threadIdx.x;
  size_t base = (size_t)n*1024 + tid*4;
  float4 x = *(const float4*)&Ob[base];
  float ss = x.x*x.x + x.y*x.y + x.z*x.z + x.w*x.w;
  ss+=__shfl_xor(ss,1);ss+=__shfl_xor(ss,2);ss+=__shfl_xor(ss,4);
  ss+=__shfl_xor(ss,8);ss+=__shfl_xor(ss,16);ss+=__shfl_xor(ss,32);
  if((tid&63)==0) red[tid>>6]=ss;
  __syncthreads();
  float sc = rsqrtf((red[0]+red[1]+red[2]+red[3])/1024.f + 1e-5f);
  float4 g = *(const float4*)&gw[tid*4];
  ushort4 o4;
  o4.x=f2bf(x.x*sc*g.x); o4.y=f2bf(x.y*sc*g.y);
  o4.z=f2bf(x.z*sc*g.z); o4.w=f2bf(x.w*sc*g.w);
  *(ushort4*)&On[base]=o4;
}

extern "C" void kernel_launch(void* const* d_in, const int* in_sizes, int n_in,
                              void* d_out, int out_size, void* d_ws, size_t ws_size,
                              hipStream_t stream){
  const float* hs   = (const float*)d_in[0];
  const float* Wq   = (const float*)d_in[1];
  const float* Wk   = (const float*)d_in[2];
  const float* Wv   = (const float*)d_in[3];
  const float* Wr   = (const float*)d_in[4];
  const float* Wa   = (const float*)d_in[5];
  const float* A_log= (const float*)d_in[6];
  const float* dtb  = (const float*)d_in[7];
  const float* qw   = (const float*)d_in[8];
  const float* kw   = (const float*)d_in[9];
  const float* gw   = (const float*)d_in[10];
  const float* Wo   = (const float*)d_in[11];
  float* out = (float*)d_out;

  char* wsp = (char*)d_ws;
  size_t off = 0;
  auto alloc = [&](size_t bytes)->void*{ void* p = wsp + off; off += (bytes + 255) & ~(size_t)255; return p; };
  unsigned short* Xhi    = (unsigned short*)alloc(2048ull*1024*2);
  unsigned short* Xlo    = (unsigned short*)alloc(2048ull*1024*2);
  unsigned short* WcatT3 = (unsigned short*)alloc(3072ull*1024*2);
  unsigned short* WrThi  = (unsigned short*)alloc(1024ull*1024*2);
  unsigned short* WrTlo  = (unsigned short*)alloc(1024ull*1024*2);
  unsigned short* WoT    = (unsigned short*)alloc(1024ull*1024*2);
  float* C1 = (float*)alloc(2048ull*3072*4);
  float* Rp = (float*)alloc(3ull*2048*1024*4);   // router partials (separate: pp_sum reads Rp while writing dS)
  float* fh = (float*)alloc(2048ull*8*4);
  float* Qd = (float*)alloc(16ull*1024*128*4);
  float* Wt = (float*)alloc(16ull*1024*128*4);
  float* Fd = (float*)alloc(16ull*1024*128*4);
  float* Vd = (float*)alloc(16ull*1024*128*4);
  float* E  = (float*)alloc(16ull*32*128*4);
  float* dS = (float*)alloc(16ull*32*16384*4);
  float* Ob = (float*)alloc(2048ull*1024*4);
  unsigned short* On = (unsigned short*)alloc(2048ull*1024*2);
  (void)ws_size; (void)in_sizes; (void)n_in; (void)out_size;

  prep_k     <<<dim3(2048),        dim3(256),   0, stream>>>(hs, Wa, A_log, dtb, Xhi, Xlo, fh);
  wtrans     <<<dim3(32,32,5),     dim3(32,8),  0, stream>>>(Wq,Wk,Wv,Wr,Wo, WcatT3,WrThi,WrTlo,WoT);
  gemm_fused <<<dim3(768),         dim3(256),   0, stream>>>(Xhi, Xlo, WcatT3, WrThi, WrTlo, C1, Rp);
  pp_sum     <<<dim3(512),         dim3(256),   0, stream>>>(C1, Rp, fh, qw, kw, Qd, Wt, Fd, Vd, dS, E);
  scan_k     <<<dim3(256),         dim3(256),   0, stream>>>(dS, E);
  chunk_out  <<<dim3(512),         dim3(256),   0, stream>>>(Qd, Wt, Fd, Vd, dS, Ob);
  gnorm_k    <<<dim3(2048),        dim3(256),   0, stream>>>(Ob, gw, On);
  gemm_out   <<<dim3(16,16),       dim3(256),   0, stream>>>(On, WoT, out);
}

// Round 8
// 246.590 us; speedup vs baseline: 1.4176x; 1.0182x over previous
//
#include <hip/hip_runtime.h>
#include <stdint.h>
#include <stddef.h>

#define H_ 8
#define T_ 1024

typedef __attribute__((ext_vector_type(8))) short s16x8;
typedef __attribute__((ext_vector_type(4))) float f32x4;
typedef __attribute__((ext_vector_type(16))) float f32x16;

static __device__ __forceinline__ unsigned short f2bf(float f){
  unsigned u = __float_as_uint(f);
  u += 0x7fffu + ((u >> 16) & 1u);          // round-to-nearest-even
  return (unsigned short)(u >> 16);
}
static __device__ __forceinline__ float bf2f(unsigned short b){
  return __uint_as_float(((unsigned)b) << 16);
}
static __device__ __forceinline__ unsigned int pack_hl(float x){
  unsigned short h = f2bf(x);
  unsigned short l = f2bf(x - bf2f(h));
  return ((unsigned int)h << 16) | l;
}
// async global->LDS 16B (m97 pattern; HW: wave-uniform base + lane*16)
static __device__ __forceinline__ void gl_lds16(const unsigned short* g, unsigned short* l){
  __builtin_amdgcn_global_load_lds((const __attribute__((address_space(1))) unsigned int*)g,
                                   (__attribute__((address_space(3))) unsigned int*)l,
                                   16, 0, 0);
}

// ---------------- prep: cast hs to bf16 hi+lo AND f_head (fused)
__global__ void prep_k(const float* __restrict__ X, const float* __restrict__ Wa,
                       const float* __restrict__ A_log, const float* __restrict__ dtb,
                       unsigned short* __restrict__ hi, unsigned short* __restrict__ lo,
                       float* __restrict__ fh){
  __shared__ float xs[1024];
  int n = blockIdx.x, tid = threadIdx.x;   // 256 threads
  size_t base = (size_t)n*1024 + tid*4;
  float4 x = *(const float4*)&X[base];
  *(float4*)&xs[tid*4] = x;
  float v[4] = {x.x,x.y,x.z,x.w};
  ushort4 h4, l4;
  unsigned short hh[4], ll[4];
#pragma unroll
  for(int j=0;j<4;j++){ hh[j]=f2bf(v[j]); ll[j]=f2bf(v[j]-bf2f(hh[j])); }
  h4.x=hh[0];h4.y=hh[1];h4.z=hh[2];h4.w=hh[3];
  l4.x=ll[0];l4.y=ll[1];l4.z=ll[2];l4.w=ll[3];
  *(ushort4*)&hi[base] = h4;
  *(ushort4*)&lo[base] = l4;
  __syncthreads();
  int h = tid>>5, l = tid&31;
  float s = 0.f;
  for(int k=l;k<1024;k+=32) s += xs[k]*Wa[(size_t)k*8 + h];
  s += __shfl_xor(s,1); s += __shfl_xor(s,2); s += __shfl_xor(s,4);
  s += __shfl_xor(s,8); s += __shfl_xor(s,16);
  if(l==0){
    float z = s + dtb[h];
    float sp = (z > 20.f) ? z : log1pf(expf(z));
    fh[(size_t)n*8 + h] = -expf(A_log[h]) * sp;
  }
}

// ---------------- transpose+cast weights
__global__ void wtrans(const float* __restrict__ Wq, const float* __restrict__ Wk,
                       const float* __restrict__ Wv, const float* __restrict__ Wr,
                       const float* __restrict__ Wo,
                       unsigned short* __restrict__ WcatT3, unsigned short* __restrict__ WrThi,
                       unsigned short* __restrict__ WrTlo, unsigned short* __restrict__ WoT){
  __shared__ float tile[32][33];
  int z = blockIdx.z;
  const float* src = (z==0)?Wq:(z==1)?Wk:(z==2)?Wv:(z==3)?Wr:Wo;
  int c0 = blockIdx.x*32;
  int k0 = blockIdx.y*32;
  int tx = threadIdx.x, ty = threadIdx.y; // 32 x 8
#pragma unroll
  for(int r=0;r<32;r+=8)
    tile[ty+r][tx] = src[(size_t)(k0+ty+r)*1024 + c0 + tx];
  __syncthreads();
#pragma unroll
  for(int r=0;r<32;r+=8){
    int c = c0 + ty + r;
    int k = k0 + tx;
    float v = tile[tx][ty+r];
    if(z < 3){
      WcatT3[((size_t)(z*1024 + c))*1024 + k] = f2bf(v);
    } else if(z == 3){
      unsigned short hv = f2bf(v);
      WrThi[(size_t)c*1024 + k] = hv;
      WrTlo[(size_t)c*1024 + k] = f2bf(v - bf2f(hv));
    } else {
      WoT[(size_t)c*1024 + k] = f2bf(v);
    }
  }
}

// ---------------- fused proj + router GEMM, 768 uniform blocks, BK=64
__launch_bounds__(256)
__global__ void gemm_fused(const unsigned short* __restrict__ Xhi, const unsigned short* __restrict__ Xlo,
                           const unsigned short* __restrict__ WcatT3, const unsigned short* __restrict__ WrThi,
                           const unsigned short* __restrict__ WrTlo,
                           float* __restrict__ C1, float* __restrict__ Rp){
  __shared__ unsigned short As[128*64];
  __shared__ unsigned short Bs[128*64];
  int bid = blockIdx.x;
  int blk = (bid&7)*96 + (bid>>3);        // XCD-contiguous (768%8==0, bijective)
  const unsigned short *Ap, *Bp;
  float* Cout;
  int bx, by, N;
  if(blk < 384){
    bx = blk%24; by = blk/24; N = 3072;
    Ap = Xhi; Bp = WcatT3; Cout = C1;
  } else {
    int rb = blk-384;
    int seg = rb>>7, t2 = rb&127;
    bx = t2&7; by = t2>>3; N = 1024;
    Ap = (seg==2) ? Xlo : Xhi;
    Bp = (seg==1) ? WrTlo : WrThi;
    Cout = Rp + (size_t)seg*2048*1024;
  }
  int tid = threadIdx.x;
  int mBase = by*128, nBase = bx*128;
  int w = tid>>6, lane = tid&63, wr = w>>1, wc = w&1;
  int kg = lane>>4, l15 = lane&15;
  f32x4 acc[4][4];
#pragma unroll
  for(int i=0;i<4;i++)
#pragma unroll
    for(int j=0;j<4;j++) acc[i][j] = (f32x4){0.f,0.f,0.f,0.f};
  size_t aoff[4], boff[4];
#pragma unroll
  for(int p=0;p<4;p++){
    int c = p*256 + tid;
    int row = c>>3, sc = c&7, c8 = sc ^ (row&7);
    aoff[p] = (size_t)(mBase+row)*1024 + c8*8;
    boff[p] = (size_t)(nBase+row)*1024 + c8*8;
  }
  for(int kb=0; kb<1024; kb+=64){
#pragma unroll
    for(int p=0;p<4;p++){
      gl_lds16(Ap + aoff[p] + kb, &As[(p*256+tid)*8]);
      gl_lds16(Bp + boff[p] + kb, &Bs[(p*256+tid)*8]);
    }
    __syncthreads();
#pragma unroll
    for(int kk=0;kk<2;kk++){
      s16x8 afr[4], bfr[4];
#pragma unroll
      for(int f=0;f<4;f++){
        int rA = wr*64 + f*16 + l15;
        int rB = wc*64 + f*16 + l15;
        int cA = (kk*4 + kg) ^ (rA&7);
        int cB = (kk*4 + kg) ^ (rB&7);
        afr[f] = *(const s16x8*)&As[rA*64 + cA*8];
        bfr[f] = *(const s16x8*)&Bs[rB*64 + cB*8];
      }
#pragma unroll
      for(int fm=0;fm<4;fm++)
#pragma unroll
        for(int fn=0;fn<4;fn++)
          acc[fm][fn] = __builtin_amdgcn_mfma_f32_16x16x32_bf16(afr[fm], bfr[fn], acc[fm][fn], 0,0,0);
    }
    __syncthreads();
  }
#pragma unroll
  for(int fm=0;fm<4;fm++)
#pragma unroll
    for(int fn=0;fn<4;fn++){
      int col = nBase + wc*64 + fn*16 + l15;
      int row = mBase + wr*64 + fm*16 + kg*4;
#pragma unroll
      for(int r=0;r<4;r++) Cout[(size_t)(row+r)*N + col] = acc[fm][fn][r];
    }
}

// ---------------- output GEMM: 128x64 tiles, BK=64, 256 blocks
__launch_bounds__(256)
__global__ void gemm_out(const unsigned short* __restrict__ A,
                         const unsigned short* __restrict__ BT,
                         float* __restrict__ C){
  __shared__ unsigned short As[128*64];
  __shared__ unsigned short Bs[64*64];
  const int K = 1024, N = 1024;
  int tid = threadIdx.x;
  int mBase = blockIdx.y*128, nBase = blockIdx.x*64;
  int w = tid>>6, lane = tid&63;
  int mh = w>>1, nh = w&1;
  int kg = lane>>4, l15 = lane&15;
  f32x4 acc[4][2];
#pragma unroll
  for(int i=0;i<4;i++)
#pragma unroll
    for(int j=0;j<2;j++) acc[i][j] = (f32x4){0.f,0.f,0.f,0.f};
  size_t aoff[4], boff[2];
#pragma unroll
  for(int p=0;p<4;p++){
    int c = p*256 + tid;
    int row = c>>3, sc = c&7, c8 = sc ^ (row&7);
    aoff[p] = (size_t)(mBase+row)*K + c8*8;
  }
#pragma unroll
  for(int p=0;p<2;p++){
    int c = p*256 + tid;
    int row = c>>3, sc = c&7, c8 = sc ^ (row&7);
    boff[p] = (size_t)(nBase+row)*K + c8*8;
  }
  for(int kb=0; kb<K; kb+=64){
#pragma unroll
    for(int p=0;p<4;p++) gl_lds16(A + aoff[p] + kb, &As[(p*256+tid)*8]);
#pragma unroll
    for(int p=0;p<2;p++) gl_lds16(BT + boff[p] + kb, &Bs[(p*256+tid)*8]);
    __syncthreads();
#pragma unroll
    for(int kk=0;kk<2;kk++){
      s16x8 afr[4], bfr[2];
#pragma unroll
      for(int f=0;f<4;f++){
        int r = mh*64 + f*16 + l15;
        afr[f] = *(const s16x8*)&As[r*64 + ((kk*4+kg) ^ (r&7))*8];
      }
#pragma unroll
      for(int f=0;f<2;f++){
        int r = nh*32 + f*16 + l15;
        bfr[f] = *(const s16x8*)&Bs[r*64 + ((kk*4+kg) ^ (r&7))*8];
      }
#pragma unroll
      for(int fm=0;fm<4;fm++)
#pragma unroll
        for(int fn=0;fn<2;fn++)
          acc[fm][fn] = __builtin_amdgcn_mfma_f32_16x16x32_bf16(afr[fm], bfr[fn], acc[fm][fn], 0,0,0);
    }
    __syncthreads();
  }
#pragma unroll
  for(int fm=0;fm<4;fm++)
#pragma unroll
    for(int fn=0;fn<2;fn++){
      int col = nBase + nh*32 + fn*16 + l15;
      int row = mBase + mh*64 + fm*16 + kg*4;
#pragma unroll
      for(int r=0;r<4;r++) C[(size_t)(row+r)*N + col] = acc[fm][fn][r];
    }
}

// ---------------- FUSED postproc + chunk_sum, MFMA dS, 48.9 KB LDS (3 blocks/CU)
// Ranking keys buffer ALIASES VsP (keys dead after ranking; 2 barriers apart).
// dS^T = Vs^T Kh via mfma_32x32x16_bf16 hi/lo 3-term (rel err ~1e-5).
__launch_bounds__(256, 3)
__global__ void pp_sum(const float* __restrict__ C1, const float* __restrict__ Rp,
                       const float* __restrict__ fh, const float* __restrict__ qw,
                       const float* __restrict__ kw,
                       float* __restrict__ Qd, float* __restrict__ Wt,
                       float* __restrict__ Fd, float* __restrict__ Vd,
                       float* __restrict__ dS, float* __restrict__ E){
  __shared__ float Fc[32][132];        // 16.9 KB
  __shared__ unsigned KhP[32][128];    // 16 KB packed bf16 hi|lo
  __shared__ unsigned VsP[32][128];    // 16 KB; doubles as ranking keys (scU)
  unsigned (*scU)[128] = VsP;
  int blk = blockIdx.x, bh = blk>>5, c = blk&31;
  int b = bh>>3, h = bh&7;
  int tid = threadIdx.x;
  int g = tid>>5, i0 = (tid&31)*4;
  int n0 = b*1024 + c*32;
  size_t fbase = ((size_t)bh*T_ + (size_t)c*32)*128;
  float si_r[4][4];
  unsigned ki_r[4][4];
  // pass 1: router scores -> keys (key = (score bits & ~127) | (127-slot))
#pragma unroll
  for(int v=0; v<4; v++){
    int t2 = v*8 + g;
    size_t rb = (size_t)(n0 + t2)*1024 + h*128 + i0;
    float4 r0 = *(const float4*)&Rp[rb];
    float4 r1 = *(const float4*)&Rp[2048ull*1024 + rb];
    float4 r2 = *(const float4*)&Rp[2ull*2048*1024 + rb];
    float rl[4] = {r0.x+r1.x+r2.x, r0.y+r1.y+r2.y, r0.z+r1.z+r2.z, r0.w+r1.w+r2.w};
#pragma unroll
    for(int j=0;j<4;j++){
      float si = 1.f/(1.f+expf(-rl[j]));
      si_r[v][j] = si;
      ki_r[v][j] = (__float_as_uint(si) & ~127u) | (unsigned)(127 - (i0+j));
      scU[t2][i0+j] = ki_r[v][j];
    }
  }
  __syncthreads();
  // pass 2a: silu / rank / rms / gates; hold wd,vv in regs for post-cumsum pack
  float wd_r[4][4], vv_r[4][4];
#pragma unroll
  for(int v=0; v<4; v++){
    int t2 = v*8 + g;
    int n = n0 + t2;
    size_t cb = (size_t)n*3072 + h*128 + i0;
    float4 q4 = *(const float4*)&C1[cb];
    float4 k4 = *(const float4*)&C1[cb + 1024];
    float4 v4 = *(const float4*)&C1[cb + 2048];
    float qv[4]={q4.x,q4.y,q4.z,q4.w}, kv[4]={k4.x,k4.y,k4.z,k4.w}, vraw[4]={v4.x,v4.y,v4.z,v4.w};
    float qs[4], ks[4];
#pragma unroll
    for(int j=0;j<4;j++){
      qs[j] = qv[j]/(1.f+expf(-qv[j]));
      ks[j] = kv[j]/(1.f+expf(-kv[j]));
      vv_r[v][j] = vraw[j]/(1.f+expf(-vraw[j]));
    }
    int cnt[4]={0,0,0,0};
#pragma unroll 4
    for(int j=0;j<128;j+=4){
      uint4 kk4 = *(const uint4*)&scU[t2][j];
      unsigned kk[4]={kk4.x,kk4.y,kk4.z,kk4.w};
#pragma unroll
      for(int m=0;m<4;m++)
        cnt[m] += (int)(kk[0]>ki_r[v][m]) + (int)(kk[1]>ki_r[v][m])
                + (int)(kk[2]>ki_r[v][m]) + (int)(kk[3]>ki_r[v][m]);
    }
    bool sel[4];
#pragma unroll
    for(int m=0;m<4;m++) sel[m] = cnt[m] < 32;   // exact stable top-32
    float x;
    x = qs[0]*qs[0]+qs[1]*qs[1]+qs[2]*qs[2]+qs[3]*qs[3];
    x+=__shfl_xor(x,1);x+=__shfl_xor(x,2);x+=__shfl_xor(x,4);x+=__shfl_xor(x,8);x+=__shfl_xor(x,16);
    float qrms = rsqrtf(x/128.f + 1e-5f);
    x = ks[0]*ks[0]+ks[1]*ks[1]+ks[2]*ks[2]+ks[3]*ks[3];
    x+=__shfl_xor(x,1);x+=__shfl_xor(x,2);x+=__shfl_xor(x,4);x+=__shfl_xor(x,8);x+=__shfl_xor(x,16);
    float krms = rsqrtf(x/128.f + 1e-5f);
    x = (sel[0]?si_r[v][0]:0.f)+(sel[1]?si_r[v][1]:0.f)+(sel[2]?si_r[v][2]:0.f)+(sel[3]?si_r[v][3]:0.f);
    x+=__shfl_xor(x,1);x+=__shfl_xor(x,2);x+=__shfl_xor(x,4);x+=__shfl_xor(x,8);x+=__shfl_xor(x,16);
    float winv = 1.f/(x + 1e-9f);
    float fhv = fh[(size_t)n*8 + h];
    float qd[4], fd[4];
#pragma unroll
    for(int j=0;j<4;j++){
      float wgt = sel[j] ? si_r[v][j]*winv : 0.f;
      float f = fhv * wgt;
      qd[j] = qs[j]*qrms*qw[i0+j];
      wd_r[v][j] = (1.f - expf(f)) * (ks[j]*krms*kw[i0+j]);
      fd[j] = f;
    }
    size_t basev = fbase + (size_t)t2*128 + i0;
    float4 qo; qo.x=qd[0];qo.y=qd[1];qo.z=qd[2];qo.w=qd[3];
    float4 wo; wo.x=wd_r[v][0];wo.y=wd_r[v][1];wo.z=wd_r[v][2];wo.w=wd_r[v][3];
    float4 vo; vo.x=vv_r[v][0];vo.y=vv_r[v][1];vo.z=vv_r[v][2];vo.w=vv_r[v][3];
    *(float4*)&Qd[basev] = qo;
    *(float4*)&Wt[basev] = wo;
    *(float4*)&Vd[basev] = vo;
    *(float4*)&Fc[t2][i0] = make_float4(fd[0],fd[1],fd[2],fd[3]);
  }
  __syncthreads();
  // cumsum F over tokens (column per thread)
  if(tid < 128){
    float a = 0.f;
    for(int t2=0;t2<32;t2++){ a += Fc[t2][tid]; Fc[t2][tid] = a; }
  }
  __syncthreads();
  // pass 2b: write Fd (cumsum), pack Kh*exp(Ftot-fc) and Vs (overwrites keys)
#pragma unroll
  for(int v=0; v<4; v++){
    int t2 = v*8 + g;
    size_t basev = fbase + (size_t)t2*128 + i0;
    float4 fc4 = *(const float4*)&Fc[t2][i0];
    *(float4*)&Fd[basev] = fc4;
    float4 ft = *(const float4*)&Fc[31][i0];
    float fcv[4]={fc4.x,fc4.y,fc4.z,fc4.w}, ftv[4]={ft.x,ft.y,ft.z,ft.w};
    unsigned kp[4], vp[4];
#pragma unroll
    for(int j=0;j<4;j++){
      kp[j] = pack_hl(wd_r[v][j] * expf(ftv[j] - fcv[j]));
      vp[j] = pack_hl(vv_r[v][j]);
    }
    uint4 k4u; k4u.x=kp[0];k4u.y=kp[1];k4u.z=kp[2];k4u.w=kp[3];
    uint4 v4u; v4u.x=vp[0];v4u.y=vp[1];v4u.z=vp[2];v4u.w=vp[3];
    *(uint4*)&KhP[t2][i0] = k4u;
    *(uint4*)&VsP[t2][i0] = v4u;
  }
  if(tid < 128) E[((size_t)bh*32 + c)*128 + tid] = expf(Fc[31][tid]);
  __syncthreads();
  // MFMA: dS^T[j][i] = sum_t Vs[t][j] * Kh[t][i]; wave w owns j-tile w, 4 i-tiles
  int w = tid>>6, lane = tid&63;
  int m = lane&31, hi2 = lane>>5;
  f32x16 acc[4];
#pragma unroll
  for(int it=0;it<4;it++)
#pragma unroll
    for(int r=0;r<16;r++) acc[it][r] = 0.f;
#pragma unroll
  for(int kh2=0; kh2<2; kh2++){
    int kb = kh2*16 + hi2*8;
    s16x8 ah, al;
#pragma unroll
    for(int jj=0;jj<8;jj++){
      unsigned u = VsP[kb+jj][w*32 + m];
      ah[jj] = (short)(u>>16); al[jj] = (short)(u&0xffff);
    }
#pragma unroll
    for(int it=0;it<4;it++){
      s16x8 bh_, bl_;
#pragma unroll
      for(int jj=0;jj<8;jj++){
        unsigned u = KhP[kb+jj][it*32 + m];
        bh_[jj] = (short)(u>>16); bl_[jj] = (short)(u&0xffff);
      }
      acc[it] = __builtin_amdgcn_mfma_f32_32x32x16_bf16(ah, bh_, acc[it], 0,0,0);
      acc[it] = __builtin_amdgcn_mfma_f32_32x32x16_bf16(ah, bl_, acc[it], 0,0,0);
      acc[it] = __builtin_amdgcn_mfma_f32_32x32x16_bf16(al, bh_, acc[it], 0,0,0);
    }
  }
  size_t dbase = (size_t)blk*16384;
#pragma unroll
  for(int it=0;it<4;it++)
#pragma unroll
    for(int r=0;r<16;r++){
      int ro = (r&3) + 8*(r>>2) + 4*hi2;     // j offset within tile
      dS[dbase + (size_t)(w*32 + ro)*128 + it*32 + m] = acc[it][r];
    }
}

// ---------------- phase 2: inter-chunk scan on dS_T (float4 + manual prefetch)
__global__ void scan_k(float* __restrict__ dS, const float* __restrict__ E){
  int g = blockIdx.x*256 + threadIdx.x;   // 65536 threads: (bh, float4 idx)
  int bh = g>>12;
  int e4 = (g&4095)*4;
  int i0 = e4 & 127;
  size_t base  = (size_t)bh*32*16384 + e4;
  size_t ebase = (size_t)bh*32*128 + i0;
  float4 S = make_float4(0.f,0.f,0.f,0.f);
  float4 d  = *(const float4*)&dS[base];
  float4 Ec = *(const float4*)&E[ebase];
  for(int c=0;c<32;c++){
    float4 dn = make_float4(0,0,0,0), En = make_float4(0,0,0,0);
    if(c < 31){
      dn = *(const float4*)&dS[base + (size_t)(c+1)*16384];
      En = *(const float4*)&E[ebase + (size_t)(c+1)*128];
    }
    *(float4*)&dS[base + (size_t)c*16384] = S;
    S.x = Ec.x*S.x + d.x;
    S.y = Ec.y*S.y + d.y;
    S.z = Ec.z*S.z + d.z;
    S.w = Ec.w*S.w + d.w;
    d = dn; Ec = En;
  }
}

// ---------------- phase 3: O = qt @ S + tril(qt kt^T) @ V, full MFMA
__launch_bounds__(256)
__global__ void chunk_out(const float* __restrict__ Qd, const float* __restrict__ Wt,
                          const float* __restrict__ Fd, const float* __restrict__ Vd,
                          const float* __restrict__ ST, float* __restrict__ O){
  __shared__ unsigned int qtP[32][132];   // packed bf16 hi|lo, [tok][k]
  __shared__ unsigned int ktP[32][132];
  __shared__ unsigned int Vt[128][36];    // packed, [vdim][tok]
  __shared__ float Amat[32][40];          // tril(qt kt^T), f32
  int blk = blockIdx.x, bh = blk>>5, c = blk&31;
  int b = bh>>3, h = bh&7;
  int tid = threadIdx.x, w = tid>>6, lane = tid&63;
  int m = lane&31, hi = lane>>5;
  size_t fbase = ((size_t)bh*T_ + (size_t)c*32)*128;
#pragma unroll
  for(int p=0;p<4;p++){
    int e = p*1024 + tid*4;
    int t2 = e>>7, i0 = e&127;
    float4 f4 = *(const float4*)&Fd[fbase + e];
    float4 q4 = *(const float4*)&Qd[fbase + e];
    float4 w4 = *(const float4*)&Wt[fbase + e];
    float fv[4] = {f4.x,f4.y,f4.z,f4.w};
    float qv[4] = {q4.x,q4.y,q4.z,q4.w};
    float wv[4] = {w4.x,w4.y,w4.z,w4.w};
    uint4 qp, kp;
    unsigned int qa[4], ka[4];
#pragma unroll
    for(int j=0;j<4;j++){
      float ef = expf(fv[j]);
      qa[j] = pack_hl(qv[j]*ef);
      ka[j] = pack_hl(wv[j]/ef);
    }
    qp.x=qa[0]; qp.y=qa[1]; qp.z=qa[2]; qp.w=qa[3];
    kp.x=ka[0]; kp.y=ka[1]; kp.z=ka[2]; kp.w=ka[3];
    *(uint4*)&qtP[t2][i0] = qp;
    *(uint4*)&ktP[t2][i0] = kp;
  }
  {
    int n = tid&127, th = (tid>>7)*16;
    unsigned int vp[16];
#pragma unroll
    for(int j=0;j<16;j++) vp[j] = pack_hl(Vd[fbase + (size_t)(th+j)*128 + n]);
#pragma unroll
    for(int j=0;j<16;j+=4){
      uint4 v4; v4.x=vp[j]; v4.y=vp[j+1]; v4.z=vp[j+2]; v4.w=vp[j+3];
      *(uint4*)&Vt[n][th+j] = v4;
    }
  }
  __syncthreads();
  if(w == 0){
    f32x16 am;
#pragma unroll
    for(int r=0;r<16;r++) am[r] = 0.f;
#pragma unroll
    for(int s=0;s<8;s++){
      int ko = s*16 + hi*8;
      uint4 qa = *(const uint4*)&qtP[m][ko];
      uint4 qb = *(const uint4*)&qtP[m][ko+4];
      uint4 ka = *(const uint4*)&ktP[m][ko];
      uint4 kb = *(const uint4*)&ktP[m][ko+4];
      s16x8 qh, ql, kh, kl;
      unsigned int qw_[8] = {qa.x,qa.y,qa.z,qa.w,qb.x,qb.y,qb.z,qb.w};
      unsigned int kw_[8] = {ka.x,ka.y,ka.z,ka.w,kb.x,kb.y,kb.z,kb.w};
#pragma unroll
      for(int j=0;j<8;j++){
        qh[j]=(short)(qw_[j]>>16); ql[j]=(short)(qw_[j]&0xffff);
        kh[j]=(short)(kw_[j]>>16); kl[j]=(short)(kw_[j]&0xffff);
      }
      am = __builtin_amdgcn_mfma_f32_32x32x16_bf16(qh, kh, am, 0,0,0);
      am = __builtin_amdgcn_mfma_f32_32x32x16_bf16(qh, kl, am, 0,0,0);
      am = __builtin_amdgcn_mfma_f32_32x32x16_bf16(ql, kh, am, 0,0,0);
    }
#pragma unroll
    for(int r=0;r<16;r++){
      int rm = (r&3) + 8*(r>>2) + 4*hi;
      Amat[rm][m] = (m <= rm) ? am[r] : 0.f;
    }
  }
  f32x16 oacc;
#pragma unroll
  for(int r=0;r<16;r++) oacc[r] = 0.f;
  const float* Sp = ST + (size_t)blk*16384 + (size_t)(w*32 + m)*128;
#pragma unroll
  for(int s=0;s<8;s++){
    int ko = s*16 + hi*8;
    uint4 qa = *(const uint4*)&qtP[m][ko];
    uint4 qb = *(const uint4*)&qtP[m][ko+4];
    s16x8 qh, ql;
    unsigned int qw_[8] = {qa.x,qa.y,qa.z,qa.w,qb.x,qb.y,qb.z,qb.w};
#pragma unroll
    for(int j=0;j<8;j++){ qh[j]=(short)(qw_[j]>>16); ql[j]=(short)(qw_[j]&0xffff); }
    float4 s0 = *(const float4*)&Sp[ko];
    float4 s1 = *(const float4*)&Sp[ko+4];
    float sv[8] = {s0.x,s0.y,s0.z,s0.w,s1.x,s1.y,s1.z,s1.w};
    s16x8 sh, sl;
#pragma unroll
    for(int j=0;j<8;j++){
      unsigned short hh = f2bf(sv[j]);
      sh[j] = (short)hh; sl[j] = (short)f2bf(sv[j]-bf2f(hh));
    }
    oacc = __builtin_amdgcn_mfma_f32_32x32x16_bf16(qh, sh, oacc, 0,0,0);
    oacc = __builtin_amdgcn_mfma_f32_32x32x16_bf16(qh, sl, oacc, 0,0,0);
    oacc = __builtin_amdgcn_mfma_f32_32x32x16_bf16(ql, sh, oacc, 0,0,0);
  }
  __syncthreads();
#pragma unroll
  for(int s=0;s<2;s++){
    int uo = s*16 + hi*8;
    float4 a0 = *(const float4*)&Amat[m][uo];
    float4 a1 = *(const float4*)&Amat[m][uo+4];
    float av[8] = {a0.x,a0.y,a0.z,a0.w,a1.x,a1.y,a1.z,a1.w};
    s16x8 ah, al;
#pragma unroll
    for(int j=0;j<8;j++){
      unsigned short hh = f2bf(av[j]);
      ah[j] = (short)hh; al[j] = (short)f2bf(av[j]-bf2f(hh));
    }
    uint4 v0 = *(const uint4*)&Vt[w*32 + m][uo];
    uint4 v1 = *(const uint4*)&Vt[w*32 + m][uo+4];
    unsigned int vw[8] = {v0.x,v0.y,v0.z,v0.w,v1.x,v1.y,v1.z,v1.w};
    s16x8 vh, vl;
#pragma unroll
    for(int j=0;j<8;j++){ vh[j]=(short)(vw[j]>>16); vl[j]=(short)(vw[j]&0xffff); }
    oacc = __builtin_amdgcn_mfma_f32_32x32x16_bf16(ah, vh, oacc, 0,0,0);
    oacc = __builtin_amdgcn_mfma_f32_32x32x16_bf16(ah, vl, oacc, 0,0,0);
    oacc = __builtin_amdgcn_mfma_f32_32x32x16_bf16(al, vh, oacc, 0,0,0);
  }
#pragma unroll
  for(int r=0;r<16;r++){
    int tok = (r&3) + 8*(r>>2) + 4*hi;
    O[((size_t)(b*T_ + c*32 + tok))*1024 + h*128 + w*32 + m] = oacc[r];
  }
}

// ---------------- final g-RMSNorm + cast bf16
__global__ void gnorm_k(const float* __restrict__ Ob, const float* __restrict__ gw,
                        unsigned short* __restrict__ On){
  __shared__ float red[4];
  int n = blockIdx.x, tid = threadIdx.x;
  size_t base = (size_t)n*1024 + tid*4;
  float4 x = *(const float4*)&Ob[base];
  float ss = x.x*x.x + x.y*x.y + x.z*x.z + x.w*x.w;
  ss+=__shfl_xor(ss,1);ss+=__shfl_xor(ss,2);ss+=__shfl_xor(ss,4);
  ss+=__shfl_xor(ss,8);ss+=__shfl_xor(ss,16);ss+=__shfl_xor(ss,32);
  if((tid&63)==0) red[tid>>6]=ss;
  __syncthreads();
  float sc = rsqrtf((red[0]+red[1]+red[2]+red[3])/1024.f + 1e-5f);
  float4 g = *(const float4*)&gw[tid*4];
  ushort4 o4;
  o4.x=f2bf(x.x*sc*g.x); o4.y=f2bf(x.y*sc*g.y);
  o4.z=f2bf(x.z*sc*g.z); o4.w=f2bf(x.w*sc*g.w);
  *(ushort4*)&On[base]=o4;
}

extern "C" void kernel_launch(void* const* d_in, const int* in_sizes, int n_in,
                              void* d_out, int out_size, void* d_ws, size_t ws_size,
                              hipStream_t stream){
  const float* hs   = (const float*)d_in[0];
  const float* Wq   = (const float*)d_in[1];
  const float* Wk   = (const float*)d_in[2];
  const float* Wv   = (const float*)d_in[3];
  const float* Wr   = (const float*)d_in[4];
  const float* Wa   = (const float*)d_in[5];
  const float* A_log= (const float*)d_in[6];
  const float* dtb  = (const float*)d_in[7];
  const float* qw   = (const float*)d_in[8];
  const float* kw   = (const float*)d_in[9];
  const float* gw   = (const float*)d_in[10];
  const float* Wo   = (const float*)d_in[11];
  float* out = (float*)d_out;

  char* wsp = (char*)d_ws;
  size_t off = 0;
  auto alloc = [&](size_t bytes)->void*{ void* p = wsp + off; off += (bytes + 255) & ~(size_t)255; return p; };
  unsigned short* Xhi    = (unsigned short*)alloc(2048ull*1024*2);
  unsigned short* Xlo    = (unsigned short*)alloc(2048ull*1024*2);
  unsigned short* WcatT3 = (unsigned short*)alloc(3072ull*1024*2);
  unsigned short* WrThi  = (unsigned short*)alloc(1024ull*1024*2);
  unsigned short* WrTlo  = (unsigned short*)alloc(1024ull*1024*2);
  unsigned short* WoT    = (unsigned short*)alloc(1024ull*1024*2);
  float* C1 = (float*)alloc(2048ull*3072*4);
  float* Rp = (float*)alloc(3ull*2048*1024*4);   // router partials
  float* fh = (float*)alloc(2048ull*8*4);
  float* Qd = (float*)alloc(16ull*1024*128*4);
  float* Wt = (float*)alloc(16ull*1024*128*4);
  float* Fd = (float*)alloc(16ull*1024*128*4);
  float* Vd = (float*)alloc(16ull*1024*128*4);
  float* E  = (float*)alloc(16ull*32*128*4);
  float* dS = (float*)alloc(16ull*32*16384*4);
  float* Ob = (float*)alloc(2048ull*1024*4);
  unsigned short* On = (unsigned short*)alloc(2048ull*1024*2);
  (void)ws_size; (void)in_sizes; (void)n_in; (void)out_size;

  prep_k     <<<dim3(2048),        dim3(256),   0, stream>>>(hs, Wa, A_log, dtb, Xhi, Xlo, fh);
  wtrans     <<<dim3(32,32,5),     dim3(32,8),  0, stream>>>(Wq,Wk,Wv,Wr,Wo, WcatT3,WrThi,WrTlo,WoT);
  gemm_fused <<<dim3(768),         dim3(256),   0, stream>>>(Xhi, Xlo, WcatT3, WrThi, WrTlo, C1, Rp);
  pp_sum     <<<dim3(512),         dim3(256),   0, stream>>>(C1, Rp, fh, qw, kw, Qd, Wt, Fd, Vd, dS, E);
  scan_k     <<<dim3(256),         dim3(256),   0, stream>>>(dS, E);
  chunk_out  <<<dim3(512),         dim3(256),   0, stream>>>(Qd, Wt, Fd, Vd, dS, Ob);
  gnorm_k    <<<dim3(2048),        dim3(256),   0, stream>>>(Ob, gw, On);
  gemm_out   <<<dim3(16,16),       dim3(256),   0, stream>>>(On, WoT, out);
}